// Round 1
// baseline (1052.957 us; speedup 1.0000x reference)
//
#include <hip/hip_runtime.h>
#include <hip/hip_bf16.h>

#define N_ENT_C 100000
#define N_REL_C 500
#define IN_DIM_C 128
#define OUT_DIM_C 128
#define NEDGE_C 500000

// ---------------- ws layout (float offsets) ----------------
// Wtc   [128][256]  : 32768     (src cols 0-127, dst cols 128-255)
// Wtr   [128][128]  : 16384
// P_r   [500][128]  : 64000     (includes a_b)
// P_s   [100000][128]
// P_d   [100000][128]
// e_b_sum [100000]              (zeroed each call)
// rel_rep [R][500][128]         (zeroed each call)
// cnt_rep [R][500]              (zeroed each call)
#define OFF_WTC   0
#define OFF_WTR   32768
#define OFF_PR    49152
#define OFF_PS    113152
#define OFF_PD    12913152
#define OFF_EBS   25713152
#define OFF_RELREP 25813152

// ---------------- weight transpose ----------------
__global__ void prep_w(const float* __restrict__ aw, float* __restrict__ Wtc,
                       float* __restrict__ Wtr) {
    int idx = blockIdx.x * 256 + threadIdx.x;   // 0..49151
    if (idx < 128 * 256) {
        int k = idx >> 8, o = idx & 255;
        float v = (o < 128) ? aw[o * 384 + k] : aw[(o - 128) * 384 + 128 + k];
        Wtc[idx] = v;
    } else if (idx < 128 * 384) {
        int t = idx - 32768;
        int k = t >> 7, o = t & 127;
        Wtr[t] = aw[o * 384 + 256 + k];
    }
}

// ---------------- rel projection: P_r[r][o] = sum_k rel[r][k]*W_r[o][k] + a_b[o] ----------------
__global__ void rel_proj(const float* __restrict__ rele, const float* __restrict__ Wtr,
                         const float* __restrict__ ab, float* __restrict__ Pr) {
    int r = blockIdx.x;
    int o = threadIdx.x;
    float acc = ab[o];
    for (int k = 0; k < 128; ++k)
        acc = fmaf(rele[r * 128 + k], Wtr[k * 128 + o], acc);
    Pr[r * 128 + o] = acc;
}

// ---------------- ent projection: P_s / P_d, 64-row tile, 8x8 reg blocking ----------------
__global__ __launch_bounds__(256) void ent_proj(const float* __restrict__ ent,
                                                const float* __restrict__ Wtc,
                                                float* __restrict__ Ps,
                                                float* __restrict__ Pd) {
    __shared__ float As[64][128];   // 32 KB
    const int tid = threadIdx.x;
    const int block_row = blockIdx.x * 64;

    // load A tile (coalesced float4), zero-pad tail rows
#pragma unroll
    for (int i = 0; i < 8; ++i) {
        int f = tid + i * 256;          // 0..2047 float4 slots
        int m = f >> 5;                 // row in tile
        int k4 = f & 31;                // float4 index in row
        float4 v = make_float4(0.f, 0.f, 0.f, 0.f);
        int grow = block_row + m;
        if (grow < N_ENT_C) v = *(const float4*)&ent[grow * 128 + k4 * 4];
        *(float4*)&As[m][k4 * 4] = v;
    }
    __syncthreads();

    const int tc = tid & 31;   // col group: cols tc*8 .. tc*8+7 of 256
    const int tr = tid >> 5;   // row group: rows tr*8 .. tr*8+7

    float acc[8][8];
#pragma unroll
    for (int i = 0; i < 8; ++i)
#pragma unroll
        for (int j = 0; j < 8; ++j) acc[i][j] = 0.f;

#pragma unroll 2
    for (int k4 = 0; k4 < 32; ++k4) {
        float4 av[8];
#pragma unroll
        for (int i = 0; i < 8; ++i) av[i] = *(const float4*)&As[tr * 8 + i][k4 * 4];
#pragma unroll
        for (int j = 0; j < 4; ++j) {
            int k = k4 * 4 + j;
            float4 b0 = *(const float4*)&Wtc[k * 256 + tc * 8];
            float4 b1 = *(const float4*)&Wtc[k * 256 + tc * 8 + 4];
#pragma unroll
            for (int i = 0; i < 8; ++i) {
                float a = ((const float*)&av[i])[j];
                acc[i][0] = fmaf(a, b0.x, acc[i][0]);
                acc[i][1] = fmaf(a, b0.y, acc[i][1]);
                acc[i][2] = fmaf(a, b0.z, acc[i][2]);
                acc[i][3] = fmaf(a, b0.w, acc[i][3]);
                acc[i][4] = fmaf(a, b1.x, acc[i][4]);
                acc[i][5] = fmaf(a, b1.y, acc[i][5]);
                acc[i][6] = fmaf(a, b1.z, acc[i][6]);
                acc[i][7] = fmaf(a, b1.w, acc[i][7]);
            }
        }
    }

#pragma unroll
    for (int i = 0; i < 8; ++i) {
        int grow = block_row + tr * 8 + i;
        if (grow >= N_ENT_C) continue;
        float4 o0 = make_float4(acc[i][0], acc[i][1], acc[i][2], acc[i][3]);
        float4 o1 = make_float4(acc[i][4], acc[i][5], acc[i][6], acc[i][7]);
        if (tc < 16) {
            *(float4*)&Ps[grow * 128 + tc * 8] = o0;
            *(float4*)&Ps[grow * 128 + tc * 8 + 4] = o1;
        } else {
            *(float4*)&Pd[grow * 128 + (tc - 16) * 8] = o0;
            *(float4*)&Pd[grow * 128 + (tc - 16) * 8 + 4] = o1;
        }
    }
}

// ---------------- edge kernel: 1 wave per edge ----------------
__global__ __launch_bounds__(256) void edge_kernel(
    const int* __restrict__ src, const int* __restrict__ dst, const int* __restrict__ rel,
    const float* __restrict__ Ps, const float* __restrict__ Pd, const float* __restrict__ Pr,
    const float* __restrict__ a2w, const float* __restrict__ a2b,
    float* __restrict__ hsum, float* __restrict__ ebsum,
    float* __restrict__ relrep, float* __restrict__ cntrep, int R) {
    const int lane = threadIdx.x & 63;
    const int wid = (blockIdx.x * blockDim.x + threadIdx.x) >> 6;
    const int nw = (gridDim.x * blockDim.x) >> 6;
    const int rep = wid % R;
    const float w0 = a2w[lane * 2];
    const float w1 = a2w[lane * 2 + 1];
    const float bb = a2b[0];

    for (int e = wid; e < NEDGE_C; e += nw) {
        int s = src[e], d = dst[e], r = rel[e];
        float2 ps = *(const float2*)&Ps[s * 128 + lane * 2];
        float2 pd = *(const float2*)&Pd[d * 128 + lane * 2];
        float2 pr = *(const float2*)&Pr[r * 128 + lane * 2];
        float cx = ps.x + pd.x + pr.x;
        float cy = ps.y + pd.y + pr.y;
        float t = fmaf(cx, w0, cy * w1);
        t += __shfl_xor(t, 32);
        t += __shfl_xor(t, 16);
        t += __shfl_xor(t, 8);
        t += __shfl_xor(t, 4);
        t += __shfl_xor(t, 2);
        t += __shfl_xor(t, 1);
        float b = t + bb;
        b = (b > 0.f) ? b : 0.01f * b;
        float eb = expf(b);
        float tx = eb * cx, ty = eb * cy;

        float* hp = &hsum[s * 128 + lane * 2];
        unsafeAtomicAdd(hp, tx);
        unsafeAtomicAdd(hp + 1, ty);
        float* rr = &relrep[(size_t)rep * 64000 + r * 128 + lane * 2];
        unsafeAtomicAdd(rr, tx);
        unsafeAtomicAdd(rr + 1, ty);
        if (lane == 0) {
            unsafeAtomicAdd(&ebsum[s], eb);
            unsafeAtomicAdd(&cntrep[rep * 500 + r], 1.0f);
        }
    }
}

// ---------------- finalize entities: elu(h_sum / ebs) in place ----------------
__global__ void fin_ent(float* __restrict__ hout, const float* __restrict__ ebsum) {
    int idx = blockIdx.x * 256 + threadIdx.x;   // float4 index, 3.2M total
    if (idx >= N_ENT_C * 32) return;
    int n = idx >> 5;
    float s = ebsum[n];
    s = (s == 0.f) ? 1e-12f : s;
    float inv = 1.f / s;
    float4* p = (float4*)hout + idx;
    float4 v = *p;
    v.x *= inv; v.y *= inv; v.z *= inv; v.w *= inv;
    v.x = (v.x > 0.f) ? v.x : (expf(v.x) - 1.f);
    v.y = (v.y > 0.f) ? v.y : (expf(v.y) - 1.f);
    v.z = (v.z > 0.f) ? v.z : (expf(v.z) - 1.f);
    v.w = (v.w > 0.f) ? v.w : (expf(v.w) - 1.f);
    *p = v;
}

// ---------------- finalize relations: reduce replicas, mean, elu ----------------
__global__ void fin_rel(const float* __restrict__ relrep, const float* __restrict__ cntrep,
                        float* __restrict__ out, int R) {
    int idx = blockIdx.x * 256 + threadIdx.x;
    if (idx >= N_REL_C * 128) return;
    int r = idx >> 7;
    float s = 0.f, c = 0.f;
    for (int rep = 0; rep < R; ++rep) {
        s += relrep[(size_t)rep * 64000 + idx];
        c += cntrep[rep * 500 + r];
    }
    float h = s / fmaxf(c, 1.f);
    out[idx] = (h > 0.f) ? h : (expf(h) - 1.f);
}

extern "C" void kernel_launch(void* const* d_in, const int* in_sizes, int n_in,
                              void* d_out, int out_size, void* d_ws, size_t ws_size,
                              hipStream_t stream) {
    const float* ent  = (const float*)d_in[0];
    const float* rele = (const float*)d_in[1];
    const float* aw   = (const float*)d_in[2];
    const float* ab   = (const float*)d_in[3];
    const float* a2w  = (const float*)d_in[4];
    const float* a2b  = (const float*)d_in[5];
    const int* src    = (const int*)d_in[6];
    const int* dst    = (const int*)d_in[7];
    const int* rel    = (const int*)d_in[8];
    float* out = (float*)d_out;

    float* ws = (float*)d_ws;
    float* Wtc = ws + OFF_WTC;
    float* Wtr = ws + OFF_WTR;
    float* Pr  = ws + OFF_PR;
    float* Ps  = ws + OFF_PS;
    float* Pd  = ws + OFF_PD;
    float* ebs = ws + OFF_EBS;
    float* relrep = ws + OFF_RELREP;

    // pick replica count R that fits the workspace (deterministic per run)
    long long avail = (long long)(ws_size / 4) - (long long)OFF_RELREP;
    int R = (int)(avail / 64500LL);
    if (R > 64) R = 64;
    if (R < 1) R = 1;
    float* cntrep = relrep + (size_t)R * 64000;

    // zero accumulators: h_sum region of d_out, ebs + rel replicas + counts
    hipMemsetAsync(out, 0, (size_t)N_ENT_C * 128 * sizeof(float), stream);
    hipMemsetAsync(ebs, 0, ((size_t)N_ENT_C + (size_t)R * 64500) * sizeof(float), stream);

    prep_w<<<192, 256, 0, stream>>>(aw, Wtc, Wtr);
    rel_proj<<<N_REL_C, 128, 0, stream>>>(rele, Wtr, ab, Pr);
    ent_proj<<<(N_ENT_C + 63) / 64, 256, 0, stream>>>(ent, Wtc, Ps, Pd);
    edge_kernel<<<2048, 256, 0, stream>>>(src, dst, rel, Ps, Pd, Pr, a2w, a2b,
                                          out, ebs, relrep, cntrep, R);
    fin_ent<<<(N_ENT_C * 32 + 255) / 256, 256, 0, stream>>>(out, ebs);
    fin_rel<<<(N_REL_C * 128 + 255) / 256, 256, 0, stream>>>(relrep, cntrep,
                                                             out + (size_t)N_ENT_C * 128, R);
}

// Round 2
// 804.267 us; speedup vs baseline: 1.3092x; 1.3092x over previous
//
#include <hip/hip_runtime.h>
#include <hip/hip_bf16.h>

#define N_ENT_C 100000
#define N_REL_C 500
#define IN_DIM_C 128
#define OUT_DIM_C 128
#define NEDGE_C 500000
#define SCAN_BLOCKS 391   // ceil(100000/256)

// ---------------- ws layout (float offsets) ----------------
// Wtc [128][256], Wtr [128][128], P_r [500][128], P_s [100000][128], P_d [100000][128]
#define OFF_WTC   0
#define OFF_WTR   32768
#define OFF_PR    49152
#define OFF_PS    113152
#define OFF_PD    12913152
// total = 25,713,152 floats = 102.85 MB (less than round-1's proven footprint)

// ---------------- d_out scratch layout (int offsets; dead until final copy) --------
#define DO_HSRC   0         // histSrc   [100000]
#define DO_OSRC   100000    // offsSrc   [100000]
#define DO_HREL   200000    // histRel/offsRel [500]
#define DO_BSUM   200512    // blockSums [512]
#define DO_DSTS   262144    // dstS [500000]
#define DO_RELS   762144    // relS [500000]
#define DO_SRCR   1262144   // srcR [500000]
#define DO_DSTR   1762144   // dstR [500000]  (ends 2,262,144 ints = 9.05 MB << 51.2 MB)

// ---------------- weight transpose ----------------
__global__ void prep_w(const float* __restrict__ aw, float* __restrict__ Wtc,
                       float* __restrict__ Wtr) {
    int idx = blockIdx.x * 256 + threadIdx.x;   // 0..49151
    if (idx < 128 * 256) {
        int k = idx >> 8, o = idx & 255;
        float v = (o < 128) ? aw[o * 384 + k] : aw[(o - 128) * 384 + 128 + k];
        Wtc[idx] = v;
    } else if (idx < 128 * 384) {
        int t = idx - 32768;
        int k = t >> 7, o = t & 127;
        Wtr[t] = aw[o * 384 + 256 + k];
    }
}

// ---------------- rel projection ----------------
__global__ void rel_proj(const float* __restrict__ rele, const float* __restrict__ Wtr,
                         const float* __restrict__ ab, float* __restrict__ Pr) {
    int r = blockIdx.x;
    int o = threadIdx.x;
    float acc = ab[o];
    for (int k = 0; k < 128; ++k)
        acc = fmaf(rele[r * 128 + k], Wtr[k * 128 + o], acc);
    Pr[r * 128 + o] = acc;
}

// ---------------- ent projection: P_s / P_d ----------------
__global__ __launch_bounds__(256) void ent_proj(const float* __restrict__ ent,
                                                const float* __restrict__ Wtc,
                                                float* __restrict__ Ps,
                                                float* __restrict__ Pd) {
    __shared__ float As[64][128];
    const int tid = threadIdx.x;
    const int block_row = blockIdx.x * 64;
#pragma unroll
    for (int i = 0; i < 8; ++i) {
        int f = tid + i * 256;
        int m = f >> 5, k4 = f & 31;
        float4 v = make_float4(0.f, 0.f, 0.f, 0.f);
        int grow = block_row + m;
        if (grow < N_ENT_C) v = *(const float4*)&ent[grow * 128 + k4 * 4];
        *(float4*)&As[m][k4 * 4] = v;
    }
    __syncthreads();
    const int tc = tid & 31;
    const int tr = tid >> 5;
    float acc[8][8];
#pragma unroll
    for (int i = 0; i < 8; ++i)
#pragma unroll
        for (int j = 0; j < 8; ++j) acc[i][j] = 0.f;
#pragma unroll 2
    for (int k4 = 0; k4 < 32; ++k4) {
        float4 av[8];
#pragma unroll
        for (int i = 0; i < 8; ++i) av[i] = *(const float4*)&As[tr * 8 + i][k4 * 4];
#pragma unroll
        for (int j = 0; j < 4; ++j) {
            int k = k4 * 4 + j;
            float4 b0 = *(const float4*)&Wtc[k * 256 + tc * 8];
            float4 b1 = *(const float4*)&Wtc[k * 256 + tc * 8 + 4];
#pragma unroll
            for (int i = 0; i < 8; ++i) {
                float a = ((const float*)&av[i])[j];
                acc[i][0] = fmaf(a, b0.x, acc[i][0]);
                acc[i][1] = fmaf(a, b0.y, acc[i][1]);
                acc[i][2] = fmaf(a, b0.z, acc[i][2]);
                acc[i][3] = fmaf(a, b0.w, acc[i][3]);
                acc[i][4] = fmaf(a, b1.x, acc[i][4]);
                acc[i][5] = fmaf(a, b1.y, acc[i][5]);
                acc[i][6] = fmaf(a, b1.z, acc[i][6]);
                acc[i][7] = fmaf(a, b1.w, acc[i][7]);
            }
        }
    }
#pragma unroll
    for (int i = 0; i < 8; ++i) {
        int grow = block_row + tr * 8 + i;
        if (grow >= N_ENT_C) continue;
        float4 o0 = make_float4(acc[i][0], acc[i][1], acc[i][2], acc[i][3]);
        float4 o1 = make_float4(acc[i][4], acc[i][5], acc[i][6], acc[i][7]);
        if (tc < 16) {
            *(float4*)&Ps[grow * 128 + tc * 8] = o0;
            *(float4*)&Ps[grow * 128 + tc * 8 + 4] = o1;
        } else {
            *(float4*)&Pd[grow * 128 + (tc - 16) * 8] = o0;
            *(float4*)&Pd[grow * 128 + (tc - 16) * 8 + 4] = o1;
        }
    }
}

// ---------------- edge histograms ----------------
__global__ void hist_edges(const int* __restrict__ src, const int* __restrict__ rel,
                           int* __restrict__ histSrc, int* __restrict__ histRel) {
    int e = blockIdx.x * 256 + threadIdx.x;
    if (e >= NEDGE_C) return;
    atomicAdd(&histSrc[src[e]], 1);
    atomicAdd(&histRel[rel[e]], 1);
}

// ---------------- scan: per-block reduce ----------------
__global__ void scan_blockred(const int* __restrict__ hist, int* __restrict__ blockSums, int n) {
    __shared__ int s[256];
    int tid = threadIdx.x;
    int i = blockIdx.x * 256 + tid;
    s[tid] = (i < n) ? hist[i] : 0;
    __syncthreads();
    for (int off = 128; off > 0; off >>= 1) {
        if (tid < off) s[tid] += s[tid + off];
        __syncthreads();
    }
    if (tid == 0) blockSums[blockIdx.x] = s[0];
}

// ---------------- scan: single-block exclusive scan in place (n <= 1024) ----------------
__global__ void scan_single(int* __restrict__ data, int n) {
    __shared__ int a[1024], b2[1024];
    int tid = threadIdx.x;
    int v = (tid < n) ? data[tid] : 0;
    a[tid] = v;
    __syncthreads();
    int* cur = a; int* nxt = b2;
    for (int off = 1; off < 1024; off <<= 1) {
        int x = cur[tid] + ((tid >= off) ? cur[tid - off] : 0);
        nxt[tid] = x;
        __syncthreads();
        int* t = cur; cur = nxt; nxt = t;
    }
    if (tid < n) data[tid] = cur[tid] - v;   // exclusive
}

// ---------------- scan: finalize per-block exclusive scan + block offset ----------------
__global__ void scan_final(const int* __restrict__ hist, const int* __restrict__ blockOffs,
                           int* __restrict__ offs, int n) {
    __shared__ int a[256], b2[256];
    int tid = threadIdx.x;
    int i = blockIdx.x * 256 + tid;
    int v = (i < n) ? hist[i] : 0;
    a[tid] = v;
    __syncthreads();
    int* cur = a; int* nxt = b2;
    for (int off = 1; off < 256; off <<= 1) {
        int x = cur[tid] + ((tid >= off) ? cur[tid - off] : 0);
        nxt[tid] = x;
        __syncthreads();
        int* t = cur; cur = nxt; nxt = t;
    }
    if (i < n) offs[i] = cur[tid] - v + blockOffs[blockIdx.x];
}

// ---------------- scatter into src-sorted and rel-sorted lists ----------------
__global__ void scatter_edges(const int* __restrict__ src, const int* __restrict__ dst,
                              const int* __restrict__ rel,
                              int* __restrict__ offsSrc, int* __restrict__ offsRel,
                              int* __restrict__ dstS, int* __restrict__ relS,
                              int* __restrict__ srcR, int* __restrict__ dstR) {
    int e = blockIdx.x * 256 + threadIdx.x;
    if (e >= NEDGE_C) return;
    int s = src[e], d = dst[e], r = rel[e];
    int p = atomicAdd(&offsSrc[s], 1);
    dstS[p] = d; relS[p] = r;
    int q = atomicAdd(&offsRel[r], 1);
    srcR[q] = s; dstR[q] = d;
}

// ---------------- rel phase: block per relation, writes final rel output ----------------
// MUST run before src_phase (reads pristine Ps).
__global__ __launch_bounds__(256) void rel_phase(const float* __restrict__ Ps,
                                                 const float* __restrict__ Pd,
                                                 const float* __restrict__ Pr,
                                                 const int* __restrict__ offsRel,
                                                 const int* __restrict__ srcR,
                                                 const int* __restrict__ dstR,
                                                 const float* __restrict__ a2w,
                                                 const float* __restrict__ a2b,
                                                 float* __restrict__ outRel) {
    int r = blockIdx.x;
    int start = (r == 0) ? 0 : offsRel[r - 1];
    int end = offsRel[r];               // post-scatter: exclusive end
    int lane = threadIdx.x & 63;
    int w = threadIdx.x >> 6;
    float w0 = a2w[lane * 2], w1 = a2w[lane * 2 + 1], bb = a2b[0];
    float2 prv = *(const float2*)&Pr[r * 128 + lane * 2];
    float ax = 0.f, ay = 0.f;
    for (int i = start + w; i < end; i += 4) {
        int s = srcR[i], d = dstR[i];
        float2 ps = *(const float2*)&Ps[s * 128 + lane * 2];
        float2 pd = *(const float2*)&Pd[d * 128 + lane * 2];
        float cx = ps.x + pd.x + prv.x;
        float cy = ps.y + pd.y + prv.y;
        float t = fmaf(cx, w0, cy * w1);
        t += __shfl_xor(t, 32);
        t += __shfl_xor(t, 16);
        t += __shfl_xor(t, 8);
        t += __shfl_xor(t, 4);
        t += __shfl_xor(t, 2);
        t += __shfl_xor(t, 1);
        float b = t + bb;
        b = (b > 0.f) ? b : 0.01f * b;
        float eb = expf(b);
        ax = fmaf(eb, cx, ax);
        ay = fmaf(eb, cy, ay);
    }
    __shared__ float lx[4][128];
    lx[w][lane * 2] = ax;
    lx[w][lane * 2 + 1] = ay;
    __syncthreads();
    int tid = threadIdx.x;
    if (tid < 128) {
        float s4 = lx[0][tid] + lx[1][tid] + lx[2][tid] + lx[3][tid];
        float cnt = (float)(end - start);
        float h = s4 / fmaxf(cnt, 1.f);
        outRel[r * 128 + tid] = (h > 0.f) ? h : (expf(h) - 1.f);
    }
}

// ---------------- src phase: one wave per source node, writes elu(h) over its Ps row ----
__global__ __launch_bounds__(256) void src_phase(float* __restrict__ Ps,
                                                 const float* __restrict__ Pd,
                                                 const float* __restrict__ Pr,
                                                 const int* __restrict__ offsSrc,
                                                 const int* __restrict__ dstS,
                                                 const int* __restrict__ relS,
                                                 const float* __restrict__ a2w,
                                                 const float* __restrict__ a2b) {
    int wid = (blockIdx.x * 256 + threadIdx.x) >> 6;
    if (wid >= N_ENT_C) return;
    int lane = threadIdx.x & 63;
    int s = wid;
    int start = (s == 0) ? 0 : offsSrc[s - 1];
    int end = offsSrc[s];
    float2* psp = (float2*)&Ps[s * 128 + lane * 2];
    if (end == start) { *psp = make_float2(0.f, 0.f); return; }   // elu(0/1e-12)=0
    float w0 = a2w[lane * 2], w1 = a2w[lane * 2 + 1], bb = a2b[0];
    float2 ps = *psp;
    float ax = 0.f, ay = 0.f, ebs = 0.f;
    for (int i = start; i < end; ++i) {
        int d = dstS[i], r = relS[i];
        float2 pd = *(const float2*)&Pd[d * 128 + lane * 2];
        float2 pr = *(const float2*)&Pr[r * 128 + lane * 2];
        float cx = ps.x + pd.x + pr.x;
        float cy = ps.y + pd.y + pr.y;
        float t = fmaf(cx, w0, cy * w1);
        t += __shfl_xor(t, 32);
        t += __shfl_xor(t, 16);
        t += __shfl_xor(t, 8);
        t += __shfl_xor(t, 4);
        t += __shfl_xor(t, 2);
        t += __shfl_xor(t, 1);
        float b = t + bb;
        b = (b > 0.f) ? b : 0.01f * b;
        float eb = expf(b);
        ax = fmaf(eb, cx, ax);
        ay = fmaf(eb, cy, ay);
        ebs += eb;
    }
    float inv = 1.f / ebs;               // ebs > 0 (eb = exp(..) > 0)
    float hx = ax * inv, hy = ay * inv;
    hx = (hx > 0.f) ? hx : (expf(hx) - 1.f);
    hy = (hy > 0.f) ? hy : (expf(hy) - 1.f);
    *psp = make_float2(hx, hy);
}

extern "C" void kernel_launch(void* const* d_in, const int* in_sizes, int n_in,
                              void* d_out, int out_size, void* d_ws, size_t ws_size,
                              hipStream_t stream) {
    const float* ent  = (const float*)d_in[0];
    const float* rele = (const float*)d_in[1];
    const float* aw   = (const float*)d_in[2];
    const float* ab   = (const float*)d_in[3];
    const float* a2w  = (const float*)d_in[4];
    const float* a2b  = (const float*)d_in[5];
    const int* src    = (const int*)d_in[6];
    const int* dst    = (const int*)d_in[7];
    const int* rel    = (const int*)d_in[8];
    float* out = (float*)d_out;

    float* ws = (float*)d_ws;
    float* Wtc = ws + OFF_WTC;
    float* Wtr = ws + OFF_WTR;
    float* Pr  = ws + OFF_PR;
    float* Ps  = ws + OFF_PS;
    float* Pd  = ws + OFF_PD;

    // d_out entity region doubles as sort scratch until the final copy
    int* dI = (int*)d_out;
    int* histSrc = dI + DO_HSRC;
    int* offsSrc = dI + DO_OSRC;
    int* offsRel = dI + DO_HREL;   // hist -> (in-place scan) -> offsets
    int* bsum    = dI + DO_BSUM;
    int* dstS    = dI + DO_DSTS;
    int* relS    = dI + DO_RELS;
    int* srcR    = dI + DO_SRCR;
    int* dstR    = dI + DO_DSTR;

    // zero hist arrays (+ blockSums pad) each call
    hipMemsetAsync(dI, 0, (size_t)(DO_BSUM + 512) * sizeof(int), stream);

    prep_w<<<192, 256, 0, stream>>>(aw, Wtc, Wtr);
    rel_proj<<<N_REL_C, 128, 0, stream>>>(rele, Wtr, ab, Pr);
    ent_proj<<<(N_ENT_C + 63) / 64, 256, 0, stream>>>(ent, Wtc, Ps, Pd);

    hist_edges<<<(NEDGE_C + 255) / 256, 256, 0, stream>>>(src, rel, histSrc, offsRel);
    scan_blockred<<<SCAN_BLOCKS, 256, 0, stream>>>(histSrc, bsum, N_ENT_C);
    scan_single<<<1, 1024, 0, stream>>>(bsum, SCAN_BLOCKS);
    scan_final<<<SCAN_BLOCKS, 256, 0, stream>>>(histSrc, bsum, offsSrc, N_ENT_C);
    scan_single<<<1, 1024, 0, stream>>>(offsRel, N_REL_C);
    scatter_edges<<<(NEDGE_C + 255) / 256, 256, 0, stream>>>(src, dst, rel, offsSrc, offsRel,
                                                             dstS, relS, srcR, dstR);

    // rel phase BEFORE src phase (src_phase overwrites Ps)
    rel_phase<<<N_REL_C, 256, 0, stream>>>(Ps, Pd, Pr, offsRel, srcR, dstR, a2w, a2b,
                                           out + (size_t)N_ENT_C * 128);
    src_phase<<<(N_ENT_C + 3) / 4, 256, 0, stream>>>(Ps, Pd, Pr, offsSrc, dstS, relS, a2w, a2b);

    // final: copy entity results (written into Ps) to d_out
    hipMemcpyAsync(out, Ps, (size_t)N_ENT_C * 128 * sizeof(float),
                   hipMemcpyDeviceToDevice, stream);
}

// Round 3
// 637.325 us; speedup vs baseline: 1.6522x; 1.2619x over previous
//
#include <hip/hip_runtime.h>
#include <hip/hip_bf16.h>

#define N_ENT_C 100000
#define N_REL_C 500
#define IN_DIM_C 128
#define OUT_DIM_C 128
#define NEDGE_C 500000
#define SCAN_BLOCKS 391   // ceil(100000/256)

// ---------------- ws layout (float offsets) — identical footprint to round 2 ----------
#define OFF_WTC   0
#define OFF_WTR   32768
#define OFF_PR    49152
#define OFF_PS    113152
#define OFF_PD    12913152
// end = 25,713,152 floats = 102.85 MB

// ---------------- d_out scratch layout (int/float offsets; dead until final copy) -----
#define DO_HSRC   0         // histSrc   [100000]
#define DO_OSRC   100000    // offsSrc   [100000]
#define DO_HREL   200000    // histRel/offsRel [500]
#define DO_BSUM   200512    // blockSums [512]
#define DO_DSTS   262144    // dstS [500000]
#define DO_RELS   762144    // relS [500000]
#define DO_SRCR   1262144   // srcR [500000]
#define DO_DSTR   1762144   // dstR [500000]
#define DO_RELP   2262144   // relpart [4000][132] = 528000 floats
#define DO_QS     2790144   // qs [100000]
#define DO_QD     2890144   // qd [100000]
#define DO_QR     2990144   // qr [500]
// end = 2,990,644 -> SCRATCH_ROWS = ceil(/128) = 23365
#define SCRATCH_ROWS 23365

// ---------------- weight transpose ----------------
__global__ void prep_w(const float* __restrict__ aw, float* __restrict__ Wtc,
                       float* __restrict__ Wtr) {
    int idx = blockIdx.x * 256 + threadIdx.x;   // 0..49151
    if (idx < 128 * 256) {
        int k = idx >> 8, o = idx & 255;
        float v = (o < 128) ? aw[o * 384 + k] : aw[(o - 128) * 384 + 128 + k];
        Wtc[idx] = v;
    } else if (idx < 128 * 384) {
        int t = idx - 32768;
        int k = t >> 7, o = t & 127;
        Wtr[t] = aw[o * 384 + 256 + k];
    }
}

// ---------------- rel projection + qr epilogue ----------------
__global__ void rel_proj(const float* __restrict__ rele, const float* __restrict__ Wtr,
                         const float* __restrict__ ab, const float* __restrict__ a2w,
                         float* __restrict__ Pr, float* __restrict__ qr) {
    int r = blockIdx.x;
    int o = threadIdx.x;
    float acc = ab[o];
    for (int k = 0; k < 128; ++k)
        acc = fmaf(rele[r * 128 + k], Wtr[k * 128 + o], acc);
    Pr[r * 128 + o] = acc;
    __shared__ float red[128];
    red[o] = acc * a2w[o];
    __syncthreads();
    for (int off = 64; off > 0; off >>= 1) {
        if (o < off) red[o] += red[o + off];
        __syncthreads();
    }
    if (o == 0) qr[r] = red[0];
}

// ---------------- ent projection + qs/qd epilogue ----------------
__global__ __launch_bounds__(256) void ent_proj(const float* __restrict__ ent,
                                                const float* __restrict__ Wtc,
                                                const float* __restrict__ a2w,
                                                float* __restrict__ Ps,
                                                float* __restrict__ Pd,
                                                float* __restrict__ qs,
                                                float* __restrict__ qd) {
    __shared__ float As[64][128];
    const int tid = threadIdx.x;
    const int block_row = blockIdx.x * 64;
#pragma unroll
    for (int i = 0; i < 8; ++i) {
        int f = tid + i * 256;
        int m = f >> 5, k4 = f & 31;
        float4 v = make_float4(0.f, 0.f, 0.f, 0.f);
        int grow = block_row + m;
        if (grow < N_ENT_C) v = *(const float4*)&ent[grow * 128 + k4 * 4];
        *(float4*)&As[m][k4 * 4] = v;
    }
    __syncthreads();
    const int tc = tid & 31;
    const int tr = tid >> 5;
    float acc[8][8];
#pragma unroll
    for (int i = 0; i < 8; ++i)
#pragma unroll
        for (int j = 0; j < 8; ++j) acc[i][j] = 0.f;
#pragma unroll 2
    for (int k4 = 0; k4 < 32; ++k4) {
        float4 av[8];
#pragma unroll
        for (int i = 0; i < 8; ++i) av[i] = *(const float4*)&As[tr * 8 + i][k4 * 4];
#pragma unroll
        for (int j = 0; j < 4; ++j) {
            int k = k4 * 4 + j;
            float4 b0 = *(const float4*)&Wtc[k * 256 + tc * 8];
            float4 b1 = *(const float4*)&Wtc[k * 256 + tc * 8 + 4];
#pragma unroll
            for (int i = 0; i < 8; ++i) {
                float a = ((const float*)&av[i])[j];
                acc[i][0] = fmaf(a, b0.x, acc[i][0]);
                acc[i][1] = fmaf(a, b0.y, acc[i][1]);
                acc[i][2] = fmaf(a, b0.z, acc[i][2]);
                acc[i][3] = fmaf(a, b0.w, acc[i][3]);
                acc[i][4] = fmaf(a, b1.x, acc[i][4]);
                acc[i][5] = fmaf(a, b1.y, acc[i][5]);
                acc[i][6] = fmaf(a, b1.z, acc[i][6]);
                acc[i][7] = fmaf(a, b1.w, acc[i][7]);
            }
        }
    }
#pragma unroll
    for (int i = 0; i < 8; ++i) {
        int grow = block_row + tr * 8 + i;
        if (grow >= N_ENT_C) continue;
        float4 o0 = make_float4(acc[i][0], acc[i][1], acc[i][2], acc[i][3]);
        float4 o1 = make_float4(acc[i][4], acc[i][5], acc[i][6], acc[i][7]);
        if (tc < 16) {
            *(float4*)&Ps[grow * 128 + tc * 8] = o0;
            *(float4*)&Ps[grow * 128 + tc * 8 + 4] = o1;
        } else {
            *(float4*)&Pd[grow * 128 + (tc - 16) * 8] = o0;
            *(float4*)&Pd[grow * 128 + (tc - 16) * 8 + 4] = o1;
        }
    }
    // epilogue: qs/qd = dot(P row, a2w). 16 lanes per row-half, shfl tree.
    float w8[8];
    int baseo = (tc & 15) * 8;
#pragma unroll
    for (int j = 0; j < 8; ++j) w8[j] = a2w[baseo + j];
#pragma unroll
    for (int i = 0; i < 8; ++i) {
        float p = 0.f;
#pragma unroll
        for (int j = 0; j < 8; ++j) p = fmaf(acc[i][j], w8[j], p);
        p += __shfl_xor(p, 8);
        p += __shfl_xor(p, 4);
        p += __shfl_xor(p, 2);
        p += __shfl_xor(p, 1);
        if ((tc & 15) == 0) {
            int grow = block_row + tr * 8 + i;
            if (grow < N_ENT_C) {
                if (tc < 16) qs[grow] = p;
                else qd[grow] = p;
            }
        }
    }
}

// ---------------- edge histograms ----------------
__global__ void hist_edges(const int* __restrict__ src, const int* __restrict__ rel,
                           int* __restrict__ histSrc, int* __restrict__ histRel) {
    int e = blockIdx.x * 256 + threadIdx.x;
    if (e >= NEDGE_C) return;
    atomicAdd(&histSrc[src[e]], 1);
    atomicAdd(&histRel[rel[e]], 1);
}

__global__ void scan_blockred(const int* __restrict__ hist, int* __restrict__ blockSums, int n) {
    __shared__ int s[256];
    int tid = threadIdx.x;
    int i = blockIdx.x * 256 + tid;
    s[tid] = (i < n) ? hist[i] : 0;
    __syncthreads();
    for (int off = 128; off > 0; off >>= 1) {
        if (tid < off) s[tid] += s[tid + off];
        __syncthreads();
    }
    if (tid == 0) blockSums[blockIdx.x] = s[0];
}

__global__ void scan_single(int* __restrict__ data, int n) {
    __shared__ int a[1024], b2[1024];
    int tid = threadIdx.x;
    int v = (tid < n) ? data[tid] : 0;
    a[tid] = v;
    __syncthreads();
    int* cur = a; int* nxt = b2;
    for (int off = 1; off < 1024; off <<= 1) {
        int x = cur[tid] + ((tid >= off) ? cur[tid - off] : 0);
        nxt[tid] = x;
        __syncthreads();
        int* t = cur; cur = nxt; nxt = t;
    }
    if (tid < n) data[tid] = cur[tid] - v;   // exclusive
}

__global__ void scan_final(const int* __restrict__ hist, const int* __restrict__ blockOffs,
                           int* __restrict__ offs, int n) {
    __shared__ int a[256], b2[256];
    int tid = threadIdx.x;
    int i = blockIdx.x * 256 + tid;
    int v = (i < n) ? hist[i] : 0;
    a[tid] = v;
    __syncthreads();
    int* cur = a; int* nxt = b2;
    for (int off = 1; off < 256; off <<= 1) {
        int x = cur[tid] + ((tid >= off) ? cur[tid - off] : 0);
        nxt[tid] = x;
        __syncthreads();
        int* t = cur; cur = nxt; nxt = t;
    }
    if (i < n) offs[i] = cur[tid] - v + blockOffs[blockIdx.x];
}

__global__ void scatter_edges(const int* __restrict__ src, const int* __restrict__ dst,
                              const int* __restrict__ rel,
                              int* __restrict__ offsSrc, int* __restrict__ offsRel,
                              int* __restrict__ dstS, int* __restrict__ relS,
                              int* __restrict__ srcR, int* __restrict__ dstR) {
    int e = blockIdx.x * 256 + threadIdx.x;
    if (e >= NEDGE_C) return;
    int s = src[e], d = dst[e], r = rel[e];
    int p = atomicAdd(&offsSrc[s], 1);
    dstS[p] = d; relS[p] = r;
    int q = atomicAdd(&offsRel[r], 1);
    srcR[q] = s; dstR[q] = d;
}

// ---------------- rel phase: 8 partial blocks per relation ----------------
__global__ __launch_bounds__(256) void rel_phase(const float* __restrict__ Ps,
                                                 const float* __restrict__ Pd,
                                                 const float* __restrict__ qs,
                                                 const float* __restrict__ qd,
                                                 const float* __restrict__ qr,
                                                 const int* __restrict__ offsRel,
                                                 const int* __restrict__ srcR,
                                                 const int* __restrict__ dstR,
                                                 const float* __restrict__ a2b,
                                                 float* __restrict__ relpart) {
    int r = blockIdx.x >> 3;
    int p = blockIdx.x & 7;
    int start = (r == 0) ? 0 : offsRel[r - 1];
    int end = offsRel[r];
    int tid = threadIdx.x;
    int w = tid >> 6;          // wave 0..3
    int h = (tid >> 5) & 1;    // half-wave
    int l = tid & 31;          // lane in half: cols l*4..l*4+3
    int slot = p * 8 + w * 2 + h;   // 0..63
    float bb = a2b[0];
    float qrr = qr[r];
    float4 acc = make_float4(0.f, 0.f, 0.f, 0.f);
    float ebs = 0.f;
    for (int i = start + slot; i < end; i += 64) {
        int s = srcR[i], d = dstR[i];
        float b = qs[s] + qd[d] + qrr + bb;
        b = (b > 0.f) ? b : 0.01f * b;
        float eb = expf(b);
        float4 pv = *(const float4*)&Ps[s * 128 + l * 4];
        float4 dv = *(const float4*)&Pd[d * 128 + l * 4];
        acc.x = fmaf(eb, pv.x + dv.x, acc.x);
        acc.y = fmaf(eb, pv.y + dv.y, acc.y);
        acc.z = fmaf(eb, pv.z + dv.z, acc.z);
        acc.w = fmaf(eb, pv.w + dv.w, acc.w);
        ebs += eb;
    }
    __shared__ float vred[8][128];
    __shared__ float sred[8];
    int sub = w * 2 + h;
    *(float4*)&vred[sub][l * 4] = acc;
    if (l == 0) sred[sub] = ebs;
    __syncthreads();
    if (tid < 128) {
        float v = 0.f;
#pragma unroll
        for (int k2 = 0; k2 < 8; ++k2) v += vred[k2][tid];
        float e = 0.f;
#pragma unroll
        for (int k2 = 0; k2 < 8; ++k2) e += sred[k2];
        int pi = r * 8 + p;
        relpart[pi * 132 + tid] = v;
        if (tid == 0) relpart[pi * 132 + 128] = e;
    }
}

// ---------------- rel finalize: reduce 8 partials, add Pr term, mean, elu -----------
__global__ void rel_fin(const float* __restrict__ relpart, const float* __restrict__ Pr,
                        const int* __restrict__ offsRel, float* __restrict__ outRel) {
    int r = blockIdx.x;
    int o = threadIdx.x;
    float v = 0.f, e = 0.f;
#pragma unroll
    for (int p = 0; p < 8; ++p) {
        v += relpart[(r * 8 + p) * 132 + o];
        e += relpart[(r * 8 + p) * 132 + 128];
    }
    int start = (r == 0) ? 0 : offsRel[r - 1];
    float cnt = (float)(offsRel[r] - start);
    float h = (v + e * Pr[r * 128 + o]) / fmaxf(cnt, 1.f);
    outRel[r * 128 + o] = (h > 0.f) ? h : (expf(h) - 1.f);
}

// ---------------- src phase: one wave per node, 2 edges in flight ----------------
__global__ __launch_bounds__(256) void src_phase(float* __restrict__ Ps,
                                                 const float* __restrict__ Pd,
                                                 const float* __restrict__ Pr,
                                                 const float* __restrict__ qs,
                                                 const float* __restrict__ qd,
                                                 const float* __restrict__ qr,
                                                 const int* __restrict__ offsSrc,
                                                 const int* __restrict__ dstS,
                                                 const int* __restrict__ relS,
                                                 const float* __restrict__ a2b,
                                                 float* __restrict__ out) {
    int wid = (blockIdx.x * 256 + threadIdx.x) >> 6;
    if (wid >= N_ENT_C) return;
    int lane = threadIdx.x & 63;
    int h = lane >> 5, l = lane & 31;
    int s = wid;
    int start = (s == 0) ? 0 : offsSrc[s - 1];
    int end = offsSrc[s];
    float* dstp = (s < SCRATCH_ROWS) ? &Ps[(size_t)s * 128] : &out[(size_t)s * 128];
    if (end == start) {
        if (h == 0) *(float4*)&dstp[l * 4] = make_float4(0.f, 0.f, 0.f, 0.f);
        return;
    }
    float bb = a2b[0];
    float qss = qs[s];
    float4 acc = make_float4(0.f, 0.f, 0.f, 0.f);
    float ebs = 0.f;
    for (int i = start + h; i < end; i += 2) {
        int d = dstS[i], r = relS[i];
        float b = qss + qd[d] + qr[r] + bb;
        b = (b > 0.f) ? b : 0.01f * b;
        float eb = expf(b);
        float4 dv = *(const float4*)&Pd[d * 128 + l * 4];
        float4 rv = *(const float4*)&Pr[r * 128 + l * 4];
        acc.x = fmaf(eb, dv.x + rv.x, acc.x);
        acc.y = fmaf(eb, dv.y + rv.y, acc.y);
        acc.z = fmaf(eb, dv.z + rv.z, acc.z);
        acc.w = fmaf(eb, dv.w + rv.w, acc.w);
        ebs += eb;
    }
    acc.x += __shfl_xor(acc.x, 32);
    acc.y += __shfl_xor(acc.y, 32);
    acc.z += __shfl_xor(acc.z, 32);
    acc.w += __shfl_xor(acc.w, 32);
    ebs += __shfl_xor(ebs, 32);
    float inv = 1.f / ebs;
    float4 ps4 = *(const float4*)&Ps[(size_t)s * 128 + l * 4];
    float hx = ps4.x + acc.x * inv;
    float hy = ps4.y + acc.y * inv;
    float hz = ps4.z + acc.z * inv;
    float hw = ps4.w + acc.w * inv;
    hx = (hx > 0.f) ? hx : (expf(hx) - 1.f);
    hy = (hy > 0.f) ? hy : (expf(hy) - 1.f);
    hz = (hz > 0.f) ? hz : (expf(hz) - 1.f);
    hw = (hw > 0.f) ? hw : (expf(hw) - 1.f);
    if (h == 0) *(float4*)&dstp[l * 4] = make_float4(hx, hy, hz, hw);
}

extern "C" void kernel_launch(void* const* d_in, const int* in_sizes, int n_in,
                              void* d_out, int out_size, void* d_ws, size_t ws_size,
                              hipStream_t stream) {
    const float* ent  = (const float*)d_in[0];
    const float* rele = (const float*)d_in[1];
    const float* aw   = (const float*)d_in[2];
    const float* ab   = (const float*)d_in[3];
    const float* a2w  = (const float*)d_in[4];
    const float* a2b  = (const float*)d_in[5];
    const int* src    = (const int*)d_in[6];
    const int* dst    = (const int*)d_in[7];
    const int* rel    = (const int*)d_in[8];
    float* out = (float*)d_out;

    float* ws = (float*)d_ws;
    float* Wtc = ws + OFF_WTC;
    float* Wtr = ws + OFF_WTR;
    float* Pr  = ws + OFF_PR;
    float* Ps  = ws + OFF_PS;
    float* Pd  = ws + OFF_PD;

    // d_out entity region doubles as scratch until the final copy
    int* dI = (int*)d_out;
    int* histSrc = dI + DO_HSRC;
    int* offsSrc = dI + DO_OSRC;
    int* offsRel = dI + DO_HREL;
    int* bsum    = dI + DO_BSUM;
    int* dstS    = dI + DO_DSTS;
    int* relS    = dI + DO_RELS;
    int* srcR    = dI + DO_SRCR;
    int* dstR    = dI + DO_DSTR;
    float* relpart = (float*)dI + DO_RELP;
    float* qs    = (float*)dI + DO_QS;
    float* qd    = (float*)dI + DO_QD;
    float* qr    = (float*)dI + DO_QR;

    hipMemsetAsync(dI, 0, (size_t)(DO_BSUM + 512) * sizeof(int), stream);

    prep_w<<<192, 256, 0, stream>>>(aw, Wtc, Wtr);
    rel_proj<<<N_REL_C, 128, 0, stream>>>(rele, Wtr, ab, a2w, Pr, qr);
    ent_proj<<<(N_ENT_C + 63) / 64, 256, 0, stream>>>(ent, Wtc, a2w, Ps, Pd, qs, qd);

    hist_edges<<<(NEDGE_C + 255) / 256, 256, 0, stream>>>(src, rel, histSrc, offsRel);
    scan_blockred<<<SCAN_BLOCKS, 256, 0, stream>>>(histSrc, bsum, N_ENT_C);
    scan_single<<<1, 1024, 0, stream>>>(bsum, SCAN_BLOCKS);
    scan_final<<<SCAN_BLOCKS, 256, 0, stream>>>(histSrc, bsum, offsSrc, N_ENT_C);
    scan_single<<<1, 1024, 0, stream>>>(offsRel, N_REL_C);
    scatter_edges<<<(NEDGE_C + 255) / 256, 256, 0, stream>>>(src, dst, rel, offsSrc, offsRel,
                                                             dstS, relS, srcR, dstR);

    rel_phase<<<N_REL_C * 8, 256, 0, stream>>>(Ps, Pd, qs, qd, qr, offsRel, srcR, dstR,
                                               a2b, relpart);
    rel_fin<<<N_REL_C, 128, 0, stream>>>(relpart, Pr, offsRel, out + (size_t)N_ENT_C * 128);

    src_phase<<<(N_ENT_C + 3) / 4, 256, 0, stream>>>(Ps, Pd, Pr, qs, qd, qr,
                                                     offsSrc, dstS, relS, a2b, out);

    // copy scratch-overlapped entity rows (rest written directly by src_phase)
    hipMemcpyAsync(out, Ps, (size_t)SCRATCH_ROWS * 128 * sizeof(float),
                   hipMemcpyDeviceToDevice, stream);
}

// Round 4
// 372.896 us; speedup vs baseline: 2.8237x; 1.7091x over previous
//
#include <hip/hip_runtime.h>
#include <hip/hip_bf16.h>

#define N_ENT_C 100000
#define N_REL_C 500
#define NEDGE_C 500000
#define SCAN_BLOCKS 391   // ceil(100000/256)
#define EPB 1024          // edges per block for rel sort
#define NB_EDGE 489       // ceil(500000/1024)
#define CHUNK_B 62        // ceil(489/8)

// ---------------- ws layout (float offsets) — identical footprint to round 2/3 --------
#define OFF_WTC   0
#define OFF_WTR   32768
#define OFF_PR    49152
#define OFF_PS    113152
#define OFF_PD    12913152
// end = 25,713,152 floats = 102.85 MB

// ---------------- d_out scratch layout (int/float offsets; dead until final copy) -----
#define DO_HSRC     0         // histSrc   [100000]
#define DO_OSRC     100000    // offsSrc   [100000]
#define DO_BSUM     200000    // blockSums [512]
#define DO_RELSTART 200512    // relStart  [512]  (exclusive scan of rel totals)
#define DO_PART8    201024    // partial   [8][512]
#define DO_CHUNKOFF 205120    // chunkOff  [8][512]
#define DO_BLKHIST  209216    // blkHist   [489][512]
#define DO_BLKOFFS  459584    // blockOffs [489][512]
#define DO_DSTS     709952    // dstS [500000]
#define DO_RELS     1209952   // relS [500000]
#define DO_SRCR     1709952   // srcR [500000]
#define DO_DSTR     2209952   // dstR [500000]
#define DO_RELP     2709952   // relpart [4000][132] = 528000
#define DO_QS       3237952   // qs [100000]
#define DO_QD       3337952   // qd [100000]
#define DO_QR       3437952   // qr [512]
// end = 3,438,464 ints -> SCRATCH_ROWS = ceil(/128) = 26863
#define SCRATCH_ROWS 26863

// ---------------- weight transpose ----------------
__global__ void prep_w(const float* __restrict__ aw, float* __restrict__ Wtc,
                       float* __restrict__ Wtr) {
    int idx = blockIdx.x * 256 + threadIdx.x;   // 0..49151
    if (idx < 128 * 256) {
        int k = idx >> 8, o = idx & 255;
        float v = (o < 128) ? aw[o * 384 + k] : aw[(o - 128) * 384 + 128 + k];
        Wtc[idx] = v;
    } else if (idx < 128 * 384) {
        int t = idx - 32768;
        int k = t >> 7, o = t & 127;
        Wtr[t] = aw[o * 384 + 256 + k];
    }
}

// ---------------- rel projection + qr epilogue ----------------
__global__ void rel_proj(const float* __restrict__ rele, const float* __restrict__ Wtr,
                         const float* __restrict__ ab, const float* __restrict__ a2w,
                         float* __restrict__ Pr, float* __restrict__ qr) {
    int r = blockIdx.x;
    int o = threadIdx.x;
    float acc = ab[o];
    for (int k = 0; k < 128; ++k)
        acc = fmaf(rele[r * 128 + k], Wtr[k * 128 + o], acc);
    Pr[r * 128 + o] = acc;
    __shared__ float red[128];
    red[o] = acc * a2w[o];
    __syncthreads();
    for (int off = 64; off > 0; off >>= 1) {
        if (o < off) red[o] += red[o + off];
        __syncthreads();
    }
    if (o == 0) qr[r] = red[0];
}

// ---------------- ent projection + qs/qd epilogue ----------------
__global__ __launch_bounds__(256) void ent_proj(const float* __restrict__ ent,
                                                const float* __restrict__ Wtc,
                                                const float* __restrict__ a2w,
                                                float* __restrict__ Ps,
                                                float* __restrict__ Pd,
                                                float* __restrict__ qs,
                                                float* __restrict__ qd) {
    __shared__ float As[64][128];
    const int tid = threadIdx.x;
    const int block_row = blockIdx.x * 64;
#pragma unroll
    for (int i = 0; i < 8; ++i) {
        int f = tid + i * 256;
        int m = f >> 5, k4 = f & 31;
        float4 v = make_float4(0.f, 0.f, 0.f, 0.f);
        int grow = block_row + m;
        if (grow < N_ENT_C) v = *(const float4*)&ent[grow * 128 + k4 * 4];
        *(float4*)&As[m][k4 * 4] = v;
    }
    __syncthreads();
    const int tc = tid & 31;
    const int tr = tid >> 5;
    float acc[8][8];
#pragma unroll
    for (int i = 0; i < 8; ++i)
#pragma unroll
        for (int j = 0; j < 8; ++j) acc[i][j] = 0.f;
#pragma unroll 2
    for (int k4 = 0; k4 < 32; ++k4) {
        float4 av[8];
#pragma unroll
        for (int i = 0; i < 8; ++i) av[i] = *(const float4*)&As[tr * 8 + i][k4 * 4];
#pragma unroll
        for (int j = 0; j < 4; ++j) {
            int k = k4 * 4 + j;
            float4 b0 = *(const float4*)&Wtc[k * 256 + tc * 8];
            float4 b1 = *(const float4*)&Wtc[k * 256 + tc * 8 + 4];
#pragma unroll
            for (int i = 0; i < 8; ++i) {
                float a = ((const float*)&av[i])[j];
                acc[i][0] = fmaf(a, b0.x, acc[i][0]);
                acc[i][1] = fmaf(a, b0.y, acc[i][1]);
                acc[i][2] = fmaf(a, b0.z, acc[i][2]);
                acc[i][3] = fmaf(a, b0.w, acc[i][3]);
                acc[i][4] = fmaf(a, b1.x, acc[i][4]);
                acc[i][5] = fmaf(a, b1.y, acc[i][5]);
                acc[i][6] = fmaf(a, b1.z, acc[i][6]);
                acc[i][7] = fmaf(a, b1.w, acc[i][7]);
            }
        }
    }
#pragma unroll
    for (int i = 0; i < 8; ++i) {
        int grow = block_row + tr * 8 + i;
        if (grow >= N_ENT_C) continue;
        float4 o0 = make_float4(acc[i][0], acc[i][1], acc[i][2], acc[i][3]);
        float4 o1 = make_float4(acc[i][4], acc[i][5], acc[i][6], acc[i][7]);
        if (tc < 16) {
            *(float4*)&Ps[grow * 128 + tc * 8] = o0;
            *(float4*)&Ps[grow * 128 + tc * 8 + 4] = o1;
        } else {
            *(float4*)&Pd[grow * 128 + (tc - 16) * 8] = o0;
            *(float4*)&Pd[grow * 128 + (tc - 16) * 8 + 4] = o1;
        }
    }
    // epilogue: qs/qd = dot(P row, a2w)
    float w8[8];
    int baseo = (tc & 15) * 8;
#pragma unroll
    for (int j = 0; j < 8; ++j) w8[j] = a2w[baseo + j];
#pragma unroll
    for (int i = 0; i < 8; ++i) {
        float p = 0.f;
#pragma unroll
        for (int j = 0; j < 8; ++j) p = fmaf(acc[i][j], w8[j], p);
        p += __shfl_xor(p, 8);
        p += __shfl_xor(p, 4);
        p += __shfl_xor(p, 2);
        p += __shfl_xor(p, 1);
        if ((tc & 15) == 0) {
            int grow = block_row + tr * 8 + i;
            if (grow < N_ENT_C) {
                if (tc < 16) qs[grow] = p;
                else qd[grow] = p;
            }
        }
    }
}

// ---------------- rel-key block histogram (LDS) + src global hist ----------------
__global__ __launch_bounds__(256) void edge_hist(const int* __restrict__ src,
                                                 const int* __restrict__ rel,
                                                 int* __restrict__ histSrc,
                                                 int* __restrict__ blkHist) {
    __shared__ int lh[512];
    int tid = threadIdx.x;
    lh[tid] = 0; lh[tid + 256] = 0;
    __syncthreads();
    int base = blockIdx.x * EPB;
#pragma unroll
    for (int j = 0; j < 4; ++j) {
        int e = base + j * 256 + tid;
        if (e < NEDGE_C) {
            atomicAdd(&histSrc[src[e]], 1);
            atomicAdd(&lh[rel[e]], 1);
        }
    }
    __syncthreads();
    blkHist[blockIdx.x * 512 + tid] = lh[tid];
    blkHist[blockIdx.x * 512 + 256 + tid] = lh[tid + 256];
}

// ---------------- per-chunk column sums of blkHist ----------------
__global__ void colsum(const int* __restrict__ blkHist, int* __restrict__ partial) {
    int r = threadIdx.x;          // 0..511
    int k = blockIdx.x;           // chunk 0..7
    int b0 = k * CHUNK_B;
    int b1 = min(b0 + CHUNK_B, NB_EDGE);
    int t = 0;
    for (int b = b0; b < b1; ++b) t += blkHist[b * 512 + r];
    partial[k * 512 + r] = t;
}

// ---------------- totals scan + per-chunk column offsets ----------------
__global__ void scan512(const int* __restrict__ partial, int* __restrict__ relStart,
                        int* __restrict__ chunkOff) {
    __shared__ int a[512], b2[512];
    int tid = threadIdx.x;
    int p8[8];
    int t = 0;
#pragma unroll
    for (int k = 0; k < 8; ++k) { p8[k] = partial[k * 512 + tid]; t += p8[k]; }
    a[tid] = t;
    __syncthreads();
    int v = t;
    int* cur = a; int* nxt = b2;
    for (int off = 1; off < 512; off <<= 1) {
        int x = cur[tid] + ((tid >= off) ? cur[tid - off] : 0);
        nxt[tid] = x;
        __syncthreads();
        int* tmp = cur; cur = nxt; nxt = tmp;
    }
    int excl = cur[tid] - v;
    relStart[tid] = excl;
    int run = excl;
#pragma unroll
    for (int k = 0; k < 8; ++k) { chunkOff[k * 512 + tid] = run; run += p8[k]; }
}

// ---------------- per-block column offsets within each chunk ----------------
__global__ void colscan(const int* __restrict__ blkHist, const int* __restrict__ chunkOff,
                        int* __restrict__ blockOffs) {
    int r = threadIdx.x;
    int k = blockIdx.x;
    int b0 = k * CHUNK_B;
    int b1 = min(b0 + CHUNK_B, NB_EDGE);
    int off = chunkOff[k * 512 + r];
    for (int b = b0; b < b1; ++b) {
        blockOffs[b * 512 + r] = off;
        off += blkHist[b * 512 + r];
    }
}

// ---------------- src scan (unchanged) ----------------
__global__ void scan_blockred(const int* __restrict__ hist, int* __restrict__ blockSums, int n) {
    __shared__ int s[256];
    int tid = threadIdx.x;
    int i = blockIdx.x * 256 + tid;
    s[tid] = (i < n) ? hist[i] : 0;
    __syncthreads();
    for (int off = 128; off > 0; off >>= 1) {
        if (tid < off) s[tid] += s[tid + off];
        __syncthreads();
    }
    if (tid == 0) blockSums[blockIdx.x] = s[0];
}

__global__ void scan_single(int* __restrict__ data, int n) {
    __shared__ int a[1024], b2[1024];
    int tid = threadIdx.x;
    int v = (tid < n) ? data[tid] : 0;
    a[tid] = v;
    __syncthreads();
    int* cur = a; int* nxt = b2;
    for (int off = 1; off < 1024; off <<= 1) {
        int x = cur[tid] + ((tid >= off) ? cur[tid - off] : 0);
        nxt[tid] = x;
        __syncthreads();
        int* t = cur; cur = nxt; nxt = t;
    }
    if (tid < n) data[tid] = cur[tid] - v;   // exclusive
}

__global__ void scan_final(const int* __restrict__ hist, const int* __restrict__ blockOffs,
                           int* __restrict__ offs, int n) {
    __shared__ int a[256], b2[256];
    int tid = threadIdx.x;
    int i = blockIdx.x * 256 + tid;
    int v = (i < n) ? hist[i] : 0;
    a[tid] = v;
    __syncthreads();
    int* cur = a; int* nxt = b2;
    for (int off = 1; off < 256; off <<= 1) {
        int x = cur[tid] + ((tid >= off) ? cur[tid - off] : 0);
        nxt[tid] = x;
        __syncthreads();
        int* t = cur; cur = nxt; nxt = t;
    }
    if (i < n) offs[i] = cur[tid] - v + blockOffs[blockIdx.x];
}

// ---------------- scatter: src via low-contention atomic, rel via LDS replay ----------
__global__ __launch_bounds__(256) void scatter_both(const int* __restrict__ src,
                                                    const int* __restrict__ dst,
                                                    const int* __restrict__ rel,
                                                    int* __restrict__ offsSrc,
                                                    const int* __restrict__ blockOffs,
                                                    int* __restrict__ dstS, int* __restrict__ relS,
                                                    int* __restrict__ srcR, int* __restrict__ dstR) {
    __shared__ int lh[512];
    int tid = threadIdx.x;
    lh[tid] = 0; lh[tid + 256] = 0;
    __syncthreads();
    int base = blockIdx.x * EPB;
    const int* bo = &blockOffs[blockIdx.x * 512];
#pragma unroll
    for (int j = 0; j < 4; ++j) {
        int e = base + j * 256 + tid;
        if (e < NEDGE_C) {
            int s = src[e], d = dst[e], r = rel[e];
            int p = atomicAdd(&offsSrc[s], 1);
            dstS[p] = d; relS[p] = r;
            int lr = atomicAdd(&lh[r], 1);
            int q = bo[r] + lr;
            srcR[q] = s; dstR[q] = d;
        }
    }
}

// ---------------- rel phase: 8 partial blocks per relation ----------------
__global__ __launch_bounds__(256) void rel_phase(const float* __restrict__ Ps,
                                                 const float* __restrict__ Pd,
                                                 const float* __restrict__ qs,
                                                 const float* __restrict__ qd,
                                                 const float* __restrict__ qr,
                                                 const int* __restrict__ relStart,
                                                 const int* __restrict__ srcR,
                                                 const int* __restrict__ dstR,
                                                 const float* __restrict__ a2b,
                                                 float* __restrict__ relpart) {
    int r = blockIdx.x >> 3;
    int p = blockIdx.x & 7;
    int start = relStart[r];
    int end = relStart[r + 1];
    int tid = threadIdx.x;
    int w = tid >> 6;
    int h = (tid >> 5) & 1;
    int l = tid & 31;
    int slot = p * 8 + w * 2 + h;
    float bb = a2b[0];
    float qrr = qr[r];
    float4 acc = make_float4(0.f, 0.f, 0.f, 0.f);
    float ebs = 0.f;
    for (int i = start + slot; i < end; i += 64) {
        int s = srcR[i], d = dstR[i];
        float b = qs[s] + qd[d] + qrr + bb;
        b = (b > 0.f) ? b : 0.01f * b;
        float eb = expf(b);
        float4 pv = *(const float4*)&Ps[s * 128 + l * 4];
        float4 dv = *(const float4*)&Pd[d * 128 + l * 4];
        acc.x = fmaf(eb, pv.x + dv.x, acc.x);
        acc.y = fmaf(eb, pv.y + dv.y, acc.y);
        acc.z = fmaf(eb, pv.z + dv.z, acc.z);
        acc.w = fmaf(eb, pv.w + dv.w, acc.w);
        ebs += eb;
    }
    __shared__ float vred[8][128];
    __shared__ float sred[8];
    int sub = w * 2 + h;
    *(float4*)&vred[sub][l * 4] = acc;
    if (l == 0) sred[sub] = ebs;
    __syncthreads();
    if (tid < 128) {
        float v = 0.f;
#pragma unroll
        for (int k2 = 0; k2 < 8; ++k2) v += vred[k2][tid];
        float e = 0.f;
#pragma unroll
        for (int k2 = 0; k2 < 8; ++k2) e += sred[k2];
        int pi = r * 8 + p;
        relpart[pi * 132 + tid] = v;
        if (tid == 0) relpart[pi * 132 + 128] = e;
    }
}

// ---------------- rel finalize ----------------
__global__ void rel_fin(const float* __restrict__ relpart, const float* __restrict__ Pr,
                        const int* __restrict__ relStart, float* __restrict__ outRel) {
    int r = blockIdx.x;
    int o = threadIdx.x;
    float v = 0.f, e = 0.f;
#pragma unroll
    for (int p = 0; p < 8; ++p) {
        v += relpart[(r * 8 + p) * 132 + o];
        e += relpart[(r * 8 + p) * 132 + 128];
    }
    float cnt = (float)(relStart[r + 1] - relStart[r]);
    float h = (v + e * Pr[r * 128 + o]) / fmaxf(cnt, 1.f);
    outRel[r * 128 + o] = (h > 0.f) ? h : (expf(h) - 1.f);
}

// ---------------- src phase ----------------
__global__ __launch_bounds__(256) void src_phase(float* __restrict__ Ps,
                                                 const float* __restrict__ Pd,
                                                 const float* __restrict__ Pr,
                                                 const float* __restrict__ qs,
                                                 const float* __restrict__ qd,
                                                 const float* __restrict__ qr,
                                                 const int* __restrict__ offsSrc,
                                                 const int* __restrict__ dstS,
                                                 const int* __restrict__ relS,
                                                 const float* __restrict__ a2b,
                                                 float* __restrict__ out) {
    int wid = (blockIdx.x * 256 + threadIdx.x) >> 6;
    if (wid >= N_ENT_C) return;
    int lane = threadIdx.x & 63;
    int h = lane >> 5, l = lane & 31;
    int s = wid;
    int start = (s == 0) ? 0 : offsSrc[s - 1];
    int end = offsSrc[s];
    float* dstp = (s < SCRATCH_ROWS) ? &Ps[(size_t)s * 128] : &out[(size_t)s * 128];
    if (end == start) {
        if (h == 0) *(float4*)&dstp[l * 4] = make_float4(0.f, 0.f, 0.f, 0.f);
        return;
    }
    float bb = a2b[0];
    float qss = qs[s];
    float4 acc = make_float4(0.f, 0.f, 0.f, 0.f);
    float ebs = 0.f;
    for (int i = start + h; i < end; i += 2) {
        int d = dstS[i], r = relS[i];
        float b = qss + qd[d] + qr[r] + bb;
        b = (b > 0.f) ? b : 0.01f * b;
        float eb = expf(b);
        float4 dv = *(const float4*)&Pd[d * 128 + l * 4];
        float4 rv = *(const float4*)&Pr[r * 128 + l * 4];
        acc.x = fmaf(eb, dv.x + rv.x, acc.x);
        acc.y = fmaf(eb, dv.y + rv.y, acc.y);
        acc.z = fmaf(eb, dv.z + rv.z, acc.z);
        acc.w = fmaf(eb, dv.w + rv.w, acc.w);
        ebs += eb;
    }
    acc.x += __shfl_xor(acc.x, 32);
    acc.y += __shfl_xor(acc.y, 32);
    acc.z += __shfl_xor(acc.z, 32);
    acc.w += __shfl_xor(acc.w, 32);
    ebs += __shfl_xor(ebs, 32);
    float inv = 1.f / ebs;
    float4 ps4 = *(const float4*)&Ps[(size_t)s * 128 + l * 4];
    float hx = ps4.x + acc.x * inv;
    float hy = ps4.y + acc.y * inv;
    float hz = ps4.z + acc.z * inv;
    float hw = ps4.w + acc.w * inv;
    hx = (hx > 0.f) ? hx : (expf(hx) - 1.f);
    hy = (hy > 0.f) ? hy : (expf(hy) - 1.f);
    hz = (hz > 0.f) ? hz : (expf(hz) - 1.f);
    hw = (hw > 0.f) ? hw : (expf(hw) - 1.f);
    if (h == 0) *(float4*)&dstp[l * 4] = make_float4(hx, hy, hz, hw);
}

extern "C" void kernel_launch(void* const* d_in, const int* in_sizes, int n_in,
                              void* d_out, int out_size, void* d_ws, size_t ws_size,
                              hipStream_t stream) {
    const float* ent  = (const float*)d_in[0];
    const float* rele = (const float*)d_in[1];
    const float* aw   = (const float*)d_in[2];
    const float* ab   = (const float*)d_in[3];
    const float* a2w  = (const float*)d_in[4];
    const float* a2b  = (const float*)d_in[5];
    const int* src    = (const int*)d_in[6];
    const int* dst    = (const int*)d_in[7];
    const int* rel    = (const int*)d_in[8];
    float* out = (float*)d_out;

    float* ws = (float*)d_ws;
    float* Wtc = ws + OFF_WTC;
    float* Wtr = ws + OFF_WTR;
    float* Pr  = ws + OFF_PR;
    float* Ps  = ws + OFF_PS;
    float* Pd  = ws + OFF_PD;

    int* dI = (int*)d_out;
    int* histSrc  = dI + DO_HSRC;
    int* offsSrc  = dI + DO_OSRC;
    int* bsum     = dI + DO_BSUM;
    int* relStart = dI + DO_RELSTART;
    int* part8    = dI + DO_PART8;
    int* chunkOff = dI + DO_CHUNKOFF;
    int* blkHist  = dI + DO_BLKHIST;
    int* blockOffs= dI + DO_BLKOFFS;
    int* dstS     = dI + DO_DSTS;
    int* relS     = dI + DO_RELS;
    int* srcR     = dI + DO_SRCR;
    int* dstR     = dI + DO_DSTR;
    float* relpart = (float*)dI + DO_RELP;
    float* qs     = (float*)dI + DO_QS;
    float* qd     = (float*)dI + DO_QD;
    float* qr     = (float*)dI + DO_QR;

    // zero only histSrc (everything else fully overwritten before read)
    hipMemsetAsync(histSrc, 0, (size_t)N_ENT_C * sizeof(int), stream);

    prep_w<<<192, 256, 0, stream>>>(aw, Wtc, Wtr);
    rel_proj<<<N_REL_C, 128, 0, stream>>>(rele, Wtr, ab, a2w, Pr, qr);
    ent_proj<<<(N_ENT_C + 63) / 64, 256, 0, stream>>>(ent, Wtc, a2w, Ps, Pd, qs, qd);

    edge_hist<<<NB_EDGE, 256, 0, stream>>>(src, rel, histSrc, blkHist);
    colsum<<<8, 512, 0, stream>>>(blkHist, part8);
    scan512<<<1, 512, 0, stream>>>(part8, relStart, chunkOff);
    colscan<<<8, 512, 0, stream>>>(blkHist, chunkOff, blockOffs);
    scan_blockred<<<SCAN_BLOCKS, 256, 0, stream>>>(histSrc, bsum, N_ENT_C);
    scan_single<<<1, 1024, 0, stream>>>(bsum, SCAN_BLOCKS);
    scan_final<<<SCAN_BLOCKS, 256, 0, stream>>>(histSrc, bsum, offsSrc, N_ENT_C);
    scatter_both<<<NB_EDGE, 256, 0, stream>>>(src, dst, rel, offsSrc, blockOffs,
                                              dstS, relS, srcR, dstR);

    rel_phase<<<N_REL_C * 8, 256, 0, stream>>>(Ps, Pd, qs, qd, qr, relStart, srcR, dstR,
                                               a2b, relpart);
    rel_fin<<<N_REL_C, 128, 0, stream>>>(relpart, Pr, relStart, out + (size_t)N_ENT_C * 128);

    src_phase<<<(N_ENT_C + 3) / 4, 256, 0, stream>>>(Ps, Pd, Pr, qs, qd, qr,
                                                     offsSrc, dstS, relS, a2b, out);

    hipMemcpyAsync(out, Ps, (size_t)SCRATCH_ROWS * 128 * sizeof(float),
                   hipMemcpyDeviceToDevice, stream);
}

// Round 5
// 312.461 us; speedup vs baseline: 3.3699x; 1.1934x over previous
//
#include <hip/hip_runtime.h>
#include <hip/hip_bf16.h>

#define N_ENT_C 100000
#define N_REL_C 500
#define NEDGE_C 500000
#define SCAN_BLOCKS 391   // ceil(100000/256)
#define EPB 1024          // edges per block for rel sort
#define NB_EDGE 489       // ceil(500000/1024)
#define CHUNK_B 62        // ceil(489/8)

// ---------------- ws layout (float offsets) — same footprint as rounds 2-4 ------------
#define OFF_WTHI  0         // Wt hi bf16 [256][128] = 32768 u16 = 16384 f32 slots
#define OFF_WTLO  16384     // Wt lo bf16 [256][128]
#define OFF_WTR   32768     // Wtr f32 [128][128]
#define OFF_PR    49152
#define OFF_PS    113152
#define OFF_PD    12913152
// end = 25,713,152 floats = 102.85 MB

// ---------------- d_out scratch layout (dead until final copy) ------------------------
#define DO_HSRC     0
#define DO_OSRC     100000
#define DO_BSUM     200000
#define DO_RELSTART 200512
#define DO_PART8    201024
#define DO_CHUNKOFF 205120
#define DO_BLKHIST  209216
#define DO_BLKOFFS  459584
#define DO_DSTS     709952
#define DO_RELS     1209952
#define DO_SRCR     1709952
#define DO_DSTR     2209952
#define DO_RELP     2709952
#define DO_QS       3237952
#define DO_QD       3337952
#define DO_QR       3437952
#define SCRATCH_ROWS 26863

typedef short bf16x8 __attribute__((ext_vector_type(8)));   // 8 bf16 in 4 VGPRs
typedef short s16x4  __attribute__((ext_vector_type(4)));
typedef float f32x4  __attribute__((ext_vector_type(4)));

__device__ inline unsigned short bf_rne(float x) {
    unsigned int u = __float_as_uint(x);
    u += 0x7FFF + ((u >> 16) & 1);          // round-nearest-even
    return (unsigned short)(u >> 16);
}
__device__ inline float bf2f(unsigned short h) {
    return __uint_as_float(((unsigned int)h) << 16);
}

// ---------------- weight prep: Wt (transposed by n, k contiguous) as bf16 hi/lo -------
__global__ void prep_w(const float* __restrict__ aw, unsigned short* __restrict__ Wthi,
                       unsigned short* __restrict__ Wtlo, float* __restrict__ Wtr) {
    int idx = blockIdx.x * 256 + threadIdx.x;   // 0..49151
    if (idx < 32768) {
        int n = idx >> 7, k = idx & 127;
        float v = (n < 128) ? aw[n * 384 + k] : aw[(n - 128) * 384 + 128 + k];
        unsigned short h = bf_rne(v);
        Wthi[idx] = h;
        Wtlo[idx] = bf_rne(v - bf2f(h));
    } else if (idx < 49152) {
        int t = idx - 32768;
        int k = t >> 7, o = t & 127;
        Wtr[t] = aw[o * 384 + 256 + k];
    }
}

// ---------------- rel projection + qr epilogue (f32, tiny) ----------------
__global__ void rel_proj(const float* __restrict__ rele, const float* __restrict__ Wtr,
                         const float* __restrict__ ab, const float* __restrict__ a2w,
                         float* __restrict__ Pr, float* __restrict__ qr) {
    int r = blockIdx.x;
    int o = threadIdx.x;
    float acc = ab[o];
    for (int k = 0; k < 128; ++k)
        acc = fmaf(rele[r * 128 + k], Wtr[k * 128 + o], acc);
    Pr[r * 128 + o] = acc;
    __shared__ float red[128];
    red[o] = acc * a2w[o];
    __syncthreads();
    for (int off = 64; off > 0; off >>= 1) {
        if (o < off) red[o] += red[o + off];
        __syncthreads();
    }
    if (o == 0) qr[r] = red[0];
}

// ---------------- ent projection via MFMA bf16 hi/lo split ----------------
// Block: 64 rows x 256 cols (Ps 0-127, Pd 128-255). 4 waves, wave w -> cols w*64..w*64+63.
__global__ __launch_bounds__(256) void ent_mfma(const float* __restrict__ ent,
                                                const unsigned short* __restrict__ Wthi,
                                                const unsigned short* __restrict__ Wtlo,
                                                const float* __restrict__ a2w,
                                                float* __restrict__ Ps,
                                                float* __restrict__ Pd,
                                                float* __restrict__ qs,
                                                float* __restrict__ qd) {
    __shared__ __align__(16) char sh[32768];    // A hi [0,16K), A lo [16K,32K), bf16, XOR-swizzled
    __shared__ float qred[4][64];
    const int tid = threadIdx.x;
    const int block_row = blockIdx.x * 64;

    // stage A tile: 64 rows x 128 k, f32 -> bf16 hi/lo into LDS
#pragma unroll
    for (int i = 0; i < 8; ++i) {
        int f = tid + i * 256;          // float4 slot
        int m = f >> 5, k4 = f & 31;
        float4 v = make_float4(0.f, 0.f, 0.f, 0.f);
        int grow = block_row + m;
        if (grow < N_ENT_C) v = *(const float4*)&ent[(size_t)grow * 128 + k4 * 4];
        unsigned short h0 = bf_rne(v.x), h1 = bf_rne(v.y), h2 = bf_rne(v.z), h3 = bf_rne(v.w);
        s16x4 hv; hv[0] = (short)h0; hv[1] = (short)h1; hv[2] = (short)h2; hv[3] = (short)h3;
        s16x4 lv;
        lv[0] = (short)bf_rne(v.x - bf2f(h0));
        lv[1] = (short)bf_rne(v.y - bf2f(h1));
        lv[2] = (short)bf_rne(v.z - bf2f(h2));
        lv[3] = (short)bf_rne(v.w - bf2f(h3));
        int off = m * 256 + k4 * 8;             // byte offset in 64x128 bf16 tile
        off ^= (m & 7) << 4;                    // bank-conflict swizzle
        *(s16x4*)(sh + off) = hv;
        *(s16x4*)(sh + 16384 + off) = lv;
    }
    __syncthreads();

    const int w = tid >> 6, lane = tid & 63;
    const int l15 = lane & 15, lh = lane >> 4;
    const int n0 = w * 64;

    f32x4 zz = {0.f, 0.f, 0.f, 0.f};
    f32x4 acc[4][4];
#pragma unroll
    for (int mf = 0; mf < 4; ++mf)
#pragma unroll
        for (int nf = 0; nf < 4; ++nf) acc[mf][nf] = zz;

#pragma unroll
    for (int ks = 0; ks < 4; ++ks) {
        int kb = ks * 32 + lh * 8;              // k element offset (8 contiguous bf16)
        bf16x8 ah[4], al[4];
#pragma unroll
        for (int mf = 0; mf < 4; ++mf) {
            int row = mf * 16 + l15;
            int off = row * 256 + kb * 2;
            off ^= (row & 7) << 4;
            ah[mf] = *(const bf16x8*)(sh + off);
            al[mf] = *(const bf16x8*)(sh + 16384 + off);
        }
#pragma unroll
        for (int nf = 0; nf < 4; ++nf) {
            int n = n0 + nf * 16 + l15;
            bf16x8 bh = *(const bf16x8*)(Wthi + n * 128 + kb);
            bf16x8 bl = *(const bf16x8*)(Wtlo + n * 128 + kb);
#pragma unroll
            for (int mf = 0; mf < 4; ++mf) {
                acc[mf][nf] = __builtin_amdgcn_mfma_f32_16x16x32_bf16(ah[mf], bh, acc[mf][nf], 0, 0, 0);
                acc[mf][nf] = __builtin_amdgcn_mfma_f32_16x16x32_bf16(ah[mf], bl, acc[mf][nf], 0, 0, 0);
                acc[mf][nf] = __builtin_amdgcn_mfma_f32_16x16x32_bf16(al[mf], bh, acc[mf][nf], 0, 0, 0);
            }
        }
    }

    // C write (col = lane&15, row = (lane>>4)*4 + reg — verified m89/m91) + q partials
    float a2[4];
#pragma unroll
    for (int nf = 0; nf < 4; ++nf) a2[nf] = a2w[(n0 + nf * 16 + l15) & 127];
    float qp[4][4];
#pragma unroll
    for (int mf = 0; mf < 4; ++mf)
#pragma unroll
        for (int v = 0; v < 4; ++v) qp[mf][v] = 0.f;

#pragma unroll
    for (int mf = 0; mf < 4; ++mf) {
#pragma unroll
        for (int nf = 0; nf < 4; ++nf) {
            int col = n0 + nf * 16 + l15;
#pragma unroll
            for (int v = 0; v < 4; ++v) {
                float val = acc[mf][nf][v];
                qp[mf][v] = fmaf(val, a2[nf], qp[mf][v]);
                int row = block_row + mf * 16 + lh * 4 + v;
                if (row < N_ENT_C) {
                    if (col < 128) Ps[(size_t)row * 128 + col] = val;
                    else Pd[(size_t)row * 128 + (col - 128)] = val;
                }
            }
        }
    }
    // reduce q partials across the 16 col-lanes (bits 0-3)
#pragma unroll
    for (int mf = 0; mf < 4; ++mf)
#pragma unroll
        for (int v = 0; v < 4; ++v) {
            float q = qp[mf][v];
            q += __shfl_xor(q, 1);
            q += __shfl_xor(q, 2);
            q += __shfl_xor(q, 4);
            q += __shfl_xor(q, 8);
            qp[mf][v] = q;
        }
    if (l15 == 0) {
#pragma unroll
        for (int mf = 0; mf < 4; ++mf)
#pragma unroll
            for (int v = 0; v < 4; ++v) qred[w][mf * 16 + lh * 4 + v] = qp[mf][v];
    }
    __syncthreads();
    if (tid < 64) {
        int row = block_row + tid;
        if (row < N_ENT_C) {
            qs[row] = qred[0][tid] + qred[1][tid];
            qd[row] = qred[2][tid] + qred[3][tid];
        }
    }
}

// ---------------- rel-key block histogram (LDS) + src global hist ----------------
__global__ __launch_bounds__(256) void edge_hist(const int* __restrict__ src,
                                                 const int* __restrict__ rel,
                                                 int* __restrict__ histSrc,
                                                 int* __restrict__ blkHist) {
    __shared__ int lh[512];
    int tid = threadIdx.x;
    lh[tid] = 0; lh[tid + 256] = 0;
    __syncthreads();
    int base = blockIdx.x * EPB;
#pragma unroll
    for (int j = 0; j < 4; ++j) {
        int e = base + j * 256 + tid;
        if (e < NEDGE_C) {
            atomicAdd(&histSrc[src[e]], 1);
            atomicAdd(&lh[rel[e]], 1);
        }
    }
    __syncthreads();
    blkHist[blockIdx.x * 512 + tid] = lh[tid];
    blkHist[blockIdx.x * 512 + 256 + tid] = lh[tid + 256];
}

__global__ void colsum(const int* __restrict__ blkHist, int* __restrict__ partial) {
    int r = threadIdx.x;
    int k = blockIdx.x;
    int b0 = k * CHUNK_B;
    int b1 = min(b0 + CHUNK_B, NB_EDGE);
    int t = 0;
    for (int b = b0; b < b1; ++b) t += blkHist[b * 512 + r];
    partial[k * 512 + r] = t;
}

__global__ void scan512(const int* __restrict__ partial, int* __restrict__ relStart,
                        int* __restrict__ chunkOff) {
    __shared__ int a[512], b2[512];
    int tid = threadIdx.x;
    int p8[8];
    int t = 0;
#pragma unroll
    for (int k = 0; k < 8; ++k) { p8[k] = partial[k * 512 + tid]; t += p8[k]; }
    a[tid] = t;
    __syncthreads();
    int v = t;
    int* cur = a; int* nxt = b2;
    for (int off = 1; off < 512; off <<= 1) {
        int x = cur[tid] + ((tid >= off) ? cur[tid - off] : 0);
        nxt[tid] = x;
        __syncthreads();
        int* tmp = cur; cur = nxt; nxt = tmp;
    }
    int excl = cur[tid] - v;
    relStart[tid] = excl;
    int run = excl;
#pragma unroll
    for (int k = 0; k < 8; ++k) { chunkOff[k * 512 + tid] = run; run += p8[k]; }
}

__global__ void colscan(const int* __restrict__ blkHist, const int* __restrict__ chunkOff,
                        int* __restrict__ blockOffs) {
    int r = threadIdx.x;
    int k = blockIdx.x;
    int b0 = k * CHUNK_B;
    int b1 = min(b0 + CHUNK_B, NB_EDGE);
    int off = chunkOff[k * 512 + r];
    for (int b = b0; b < b1; ++b) {
        blockOffs[b * 512 + r] = off;
        off += blkHist[b * 512 + r];
    }
}

__global__ void scan_blockred(const int* __restrict__ hist, int* __restrict__ blockSums, int n) {
    __shared__ int s[256];
    int tid = threadIdx.x;
    int i = blockIdx.x * 256 + tid;
    s[tid] = (i < n) ? hist[i] : 0;
    __syncthreads();
    for (int off = 128; off > 0; off >>= 1) {
        if (tid < off) s[tid] += s[tid + off];
        __syncthreads();
    }
    if (tid == 0) blockSums[blockIdx.x] = s[0];
}

__global__ void scan_single(int* __restrict__ data, int n) {
    __shared__ int a[1024], b2[1024];
    int tid = threadIdx.x;
    int v = (tid < n) ? data[tid] : 0;
    a[tid] = v;
    __syncthreads();
    int* cur = a; int* nxt = b2;
    for (int off = 1; off < 1024; off <<= 1) {
        int x = cur[tid] + ((tid >= off) ? cur[tid - off] : 0);
        nxt[tid] = x;
        __syncthreads();
        int* t = cur; cur = nxt; nxt = t;
    }
    if (tid < n) data[tid] = cur[tid] - v;   // exclusive
}

__global__ void scan_final(const int* __restrict__ hist, const int* __restrict__ blockOffs,
                           int* __restrict__ offs, int n) {
    __shared__ int a[256], b2[256];
    int tid = threadIdx.x;
    int i = blockIdx.x * 256 + tid;
    int v = (i < n) ? hist[i] : 0;
    a[tid] = v;
    __syncthreads();
    int* cur = a; int* nxt = b2;
    for (int off = 1; off < 256; off <<= 1) {
        int x = cur[tid] + ((tid >= off) ? cur[tid - off] : 0);
        nxt[tid] = x;
        __syncthreads();
        int* t = cur; cur = nxt; nxt = t;
    }
    if (i < n) offs[i] = cur[tid] - v + blockOffs[blockIdx.x];
}

__global__ __launch_bounds__(256) void scatter_both(const int* __restrict__ src,
                                                    const int* __restrict__ dst,
                                                    const int* __restrict__ rel,
                                                    int* __restrict__ offsSrc,
                                                    const int* __restrict__ blockOffs,
                                                    int* __restrict__ dstS, int* __restrict__ relS,
                                                    int* __restrict__ srcR, int* __restrict__ dstR) {
    __shared__ int lh[512];
    int tid = threadIdx.x;
    lh[tid] = 0; lh[tid + 256] = 0;
    __syncthreads();
    int base = blockIdx.x * EPB;
    const int* bo = &blockOffs[blockIdx.x * 512];
#pragma unroll
    for (int j = 0; j < 4; ++j) {
        int e = base + j * 256 + tid;
        if (e < NEDGE_C) {
            int s = src[e], d = dst[e], r = rel[e];
            int p = atomicAdd(&offsSrc[s], 1);
            dstS[p] = d; relS[p] = r;
            int lr = atomicAdd(&lh[r], 1);
            int q = bo[r] + lr;
            srcR[q] = s; dstR[q] = d;
        }
    }
}

// ---------------- rel phase: 8 partial blocks per relation ----------------
__global__ __launch_bounds__(256) void rel_phase(const float* __restrict__ Ps,
                                                 const float* __restrict__ Pd,
                                                 const float* __restrict__ qs,
                                                 const float* __restrict__ qd,
                                                 const float* __restrict__ qr,
                                                 const int* __restrict__ relStart,
                                                 const int* __restrict__ srcR,
                                                 const int* __restrict__ dstR,
                                                 const float* __restrict__ a2b,
                                                 float* __restrict__ relpart) {
    int r = blockIdx.x >> 3;
    int p = blockIdx.x & 7;
    int start = relStart[r];
    int end = relStart[r + 1];
    int tid = threadIdx.x;
    int w = tid >> 6;
    int h = (tid >> 5) & 1;
    int l = tid & 31;
    int slot = p * 8 + w * 2 + h;
    float bb = a2b[0];
    float qrr = qr[r];
    float4 acc = make_float4(0.f, 0.f, 0.f, 0.f);
    float ebs = 0.f;
    for (int i = start + slot; i < end; i += 64) {
        int s = srcR[i], d = dstR[i];
        float b = qs[s] + qd[d] + qrr + bb;
        b = (b > 0.f) ? b : 0.01f * b;
        float eb = expf(b);
        float4 pv = *(const float4*)&Ps[(size_t)s * 128 + l * 4];
        float4 dv = *(const float4*)&Pd[(size_t)d * 128 + l * 4];
        acc.x = fmaf(eb, pv.x + dv.x, acc.x);
        acc.y = fmaf(eb, pv.y + dv.y, acc.y);
        acc.z = fmaf(eb, pv.z + dv.z, acc.z);
        acc.w = fmaf(eb, pv.w + dv.w, acc.w);
        ebs += eb;
    }
    __shared__ float vred[8][128];
    __shared__ float sred[8];
    int sub = w * 2 + h;
    *(float4*)&vred[sub][l * 4] = acc;
    if (l == 0) sred[sub] = ebs;
    __syncthreads();
    if (tid < 128) {
        float v = 0.f;
#pragma unroll
        for (int k2 = 0; k2 < 8; ++k2) v += vred[k2][tid];
        float e = 0.f;
#pragma unroll
        for (int k2 = 0; k2 < 8; ++k2) e += sred[k2];
        int pi = r * 8 + p;
        relpart[pi * 132 + tid] = v;
        if (tid == 0) relpart[pi * 132 + 128] = e;
    }
}

__global__ void rel_fin(const float* __restrict__ relpart, const float* __restrict__ Pr,
                        const int* __restrict__ relStart, float* __restrict__ outRel) {
    int r = blockIdx.x;
    int o = threadIdx.x;
    float v = 0.f, e = 0.f;
#pragma unroll
    for (int p = 0; p < 8; ++p) {
        v += relpart[(r * 8 + p) * 132 + o];
        e += relpart[(r * 8 + p) * 132 + 128];
    }
    float cnt = (float)(relStart[r + 1] - relStart[r]);
    float h = (v + e * Pr[r * 128 + o]) / fmaxf(cnt, 1.f);
    outRel[r * 128 + o] = (h > 0.f) ? h : (expf(h) - 1.f);
}

// ---------------- src phase ----------------
__global__ __launch_bounds__(256) void src_phase(float* __restrict__ Ps,
                                                 const float* __restrict__ Pd,
                                                 const float* __restrict__ Pr,
                                                 const float* __restrict__ qs,
                                                 const float* __restrict__ qd,
                                                 const float* __restrict__ qr,
                                                 const int* __restrict__ offsSrc,
                                                 const int* __restrict__ dstS,
                                                 const int* __restrict__ relS,
                                                 const float* __restrict__ a2b,
                                                 float* __restrict__ out) {
    int wid = (blockIdx.x * 256 + threadIdx.x) >> 6;
    if (wid >= N_ENT_C) return;
    int lane = threadIdx.x & 63;
    int h = lane >> 5, l = lane & 31;
    int s = wid;
    int start = (s == 0) ? 0 : offsSrc[s - 1];
    int end = offsSrc[s];
    float* dstp = (s < SCRATCH_ROWS) ? &Ps[(size_t)s * 128] : &out[(size_t)s * 128];
    if (end == start) {
        if (h == 0) *(float4*)&dstp[l * 4] = make_float4(0.f, 0.f, 0.f, 0.f);
        return;
    }
    float bb = a2b[0];
    float qss = qs[s];
    float4 acc = make_float4(0.f, 0.f, 0.f, 0.f);
    float ebs = 0.f;
    for (int i = start + h; i < end; i += 2) {
        int d = dstS[i], r = relS[i];
        float b = qss + qd[d] + qr[r] + bb;
        b = (b > 0.f) ? b : 0.01f * b;
        float eb = expf(b);
        float4 dv = *(const float4*)&Pd[(size_t)d * 128 + l * 4];
        float4 rv = *(const float4*)&Pr[(size_t)r * 128 + l * 4];
        acc.x = fmaf(eb, dv.x + rv.x, acc.x);
        acc.y = fmaf(eb, dv.y + rv.y, acc.y);
        acc.z = fmaf(eb, dv.z + rv.z, acc.z);
        acc.w = fmaf(eb, dv.w + rv.w, acc.w);
        ebs += eb;
    }
    acc.x += __shfl_xor(acc.x, 32);
    acc.y += __shfl_xor(acc.y, 32);
    acc.z += __shfl_xor(acc.z, 32);
    acc.w += __shfl_xor(acc.w, 32);
    ebs += __shfl_xor(ebs, 32);
    float inv = 1.f / ebs;
    float4 ps4 = *(const float4*)&Ps[(size_t)s * 128 + l * 4];
    float hx = ps4.x + acc.x * inv;
    float hy = ps4.y + acc.y * inv;
    float hz = ps4.z + acc.z * inv;
    float hw = ps4.w + acc.w * inv;
    hx = (hx > 0.f) ? hx : (expf(hx) - 1.f);
    hy = (hy > 0.f) ? hy : (expf(hy) - 1.f);
    hz = (hz > 0.f) ? hz : (expf(hz) - 1.f);
    hw = (hw > 0.f) ? hw : (expf(hw) - 1.f);
    if (h == 0) *(float4*)&dstp[l * 4] = make_float4(hx, hy, hz, hw);
}

extern "C" void kernel_launch(void* const* d_in, const int* in_sizes, int n_in,
                              void* d_out, int out_size, void* d_ws, size_t ws_size,
                              hipStream_t stream) {
    const float* ent  = (const float*)d_in[0];
    const float* rele = (const float*)d_in[1];
    const float* aw   = (const float*)d_in[2];
    const float* ab   = (const float*)d_in[3];
    const float* a2w  = (const float*)d_in[4];
    const float* a2b  = (const float*)d_in[5];
    const int* src    = (const int*)d_in[6];
    const int* dst    = (const int*)d_in[7];
    const int* rel    = (const int*)d_in[8];
    float* out = (float*)d_out;

    float* ws = (float*)d_ws;
    unsigned short* Wthi = (unsigned short*)(ws + OFF_WTHI);
    unsigned short* Wtlo = (unsigned short*)(ws + OFF_WTLO);
    float* Wtr = ws + OFF_WTR;
    float* Pr  = ws + OFF_PR;
    float* Ps  = ws + OFF_PS;
    float* Pd  = ws + OFF_PD;

    int* dI = (int*)d_out;
    int* histSrc  = dI + DO_HSRC;
    int* offsSrc  = dI + DO_OSRC;
    int* bsum     = dI + DO_BSUM;
    int* relStart = dI + DO_RELSTART;
    int* part8    = dI + DO_PART8;
    int* chunkOff = dI + DO_CHUNKOFF;
    int* blkHist  = dI + DO_BLKHIST;
    int* blockOffs= dI + DO_BLKOFFS;
    int* dstS     = dI + DO_DSTS;
    int* relS     = dI + DO_RELS;
    int* srcR     = dI + DO_SRCR;
    int* dstR     = dI + DO_DSTR;
    float* relpart = (float*)dI + DO_RELP;
    float* qs     = (float*)dI + DO_QS;
    float* qd     = (float*)dI + DO_QD;
    float* qr     = (float*)dI + DO_QR;

    hipMemsetAsync(histSrc, 0, (size_t)N_ENT_C * sizeof(int), stream);

    prep_w<<<192, 256, 0, stream>>>(aw, Wthi, Wtlo, Wtr);
    rel_proj<<<N_REL_C, 128, 0, stream>>>(rele, Wtr, ab, a2w, Pr, qr);
    ent_mfma<<<(N_ENT_C + 63) / 64, 256, 0, stream>>>(ent, Wthi, Wtlo, a2w, Ps, Pd, qs, qd);

    edge_hist<<<NB_EDGE, 256, 0, stream>>>(src, rel, histSrc, blkHist);
    colsum<<<8, 512, 0, stream>>>(blkHist, part8);
    scan512<<<1, 512, 0, stream>>>(part8, relStart, chunkOff);
    colscan<<<8, 512, 0, stream>>>(blkHist, chunkOff, blockOffs);
    scan_blockred<<<SCAN_BLOCKS, 256, 0, stream>>>(histSrc, bsum, N_ENT_C);
    scan_single<<<1, 1024, 0, stream>>>(bsum, SCAN_BLOCKS);
    scan_final<<<SCAN_BLOCKS, 256, 0, stream>>>(histSrc, bsum, offsSrc, N_ENT_C);
    scatter_both<<<NB_EDGE, 256, 0, stream>>>(src, dst, rel, offsSrc, blockOffs,
                                              dstS, relS, srcR, dstR);

    rel_phase<<<N_REL_C * 8, 256, 0, stream>>>(Ps, Pd, qs, qd, qr, relStart, srcR, dstR,
                                               a2b, relpart);
    rel_fin<<<N_REL_C, 128, 0, stream>>>(relpart, Pr, relStart, out + (size_t)N_ENT_C * 128);

    src_phase<<<(N_ENT_C + 3) / 4, 256, 0, stream>>>(Ps, Pd, Pr, qs, qd, qr,
                                                     offsSrc, dstS, relS, a2b, out);

    hipMemcpyAsync(out, Ps, (size_t)SCRATCH_ROWS * 128 * sizeof(float),
                   hipMemcpyDeviceToDevice, stream);
}

// Round 6
// 274.690 us; speedup vs baseline: 3.8333x; 1.1375x over previous
//
#include <hip/hip_runtime.h>
#include <hip/hip_bf16.h>

#define N_ENT_C 100000
#define N_REL_C 500
#define NEDGE_C 500000
#define SCAN_BLOCKS 391   // ceil(100000/256)
#define EPB 1024          // edges per block for rel sort
#define NB_EDGE 489       // ceil(500000/1024)
#define CHUNK_B 62        // ceil(489/8)

// ---------------- ws layout (float offsets) — same total footprint as rounds 2-5 ------
#define OFF_WTHI  0         // Wt hi bf16 [256][128] -> 16384 f32 slots
#define OFF_WTLO  16384     // Wt lo bf16 [256][128]
#define OFF_WTR   32768     // Wtr f32 [128][128]
#define OFF_PR    49152     // Pr f32 [500][128]
#define OFF_PS    113152    // Ps f32 [100000][128]           (own-row + output staging)
#define OFF_PSH   12913152  // PsH bf16 [100000][128] -> 6.4M f32 slots (gather copy)
#define OFF_PDH   19313152  // PdH bf16 [100000][128] -> 6.4M f32 slots (gather copy)
// end = 25,713,152 floats = 102.85 MB (identical to proven footprint)

// ---------------- d_out scratch layout (dead until final copy) ------------------------
#define DO_HSRC     0
#define DO_OSRC     100000
#define DO_BSUM     200000
#define DO_RELSTART 200512
#define DO_PART8    201024
#define DO_CHUNKOFF 205120
#define DO_BLKHIST  209216
#define DO_BLKOFFS  459584
#define DO_DSTS     709952
#define DO_RELS     1209952
#define DO_SRCR     1709952
#define DO_DSTR     2209952
#define DO_RELP     2709952
#define DO_QS       3237952
#define DO_QD       3337952
#define DO_QR       3437952
#define SCRATCH_ROWS 26863

typedef short bf16x8 __attribute__((ext_vector_type(8)));   // 8 bf16 in 4 VGPRs
typedef short s16x4  __attribute__((ext_vector_type(4)));
typedef float f32x4  __attribute__((ext_vector_type(4)));

__device__ inline unsigned short bf_rne(float x) {
    unsigned int u = __float_as_uint(x);
    u += 0x7FFF + ((u >> 16) & 1);          // round-nearest-even
    return (unsigned short)(u >> 16);
}
__device__ inline float bf2f(unsigned short h) {
    return __uint_as_float(((unsigned int)h) << 16);
}

// ---------------- weight prep: Wt (transposed by n, k contiguous) as bf16 hi/lo -------
__global__ void prep_w(const float* __restrict__ aw, unsigned short* __restrict__ Wthi,
                       unsigned short* __restrict__ Wtlo, float* __restrict__ Wtr) {
    int idx = blockIdx.x * 256 + threadIdx.x;   // 0..49151
    if (idx < 32768) {
        int n = idx >> 7, k = idx & 127;
        float v = (n < 128) ? aw[n * 384 + k] : aw[(n - 128) * 384 + 128 + k];
        unsigned short h = bf_rne(v);
        Wthi[idx] = h;
        Wtlo[idx] = bf_rne(v - bf2f(h));
    } else if (idx < 49152) {
        int t = idx - 32768;
        int k = t >> 7, o = t & 127;
        Wtr[t] = aw[o * 384 + 256 + k];
    }
}

// ---------------- rel projection + qr epilogue (f32, tiny) ----------------
__global__ void rel_proj(const float* __restrict__ rele, const float* __restrict__ Wtr,
                         const float* __restrict__ ab, const float* __restrict__ a2w,
                         float* __restrict__ Pr, float* __restrict__ qr) {
    int r = blockIdx.x;
    int o = threadIdx.x;
    float acc = ab[o];
    for (int k = 0; k < 128; ++k)
        acc = fmaf(rele[r * 128 + k], Wtr[k * 128 + o], acc);
    Pr[r * 128 + o] = acc;
    __shared__ float red[128];
    red[o] = acc * a2w[o];
    __syncthreads();
    for (int off = 64; off > 0; off >>= 1) {
        if (o < off) red[o] += red[o + off];
        __syncthreads();
    }
    if (o == 0) qr[r] = red[0];
}

// ---------------- ent projection via MFMA bf16 hi/lo split ----------------
// Block: 64 rows x 256 cols (Ps 0-127, Pd 128-255). 4 waves, wave w -> cols w*64..w*64+63.
__global__ __launch_bounds__(256) void ent_mfma(const float* __restrict__ ent,
                                                const unsigned short* __restrict__ Wthi,
                                                const unsigned short* __restrict__ Wtlo,
                                                const float* __restrict__ a2w,
                                                float* __restrict__ Ps,
                                                unsigned short* __restrict__ PsH,
                                                unsigned short* __restrict__ PdH,
                                                float* __restrict__ qs,
                                                float* __restrict__ qd) {
    __shared__ __align__(16) char sh[32768];    // A hi [0,16K), A lo [16K,32K), bf16, XOR-swizzled
    __shared__ float qred[4][64];
    const int tid = threadIdx.x;
    const int block_row = blockIdx.x * 64;

    // stage A tile: 64 rows x 128 k, f32 -> bf16 hi/lo into LDS
#pragma unroll
    for (int i = 0; i < 8; ++i) {
        int f = tid + i * 256;          // float4 slot
        int m = f >> 5, k4 = f & 31;
        float4 v = make_float4(0.f, 0.f, 0.f, 0.f);
        int grow = block_row + m;
        if (grow < N_ENT_C) v = *(const float4*)&ent[(size_t)grow * 128 + k4 * 4];
        unsigned short h0 = bf_rne(v.x), h1 = bf_rne(v.y), h2 = bf_rne(v.z), h3 = bf_rne(v.w);
        s16x4 hv; hv[0] = (short)h0; hv[1] = (short)h1; hv[2] = (short)h2; hv[3] = (short)h3;
        s16x4 lv;
        lv[0] = (short)bf_rne(v.x - bf2f(h0));
        lv[1] = (short)bf_rne(v.y - bf2f(h1));
        lv[2] = (short)bf_rne(v.z - bf2f(h2));
        lv[3] = (short)bf_rne(v.w - bf2f(h3));
        int off = m * 256 + k4 * 8;             // byte offset in 64x128 bf16 tile
        off ^= (m & 7) << 4;                    // bank-conflict swizzle
        *(s16x4*)(sh + off) = hv;
        *(s16x4*)(sh + 16384 + off) = lv;
    }
    __syncthreads();

    const int w = tid >> 6, lane = tid & 63;
    const int l15 = lane & 15, lh = lane >> 4;
    const int n0 = w * 64;

    f32x4 zz = {0.f, 0.f, 0.f, 0.f};
    f32x4 acc[4][4];
#pragma unroll
    for (int mf = 0; mf < 4; ++mf)
#pragma unroll
        for (int nf = 0; nf < 4; ++nf) acc[mf][nf] = zz;

#pragma unroll
    for (int ks = 0; ks < 4; ++ks) {
        int kb = ks * 32 + lh * 8;              // k element offset (8 contiguous bf16)
        bf16x8 ah[4], al[4];
#pragma unroll
        for (int mf = 0; mf < 4; ++mf) {
            int row = mf * 16 + l15;
            int off = row * 256 + kb * 2;
            off ^= (row & 7) << 4;
            ah[mf] = *(const bf16x8*)(sh + off);
            al[mf] = *(const bf16x8*)(sh + 16384 + off);
        }
#pragma unroll
        for (int nf = 0; nf < 4; ++nf) {
            int n = n0 + nf * 16 + l15;
            bf16x8 bh = *(const bf16x8*)(Wthi + n * 128 + kb);
            bf16x8 bl = *(const bf16x8*)(Wtlo + n * 128 + kb);
#pragma unroll
            for (int mf = 0; mf < 4; ++mf) {
                acc[mf][nf] = __builtin_amdgcn_mfma_f32_16x16x32_bf16(ah[mf], bh, acc[mf][nf], 0, 0, 0);
                acc[mf][nf] = __builtin_amdgcn_mfma_f32_16x16x32_bf16(ah[mf], bl, acc[mf][nf], 0, 0, 0);
                acc[mf][nf] = __builtin_amdgcn_mfma_f32_16x16x32_bf16(al[mf], bh, acc[mf][nf], 0, 0, 0);
            }
        }
    }

    // C write (col = lane&15, row = (lane>>4)*4 + reg — verified m89/m91) + q partials
    float a2[4];
#pragma unroll
    for (int nf = 0; nf < 4; ++nf) a2[nf] = a2w[(n0 + nf * 16 + l15) & 127];
    float qp[4][4];
#pragma unroll
    for (int mf = 0; mf < 4; ++mf)
#pragma unroll
        for (int v = 0; v < 4; ++v) qp[mf][v] = 0.f;

#pragma unroll
    for (int mf = 0; mf < 4; ++mf) {
#pragma unroll
        for (int nf = 0; nf < 4; ++nf) {
            int col = n0 + nf * 16 + l15;
#pragma unroll
            for (int v = 0; v < 4; ++v) {
                float val = acc[mf][nf][v];
                qp[mf][v] = fmaf(val, a2[nf], qp[mf][v]);
                int row = block_row + mf * 16 + lh * 4 + v;
                if (row < N_ENT_C) {
                    if (col < 128) {
                        Ps[(size_t)row * 128 + col] = val;
                        PsH[(size_t)row * 128 + col] = bf_rne(val);
                    } else {
                        PdH[(size_t)row * 128 + (col - 128)] = bf_rne(val);
                    }
                }
            }
        }
    }
    // reduce q partials across the 16 col-lanes (bits 0-3)
#pragma unroll
    for (int mf = 0; mf < 4; ++mf)
#pragma unroll
        for (int v = 0; v < 4; ++v) {
            float q = qp[mf][v];
            q += __shfl_xor(q, 1);
            q += __shfl_xor(q, 2);
            q += __shfl_xor(q, 4);
            q += __shfl_xor(q, 8);
            qp[mf][v] = q;
        }
    if (l15 == 0) {
#pragma unroll
        for (int mf = 0; mf < 4; ++mf)
#pragma unroll
            for (int v = 0; v < 4; ++v) qred[w][mf * 16 + lh * 4 + v] = qp[mf][v];
    }
    __syncthreads();
    if (tid < 64) {
        int row = block_row + tid;
        if (row < N_ENT_C) {
            qs[row] = qred[0][tid] + qred[1][tid];
            qd[row] = qred[2][tid] + qred[3][tid];
        }
    }
}

// ---------------- rel-key block histogram (LDS) + src global hist ----------------
__global__ __launch_bounds__(256) void edge_hist(const int* __restrict__ src,
                                                 const int* __restrict__ rel,
                                                 int* __restrict__ histSrc,
                                                 int* __restrict__ blkHist) {
    __shared__ int lh[512];
    int tid = threadIdx.x;
    lh[tid] = 0; lh[tid + 256] = 0;
    __syncthreads();
    int base = blockIdx.x * EPB;
#pragma unroll
    for (int j = 0; j < 4; ++j) {
        int e = base + j * 256 + tid;
        if (e < NEDGE_C) {
            atomicAdd(&histSrc[src[e]], 1);
            atomicAdd(&lh[rel[e]], 1);
        }
    }
    __syncthreads();
    blkHist[blockIdx.x * 512 + tid] = lh[tid];
    blkHist[blockIdx.x * 512 + 256 + tid] = lh[tid + 256];
}

__global__ void colsum(const int* __restrict__ blkHist, int* __restrict__ partial) {
    int r = threadIdx.x;
    int k = blockIdx.x;
    int b0 = k * CHUNK_B;
    int b1 = min(b0 + CHUNK_B, NB_EDGE);
    int t = 0;
    for (int b = b0; b < b1; ++b) t += blkHist[b * 512 + r];
    partial[k * 512 + r] = t;
}

__global__ void scan512(const int* __restrict__ partial, int* __restrict__ relStart,
                        int* __restrict__ chunkOff) {
    __shared__ int a[512], b2[512];
    int tid = threadIdx.x;
    int p8[8];
    int t = 0;
#pragma unroll
    for (int k = 0; k < 8; ++k) { p8[k] = partial[k * 512 + tid]; t += p8[k]; }
    a[tid] = t;
    __syncthreads();
    int v = t;
    int* cur = a; int* nxt = b2;
    for (int off = 1; off < 512; off <<= 1) {
        int x = cur[tid] + ((tid >= off) ? cur[tid - off] : 0);
        nxt[tid] = x;
        __syncthreads();
        int* tmp = cur; cur = nxt; nxt = tmp;
    }
    int excl = cur[tid] - v;
    relStart[tid] = excl;
    int run = excl;
#pragma unroll
    for (int k = 0; k < 8; ++k) { chunkOff[k * 512 + tid] = run; run += p8[k]; }
}

__global__ void colscan(const int* __restrict__ blkHist, const int* __restrict__ chunkOff,
                        int* __restrict__ blockOffs) {
    int r = threadIdx.x;
    int k = blockIdx.x;
    int b0 = k * CHUNK_B;
    int b1 = min(b0 + CHUNK_B, NB_EDGE);
    int off = chunkOff[k * 512 + r];
    for (int b = b0; b < b1; ++b) {
        blockOffs[b * 512 + r] = off;
        off += blkHist[b * 512 + r];
    }
}

__global__ void scan_blockred(const int* __restrict__ hist, int* __restrict__ blockSums, int n) {
    __shared__ int s[256];
    int tid = threadIdx.x;
    int i = blockIdx.x * 256 + tid;
    s[tid] = (i < n) ? hist[i] : 0;
    __syncthreads();
    for (int off = 128; off > 0; off >>= 1) {
        if (tid < off) s[tid] += s[tid + off];
        __syncthreads();
    }
    if (tid == 0) blockSums[blockIdx.x] = s[0];
}

__global__ void scan_single(int* __restrict__ data, int n) {
    __shared__ int a[1024], b2[1024];
    int tid = threadIdx.x;
    int v = (tid < n) ? data[tid] : 0;
    a[tid] = v;
    __syncthreads();
    int* cur = a; int* nxt = b2;
    for (int off = 1; off < 1024; off <<= 1) {
        int x = cur[tid] + ((tid >= off) ? cur[tid - off] : 0);
        nxt[tid] = x;
        __syncthreads();
        int* t = cur; cur = nxt; nxt = t;
    }
    if (tid < n) data[tid] = cur[tid] - v;   // exclusive
}

__global__ void scan_final(const int* __restrict__ hist, const int* __restrict__ blockOffs,
                           int* __restrict__ offs, int n) {
    __shared__ int a[256], b2[256];
    int tid = threadIdx.x;
    int i = blockIdx.x * 256 + tid;
    int v = (i < n) ? hist[i] : 0;
    a[tid] = v;
    __syncthreads();
    int* cur = a; int* nxt = b2;
    for (int off = 1; off < 256; off <<= 1) {
        int x = cur[tid] + ((tid >= off) ? cur[tid - off] : 0);
        nxt[tid] = x;
        __syncthreads();
        int* t = cur; cur = nxt; nxt = t;
    }
    if (i < n) offs[i] = cur[tid] - v + blockOffs[blockIdx.x];
}

__global__ __launch_bounds__(256) void scatter_both(const int* __restrict__ src,
                                                    const int* __restrict__ dst,
                                                    const int* __restrict__ rel,
                                                    int* __restrict__ offsSrc,
                                                    const int* __restrict__ blockOffs,
                                                    int* __restrict__ dstS, int* __restrict__ relS,
                                                    int* __restrict__ srcR, int* __restrict__ dstR) {
    __shared__ int lh[512];
    int tid = threadIdx.x;
    lh[tid] = 0; lh[tid + 256] = 0;
    __syncthreads();
    int base = blockIdx.x * EPB;
    const int* bo = &blockOffs[blockIdx.x * 512];
#pragma unroll
    for (int j = 0; j < 4; ++j) {
        int e = base + j * 256 + tid;
        if (e < NEDGE_C) {
            int s = src[e], d = dst[e], r = rel[e];
            int p = atomicAdd(&offsSrc[s], 1);
            dstS[p] = d; relS[p] = r;
            int lr = atomicAdd(&lh[r], 1);
            int q = bo[r] + lr;
            srcR[q] = s; dstR[q] = d;
        }
    }
}

// ---------------- rel phase: 8 partial blocks per relation, bf16 row gathers ----------
__global__ __launch_bounds__(256) void rel_phase(const unsigned short* __restrict__ PsH,
                                                 const unsigned short* __restrict__ PdH,
                                                 const float* __restrict__ qs,
                                                 const float* __restrict__ qd,
                                                 const float* __restrict__ qr,
                                                 const int* __restrict__ relStart,
                                                 const int* __restrict__ srcR,
                                                 const int* __restrict__ dstR,
                                                 const float* __restrict__ a2b,
                                                 float* __restrict__ relpart) {
    int r = blockIdx.x >> 3;
    int p = blockIdx.x & 7;
    int start = relStart[r];
    int end = relStart[r + 1];
    int tid = threadIdx.x;
    int w = tid >> 6;
    int h = (tid >> 5) & 1;
    int l = tid & 31;
    int slot = p * 8 + w * 2 + h;
    float bb = a2b[0];
    float qrr = qr[r];
    float4 acc = make_float4(0.f, 0.f, 0.f, 0.f);
    float ebs = 0.f;
    for (int i = start + slot; i < end; i += 64) {
        int s = srcR[i], d = dstR[i];
        float b = qs[s] + qd[d] + qrr + bb;
        b = (b > 0.f) ? b : 0.01f * b;
        float eb = expf(b);
        ushort4 pv = *(const ushort4*)&PsH[(size_t)s * 128 + l * 4];
        ushort4 dv = *(const ushort4*)&PdH[(size_t)d * 128 + l * 4];
        acc.x = fmaf(eb, bf2f(pv.x) + bf2f(dv.x), acc.x);
        acc.y = fmaf(eb, bf2f(pv.y) + bf2f(dv.y), acc.y);
        acc.z = fmaf(eb, bf2f(pv.z) + bf2f(dv.z), acc.z);
        acc.w = fmaf(eb, bf2f(pv.w) + bf2f(dv.w), acc.w);
        ebs += eb;
    }
    __shared__ float vred[8][128];
    __shared__ float sred[8];
    int sub = w * 2 + h;
    *(float4*)&vred[sub][l * 4] = acc;
    if (l == 0) sred[sub] = ebs;
    __syncthreads();
    if (tid < 128) {
        float v = 0.f;
#pragma unroll
        for (int k2 = 0; k2 < 8; ++k2) v += vred[k2][tid];
        float e = 0.f;
#pragma unroll
        for (int k2 = 0; k2 < 8; ++k2) e += sred[k2];
        int pi = r * 8 + p;
        relpart[pi * 132 + tid] = v;
        if (tid == 0) relpart[pi * 132 + 128] = e;
    }
}

__global__ void rel_fin(const float* __restrict__ relpart, const float* __restrict__ Pr,
                        const int* __restrict__ relStart, float* __restrict__ outRel) {
    int r = blockIdx.x;
    int o = threadIdx.x;
    float v = 0.f, e = 0.f;
#pragma unroll
    for (int p = 0; p < 8; ++p) {
        v += relpart[(r * 8 + p) * 132 + o];
        e += relpart[(r * 8 + p) * 132 + 128];
    }
    float cnt = (float)(relStart[r + 1] - relStart[r]);
    float h = (v + e * Pr[r * 128 + o]) / fmaxf(cnt, 1.f);
    outRel[r * 128 + o] = (h > 0.f) ? h : (expf(h) - 1.f);
}

// ---------------- src phase: bf16 Pd gathers, f32 own row / Pr ----------------
__global__ __launch_bounds__(256) void src_phase(float* __restrict__ Ps,
                                                 const unsigned short* __restrict__ PdH,
                                                 const float* __restrict__ Pr,
                                                 const float* __restrict__ qs,
                                                 const float* __restrict__ qd,
                                                 const float* __restrict__ qr,
                                                 const int* __restrict__ offsSrc,
                                                 const int* __restrict__ dstS,
                                                 const int* __restrict__ relS,
                                                 const float* __restrict__ a2b,
                                                 float* __restrict__ out) {
    int wid = (blockIdx.x * 256 + threadIdx.x) >> 6;
    if (wid >= N_ENT_C) return;
    int lane = threadIdx.x & 63;
    int h = lane >> 5, l = lane & 31;
    int s = wid;
    int start = (s == 0) ? 0 : offsSrc[s - 1];
    int end = offsSrc[s];
    float* dstp = (s < SCRATCH_ROWS) ? &Ps[(size_t)s * 128] : &out[(size_t)s * 128];
    if (end == start) {
        if (h == 0) *(float4*)&dstp[l * 4] = make_float4(0.f, 0.f, 0.f, 0.f);
        return;
    }
    float bb = a2b[0];
    float qss = qs[s];
    float4 acc = make_float4(0.f, 0.f, 0.f, 0.f);
    float ebs = 0.f;
    for (int i = start + h; i < end; i += 2) {
        int d = dstS[i], r = relS[i];
        float b = qss + qd[d] + qr[r] + bb;
        b = (b > 0.f) ? b : 0.01f * b;
        float eb = expf(b);
        ushort4 dv = *(const ushort4*)&PdH[(size_t)d * 128 + l * 4];
        float4 rv = *(const float4*)&Pr[(size_t)r * 128 + l * 4];
        acc.x = fmaf(eb, bf2f(dv.x) + rv.x, acc.x);
        acc.y = fmaf(eb, bf2f(dv.y) + rv.y, acc.y);
        acc.z = fmaf(eb, bf2f(dv.z) + rv.z, acc.z);
        acc.w = fmaf(eb, bf2f(dv.w) + rv.w, acc.w);
        ebs += eb;
    }
    acc.x += __shfl_xor(acc.x, 32);
    acc.y += __shfl_xor(acc.y, 32);
    acc.z += __shfl_xor(acc.z, 32);
    acc.w += __shfl_xor(acc.w, 32);
    ebs += __shfl_xor(ebs, 32);
    float inv = 1.f / ebs;
    float4 ps4 = *(const float4*)&Ps[(size_t)s * 128 + l * 4];
    float hx = ps4.x + acc.x * inv;
    float hy = ps4.y + acc.y * inv;
    float hz = ps4.z + acc.z * inv;
    float hw = ps4.w + acc.w * inv;
    hx = (hx > 0.f) ? hx : (expf(hx) - 1.f);
    hy = (hy > 0.f) ? hy : (expf(hy) - 1.f);
    hz = (hz > 0.f) ? hz : (expf(hz) - 1.f);
    hw = (hw > 0.f) ? hw : (expf(hw) - 1.f);
    if (h == 0) *(float4*)&dstp[l * 4] = make_float4(hx, hy, hz, hw);
}

extern "C" void kernel_launch(void* const* d_in, const int* in_sizes, int n_in,
                              void* d_out, int out_size, void* d_ws, size_t ws_size,
                              hipStream_t stream) {
    const float* ent  = (const float*)d_in[0];
    const float* rele = (const float*)d_in[1];
    const float* aw   = (const float*)d_in[2];
    const float* ab   = (const float*)d_in[3];
    const float* a2w  = (const float*)d_in[4];
    const float* a2b  = (const float*)d_in[5];
    const int* src    = (const int*)d_in[6];
    const int* dst    = (const int*)d_in[7];
    const int* rel    = (const int*)d_in[8];
    float* out = (float*)d_out;

    float* ws = (float*)d_ws;
    unsigned short* Wthi = (unsigned short*)(ws + OFF_WTHI);
    unsigned short* Wtlo = (unsigned short*)(ws + OFF_WTLO);
    float* Wtr = ws + OFF_WTR;
    float* Pr  = ws + OFF_PR;
    float* Ps  = ws + OFF_PS;
    unsigned short* PsH = (unsigned short*)(ws + OFF_PSH);
    unsigned short* PdH = (unsigned short*)(ws + OFF_PDH);

    int* dI = (int*)d_out;
    int* histSrc  = dI + DO_HSRC;
    int* offsSrc  = dI + DO_OSRC;
    int* bsum     = dI + DO_BSUM;
    int* relStart = dI + DO_RELSTART;
    int* part8    = dI + DO_PART8;
    int* chunkOff = dI + DO_CHUNKOFF;
    int* blkHist  = dI + DO_BLKHIST;
    int* blockOffs= dI + DO_BLKOFFS;
    int* dstS     = dI + DO_DSTS;
    int* relS     = dI + DO_RELS;
    int* srcR     = dI + DO_SRCR;
    int* dstR     = dI + DO_DSTR;
    float* relpart = (float*)dI + DO_RELP;
    float* qs     = (float*)dI + DO_QS;
    float* qd     = (float*)dI + DO_QD;
    float* qr     = (float*)dI + DO_QR;

    hipMemsetAsync(histSrc, 0, (size_t)N_ENT_C * sizeof(int), stream);

    prep_w<<<192, 256, 0, stream>>>(aw, Wthi, Wtlo, Wtr);
    rel_proj<<<N_REL_C, 128, 0, stream>>>(rele, Wtr, ab, a2w, Pr, qr);
    ent_mfma<<<(N_ENT_C + 63) / 64, 256, 0, stream>>>(ent, Wthi, Wtlo, a2w, Ps, PsH, PdH, qs, qd);

    edge_hist<<<NB_EDGE, 256, 0, stream>>>(src, rel, histSrc, blkHist);
    colsum<<<8, 512, 0, stream>>>(blkHist, part8);
    scan512<<<1, 512, 0, stream>>>(part8, relStart, chunkOff);
    colscan<<<8, 512, 0, stream>>>(blkHist, chunkOff, blockOffs);
    scan_blockred<<<SCAN_BLOCKS, 256, 0, stream>>>(histSrc, bsum, N_ENT_C);
    scan_single<<<1, 1024, 0, stream>>>(bsum, SCAN_BLOCKS);
    scan_final<<<SCAN_BLOCKS, 256, 0, stream>>>(histSrc, bsum, offsSrc, N_ENT_C);
    scatter_both<<<NB_EDGE, 256, 0, stream>>>(src, dst, rel, offsSrc, blockOffs,
                                              dstS, relS, srcR, dstR);

    rel_phase<<<N_REL_C * 8, 256, 0, stream>>>(PsH, PdH, qs, qd, qr, relStart, srcR, dstR,
                                               a2b, relpart);
    rel_fin<<<N_REL_C, 128, 0, stream>>>(relpart, Pr, relStart, out + (size_t)N_ENT_C * 128);

    src_phase<<<(N_ENT_C + 3) / 4, 256, 0, stream>>>(Ps, PdH, Pr, qs, qd, qr,
                                                     offsSrc, dstS, relS, a2b, out);

    hipMemcpyAsync(out, Ps, (size_t)SCRATCH_ROWS * 128 * sizeof(float),
                   hipMemcpyDeviceToDevice, stream);
}

// Round 7
// 269.306 us; speedup vs baseline: 3.9099x; 1.0200x over previous
//
#include <hip/hip_runtime.h>
#include <hip/hip_bf16.h>

#define N_ENT_C 100000
#define N_REL_C 500
#define NEDGE_C 500000
#define SCAN_BLOCKS 391   // ceil(100000/256)
#define EPB 1024          // edges per block for rel sort
#define NB_EDGE 489       // ceil(500000/1024)
#define CHUNK_B 62        // ceil(489/8)

// ---------------- ws layout (float offsets) — well under the proven 25.7M footprint ---
#define OFF_WTHI  0         // Wt hi bf16 [256][128] -> 16384 f32 slots
#define OFF_WTLO  16384     // Wt lo bf16 [256][128]
#define OFF_WTR   32768     // Wtr f32 [128][128]
#define OFF_PR    49152     // Pr f32 [500][128]
#define OFF_PRH   113152    // PrH bf16 [500][128] -> 32000 f32 slots
#define OFF_STAGE 145152    // stage f32 [10161][128] = 1,300,608
#define OFF_PSH   1445760   // PsH bf16 [100000][128] -> 6.4M f32 slots
#define OFF_PDH   7845760   // PdH bf16 [100000][128] -> 6.4M f32 slots
// end = 14,245,760 floats = 57 MB

// ---------------- d_out scratch layout ------------------------------------------------
// LOW region: live during src_phase (rows 0..SCRATCH_ROWS-1, staged in ws, memcpy'd last)
#define DO_OSRC     0         // offsSrc [100000]
#define DO_DSTS     100000    // dstS [500000]
#define DO_RELS     600000    // relS [500000]
#define DO_QS       1100000   // qs [100000]
#define DO_QD       1200000   // qd [100000]
#define DO_QR       1300000   // qr [512]
// end low = 1,300,512 -> SCRATCH_ROWS = ceil(/128) = 10161
#define SCRATCH_ROWS 10161
// HIGH region: dead before src_phase runs (src_phase writes these rows directly)
#define DO_HSRC     1300512   // histSrc [100000]
#define DO_BSUM     1400512   // blockSums [512]
#define DO_RELSTART 1401024   // relStart [512]
#define DO_PART8    1401536   // partial [8][512]
#define DO_CHUNKOFF 1405632   // chunkOff [8][512]
#define DO_BLKHIST  1409728   // blkHist [489][512]
#define DO_BLKOFFS  1660096   // blockOffs [489][512]
#define DO_SRCR     1910464   // srcR [500000]
#define DO_DSTR     2410464   // dstR [500000]
#define DO_RELP     2910464   // relpart [4000][132]
// end = 3,438,464 ints << 12.8M entity region

typedef short bf16x8 __attribute__((ext_vector_type(8)));   // 8 bf16 in 4 VGPRs
typedef short s16x4  __attribute__((ext_vector_type(4)));
typedef float f32x4  __attribute__((ext_vector_type(4)));
typedef unsigned short u16x8 __attribute__((ext_vector_type(8)));

__device__ inline unsigned short bf_rne(float x) {
    unsigned int u = __float_as_uint(x);
    u += 0x7FFF + ((u >> 16) & 1);          // round-nearest-even
    return (unsigned short)(u >> 16);
}
__device__ inline float bf2f(unsigned short h) {
    return __uint_as_float(((unsigned int)h) << 16);
}

// ---------------- weight prep: Wt (transposed by n, k contiguous) as bf16 hi/lo -------
__global__ void prep_w(const float* __restrict__ aw, unsigned short* __restrict__ Wthi,
                       unsigned short* __restrict__ Wtlo, float* __restrict__ Wtr) {
    int idx = blockIdx.x * 256 + threadIdx.x;   // 0..49151
    if (idx < 32768) {
        int n = idx >> 7, k = idx & 127;
        float v = (n < 128) ? aw[n * 384 + k] : aw[(n - 128) * 384 + 128 + k];
        unsigned short h = bf_rne(v);
        Wthi[idx] = h;
        Wtlo[idx] = bf_rne(v - bf2f(h));
    } else if (idx < 49152) {
        int t = idx - 32768;
        int k = t >> 7, o = t & 127;
        Wtr[t] = aw[o * 384 + 256 + k];
    }
}

// ---------------- rel projection + qr epilogue (f32, tiny) ----------------
__global__ void rel_proj(const float* __restrict__ rele, const float* __restrict__ Wtr,
                         const float* __restrict__ ab, const float* __restrict__ a2w,
                         float* __restrict__ Pr, unsigned short* __restrict__ PrH,
                         float* __restrict__ qr) {
    int r = blockIdx.x;
    int o = threadIdx.x;
    float acc = ab[o];
    for (int k = 0; k < 128; ++k)
        acc = fmaf(rele[r * 128 + k], Wtr[k * 128 + o], acc);
    Pr[r * 128 + o] = acc;
    PrH[r * 128 + o] = bf_rne(acc);
    __shared__ float red[128];
    red[o] = acc * a2w[o];
    __syncthreads();
    for (int off = 64; off > 0; off >>= 1) {
        if (o < off) red[o] += red[o + off];
        __syncthreads();
    }
    if (o == 0) qr[r] = red[0];
}

// ---------------- ent projection via MFMA bf16 hi/lo split; bf16-only outputs ---------
__global__ __launch_bounds__(256) void ent_mfma(const float* __restrict__ ent,
                                                const unsigned short* __restrict__ Wthi,
                                                const unsigned short* __restrict__ Wtlo,
                                                const float* __restrict__ a2w,
                                                unsigned short* __restrict__ PsH,
                                                unsigned short* __restrict__ PdH,
                                                float* __restrict__ qs,
                                                float* __restrict__ qd) {
    __shared__ __align__(16) char sh[32768];    // A hi [0,16K), A lo [16K,32K), XOR-swizzled
    __shared__ float qred[4][64];
    const int tid = threadIdx.x;
    const int block_row = blockIdx.x * 64;

#pragma unroll
    for (int i = 0; i < 8; ++i) {
        int f = tid + i * 256;
        int m = f >> 5, k4 = f & 31;
        float4 v = make_float4(0.f, 0.f, 0.f, 0.f);
        int grow = block_row + m;
        if (grow < N_ENT_C) v = *(const float4*)&ent[(size_t)grow * 128 + k4 * 4];
        unsigned short h0 = bf_rne(v.x), h1 = bf_rne(v.y), h2 = bf_rne(v.z), h3 = bf_rne(v.w);
        s16x4 hv; hv[0] = (short)h0; hv[1] = (short)h1; hv[2] = (short)h2; hv[3] = (short)h3;
        s16x4 lv;
        lv[0] = (short)bf_rne(v.x - bf2f(h0));
        lv[1] = (short)bf_rne(v.y - bf2f(h1));
        lv[2] = (short)bf_rne(v.z - bf2f(h2));
        lv[3] = (short)bf_rne(v.w - bf2f(h3));
        int off = m * 256 + k4 * 8;
        off ^= (m & 7) << 4;
        *(s16x4*)(sh + off) = hv;
        *(s16x4*)(sh + 16384 + off) = lv;
    }
    __syncthreads();

    const int w = tid >> 6, lane = tid & 63;
    const int l15 = lane & 15, lh = lane >> 4;
    const int n0 = w * 64;

    f32x4 zz = {0.f, 0.f, 0.f, 0.f};
    f32x4 acc[4][4];
#pragma unroll
    for (int mf = 0; mf < 4; ++mf)
#pragma unroll
        for (int nf = 0; nf < 4; ++nf) acc[mf][nf] = zz;

#pragma unroll
    for (int ks = 0; ks < 4; ++ks) {
        int kb = ks * 32 + lh * 8;
        bf16x8 ah[4], al[4];
#pragma unroll
        for (int mf = 0; mf < 4; ++mf) {
            int row = mf * 16 + l15;
            int off = row * 256 + kb * 2;
            off ^= (row & 7) << 4;
            ah[mf] = *(const bf16x8*)(sh + off);
            al[mf] = *(const bf16x8*)(sh + 16384 + off);
        }
#pragma unroll
        for (int nf = 0; nf < 4; ++nf) {
            int n = n0 + nf * 16 + l15;
            bf16x8 bh = *(const bf16x8*)(Wthi + n * 128 + kb);
            bf16x8 bl = *(const bf16x8*)(Wtlo + n * 128 + kb);
#pragma unroll
            for (int mf = 0; mf < 4; ++mf) {
                acc[mf][nf] = __builtin_amdgcn_mfma_f32_16x16x32_bf16(ah[mf], bh, acc[mf][nf], 0, 0, 0);
                acc[mf][nf] = __builtin_amdgcn_mfma_f32_16x16x32_bf16(ah[mf], bl, acc[mf][nf], 0, 0, 0);
                acc[mf][nf] = __builtin_amdgcn_mfma_f32_16x16x32_bf16(al[mf], bh, acc[mf][nf], 0, 0, 0);
            }
        }
    }

    // C write (col = lane&15, row = (lane>>4)*4 + reg) + q partials. bf16 stores only.
    float a2[4];
#pragma unroll
    for (int nf = 0; nf < 4; ++nf) a2[nf] = a2w[(n0 + nf * 16 + l15) & 127];
    float qp[4][4];
#pragma unroll
    for (int mf = 0; mf < 4; ++mf)
#pragma unroll
        for (int v = 0; v < 4; ++v) qp[mf][v] = 0.f;

#pragma unroll
    for (int mf = 0; mf < 4; ++mf) {
#pragma unroll
        for (int nf = 0; nf < 4; ++nf) {
            int col = n0 + nf * 16 + l15;
#pragma unroll
            for (int v = 0; v < 4; ++v) {
                float val = acc[mf][nf][v];
                qp[mf][v] = fmaf(val, a2[nf], qp[mf][v]);
                int row = block_row + mf * 16 + lh * 4 + v;
                if (row < N_ENT_C) {
                    unsigned short hv = bf_rne(val);
                    if (col < 128) PsH[(size_t)row * 128 + col] = hv;
                    else PdH[(size_t)row * 128 + (col - 128)] = hv;
                }
            }
        }
    }
#pragma unroll
    for (int mf = 0; mf < 4; ++mf)
#pragma unroll
        for (int v = 0; v < 4; ++v) {
            float q = qp[mf][v];
            q += __shfl_xor(q, 1);
            q += __shfl_xor(q, 2);
            q += __shfl_xor(q, 4);
            q += __shfl_xor(q, 8);
            qp[mf][v] = q;
        }
    if (l15 == 0) {
#pragma unroll
        for (int mf = 0; mf < 4; ++mf)
#pragma unroll
            for (int v = 0; v < 4; ++v) qred[w][mf * 16 + lh * 4 + v] = qp[mf][v];
    }
    __syncthreads();
    if (tid < 64) {
        int row = block_row + tid;
        if (row < N_ENT_C) {
            qs[row] = qred[0][tid] + qred[1][tid];
            qd[row] = qred[2][tid] + qred[3][tid];
        }
    }
}

// ---------------- rel-key block histogram (LDS) + src global hist ----------------
__global__ __launch_bounds__(256) void edge_hist(const int* __restrict__ src,
                                                 const int* __restrict__ rel,
                                                 int* __restrict__ histSrc,
                                                 int* __restrict__ blkHist) {
    __shared__ int lh[512];
    int tid = threadIdx.x;
    lh[tid] = 0; lh[tid + 256] = 0;
    __syncthreads();
    int base = blockIdx.x * EPB;
#pragma unroll
    for (int j = 0; j < 4; ++j) {
        int e = base + j * 256 + tid;
        if (e < NEDGE_C) {
            atomicAdd(&histSrc[src[e]], 1);
            atomicAdd(&lh[rel[e]], 1);
        }
    }
    __syncthreads();
    blkHist[blockIdx.x * 512 + tid] = lh[tid];
    blkHist[blockIdx.x * 512 + 256 + tid] = lh[tid + 256];
}

__global__ void colsum(const int* __restrict__ blkHist, int* __restrict__ partial) {
    int r = threadIdx.x;
    int k = blockIdx.x;
    int b0 = k * CHUNK_B;
    int b1 = min(b0 + CHUNK_B, NB_EDGE);
    int t = 0;
    for (int b = b0; b < b1; ++b) t += blkHist[b * 512 + r];
    partial[k * 512 + r] = t;
}

__global__ void scan512(const int* __restrict__ partial, int* __restrict__ relStart,
                        int* __restrict__ chunkOff) {
    __shared__ int a[512], b2[512];
    int tid = threadIdx.x;
    int p8[8];
    int t = 0;
#pragma unroll
    for (int k = 0; k < 8; ++k) { p8[k] = partial[k * 512 + tid]; t += p8[k]; }
    a[tid] = t;
    __syncthreads();
    int v = t;
    int* cur = a; int* nxt = b2;
    for (int off = 1; off < 512; off <<= 1) {
        int x = cur[tid] + ((tid >= off) ? cur[tid - off] : 0);
        nxt[tid] = x;
        __syncthreads();
        int* tmp = cur; cur = nxt; nxt = tmp;
    }
    int excl = cur[tid] - v;
    relStart[tid] = excl;
    int run = excl;
#pragma unroll
    for (int k = 0; k < 8; ++k) { chunkOff[k * 512 + tid] = run; run += p8[k]; }
}

__global__ void colscan(const int* __restrict__ blkHist, const int* __restrict__ chunkOff,
                        int* __restrict__ blockOffs) {
    int r = threadIdx.x;
    int k = blockIdx.x;
    int b0 = k * CHUNK_B;
    int b1 = min(b0 + CHUNK_B, NB_EDGE);
    int off = chunkOff[k * 512 + r];
    for (int b = b0; b < b1; ++b) {
        blockOffs[b * 512 + r] = off;
        off += blkHist[b * 512 + r];
    }
}

__global__ void scan_blockred(const int* __restrict__ hist, int* __restrict__ blockSums, int n) {
    __shared__ int s[256];
    int tid = threadIdx.x;
    int i = blockIdx.x * 256 + tid;
    s[tid] = (i < n) ? hist[i] : 0;
    __syncthreads();
    for (int off = 128; off > 0; off >>= 1) {
        if (tid < off) s[tid] += s[tid + off];
        __syncthreads();
    }
    if (tid == 0) blockSums[blockIdx.x] = s[0];
}

__global__ void scan_single(int* __restrict__ data, int n) {
    __shared__ int a[1024], b2[1024];
    int tid = threadIdx.x;
    int v = (tid < n) ? data[tid] : 0;
    a[tid] = v;
    __syncthreads();
    int* cur = a; int* nxt = b2;
    for (int off = 1; off < 1024; off <<= 1) {
        int x = cur[tid] + ((tid >= off) ? cur[tid - off] : 0);
        nxt[tid] = x;
        __syncthreads();
        int* t = cur; cur = nxt; nxt = t;
    }
    if (tid < n) data[tid] = cur[tid] - v;   // exclusive
}

__global__ void scan_final(const int* __restrict__ hist, const int* __restrict__ blockOffs,
                           int* __restrict__ offs, int n) {
    __shared__ int a[256], b2[256];
    int tid = threadIdx.x;
    int i = blockIdx.x * 256 + tid;
    int v = (i < n) ? hist[i] : 0;
    a[tid] = v;
    __syncthreads();
    int* cur = a; int* nxt = b2;
    for (int off = 1; off < 256; off <<= 1) {
        int x = cur[tid] + ((tid >= off) ? cur[tid - off] : 0);
        nxt[tid] = x;
        __syncthreads();
        int* t = cur; cur = nxt; nxt = t;
    }
    if (i < n) offs[i] = cur[tid] - v + blockOffs[blockIdx.x];
}

__global__ __launch_bounds__(256) void scatter_both(const int* __restrict__ src,
                                                    const int* __restrict__ dst,
                                                    const int* __restrict__ rel,
                                                    int* __restrict__ offsSrc,
                                                    const int* __restrict__ blockOffs,
                                                    int* __restrict__ dstS, int* __restrict__ relS,
                                                    int* __restrict__ srcR, int* __restrict__ dstR) {
    __shared__ int lh[512];
    int tid = threadIdx.x;
    lh[tid] = 0; lh[tid + 256] = 0;
    __syncthreads();
    int base = blockIdx.x * EPB;
    const int* bo = &blockOffs[blockIdx.x * 512];
#pragma unroll
    for (int j = 0; j < 4; ++j) {
        int e = base + j * 256 + tid;
        if (e < NEDGE_C) {
            int s = src[e], d = dst[e], r = rel[e];
            int p = atomicAdd(&offsSrc[s], 1);
            dstS[p] = d; relS[p] = r;
            int lr = atomicAdd(&lh[r], 1);
            int q = bo[r] + lr;
            srcR[q] = s; dstR[q] = d;
        }
    }
}

// ---------------- rel phase: 8 partial blocks per relation, bf16 row gathers ----------
__global__ __launch_bounds__(256) void rel_phase(const unsigned short* __restrict__ PsH,
                                                 const unsigned short* __restrict__ PdH,
                                                 const float* __restrict__ qs,
                                                 const float* __restrict__ qd,
                                                 const float* __restrict__ qr,
                                                 const int* __restrict__ relStart,
                                                 const int* __restrict__ srcR,
                                                 const int* __restrict__ dstR,
                                                 const float* __restrict__ a2b,
                                                 float* __restrict__ relpart) {
    int r = blockIdx.x >> 3;
    int p = blockIdx.x & 7;
    int start = relStart[r];
    int end = relStart[r + 1];
    int tid = threadIdx.x;
    int w = tid >> 6;
    int h = (tid >> 5) & 1;
    int l = tid & 31;
    int slot = p * 8 + w * 2 + h;
    float bb = a2b[0];
    float qrr = qr[r];
    float4 acc = make_float4(0.f, 0.f, 0.f, 0.f);
    float ebs = 0.f;
    for (int i = start + slot; i < end; i += 64) {
        int s = srcR[i], d = dstR[i];
        float b = qs[s] + qd[d] + qrr + bb;
        b = (b > 0.f) ? b : 0.01f * b;
        float eb = expf(b);
        ushort4 pv = *(const ushort4*)&PsH[(size_t)s * 128 + l * 4];
        ushort4 dv = *(const ushort4*)&PdH[(size_t)d * 128 + l * 4];
        acc.x = fmaf(eb, bf2f(pv.x) + bf2f(dv.x), acc.x);
        acc.y = fmaf(eb, bf2f(pv.y) + bf2f(dv.y), acc.y);
        acc.z = fmaf(eb, bf2f(pv.z) + bf2f(dv.z), acc.z);
        acc.w = fmaf(eb, bf2f(pv.w) + bf2f(dv.w), acc.w);
        ebs += eb;
    }
    __shared__ float vred[8][128];
    __shared__ float sred[8];
    int sub = w * 2 + h;
    *(float4*)&vred[sub][l * 4] = acc;
    if (l == 0) sred[sub] = ebs;
    __syncthreads();
    if (tid < 128) {
        float v = 0.f;
#pragma unroll
        for (int k2 = 0; k2 < 8; ++k2) v += vred[k2][tid];
        float e = 0.f;
#pragma unroll
        for (int k2 = 0; k2 < 8; ++k2) e += sred[k2];
        int pi = r * 8 + p;
        relpart[pi * 132 + tid] = v;
        if (tid == 0) relpart[pi * 132 + 128] = e;
    }
}

__global__ void rel_fin(const float* __restrict__ relpart, const float* __restrict__ Pr,
                        const int* __restrict__ relStart, float* __restrict__ outRel) {
    int r = blockIdx.x;
    int o = threadIdx.x;
    float v = 0.f, e = 0.f;
#pragma unroll
    for (int p = 0; p < 8; ++p) {
        v += relpart[(r * 8 + p) * 132 + o];
        e += relpart[(r * 8 + p) * 132 + 128];
    }
    float cnt = (float)(relStart[r + 1] - relStart[r]);
    float h = (v + e * Pr[r * 128 + o]) / fmaxf(cnt, 1.f);
    outRel[r * 128 + o] = (h > 0.f) ? h : (expf(h) - 1.f);
}

// ---------------- src phase: 4 edges in flight, all-bf16 gathers ----------------
__global__ __launch_bounds__(256) void src_phase(const unsigned short* __restrict__ PsH,
                                                 const unsigned short* __restrict__ PdH,
                                                 const unsigned short* __restrict__ PrH,
                                                 const float* __restrict__ qs,
                                                 const float* __restrict__ qd,
                                                 const float* __restrict__ qr,
                                                 const int* __restrict__ offsSrc,
                                                 const int* __restrict__ dstS,
                                                 const int* __restrict__ relS,
                                                 const float* __restrict__ a2b,
                                                 float* __restrict__ stage,
                                                 float* __restrict__ out) {
    int wid = (blockIdx.x * 256 + threadIdx.x) >> 6;
    if (wid >= N_ENT_C) return;
    int lane = threadIdx.x & 63;
    int g = lane >> 4, l = lane & 15;       // 4 groups x 16 lanes; lane covers cols l*8..l*8+7
    int s = wid;
    int start = (s == 0) ? 0 : offsSrc[s - 1];
    int end = offsSrc[s];
    float* dstp = (s < SCRATCH_ROWS) ? &stage[(size_t)s * 128] : &out[(size_t)s * 128];
    if (end == start) {
        if (g == 0) {
            *(float4*)&dstp[l * 8] = make_float4(0.f, 0.f, 0.f, 0.f);
            *(float4*)&dstp[l * 8 + 4] = make_float4(0.f, 0.f, 0.f, 0.f);
        }
        return;
    }
    float bb = a2b[0];
    float qss = qs[s];
    float acc[8];
#pragma unroll
    for (int j = 0; j < 8; ++j) acc[j] = 0.f;
    float ebs = 0.f;
    for (int i = start + g; i < end; i += 4) {
        int d = dstS[i], r = relS[i];
        float b = qss + qd[d] + qr[r] + bb;
        b = (b > 0.f) ? b : 0.01f * b;
        float eb = expf(b);
        u16x8 dv = *(const u16x8*)&PdH[(size_t)d * 128 + l * 8];
        u16x8 rv = *(const u16x8*)&PrH[(size_t)r * 128 + l * 8];
#pragma unroll
        for (int j = 0; j < 8; ++j)
            acc[j] = fmaf(eb, bf2f(dv[j]) + bf2f(rv[j]), acc[j]);
        ebs += eb;
    }
#pragma unroll
    for (int j = 0; j < 8; ++j) {
        acc[j] += __shfl_xor(acc[j], 16);
        acc[j] += __shfl_xor(acc[j], 32);
    }
    ebs += __shfl_xor(ebs, 16);
    ebs += __shfl_xor(ebs, 32);
    if (g == 0) {
        float inv = 1.f / ebs;
        u16x8 ps = *(const u16x8*)&PsH[(size_t)s * 128 + l * 8];
        float h[8];
#pragma unroll
        for (int j = 0; j < 8; ++j) {
            float x = bf2f(ps[j]) + acc[j] * inv;
            h[j] = (x > 0.f) ? x : (expf(x) - 1.f);
        }
        *(float4*)&dstp[l * 8]     = make_float4(h[0], h[1], h[2], h[3]);
        *(float4*)&dstp[l * 8 + 4] = make_float4(h[4], h[5], h[6], h[7]);
    }
}

extern "C" void kernel_launch(void* const* d_in, const int* in_sizes, int n_in,
                              void* d_out, int out_size, void* d_ws, size_t ws_size,
                              hipStream_t stream) {
    const float* ent  = (const float*)d_in[0];
    const float* rele = (const float*)d_in[1];
    const float* aw   = (const float*)d_in[2];
    const float* ab   = (const float*)d_in[3];
    const float* a2w  = (const float*)d_in[4];
    const float* a2b  = (const float*)d_in[5];
    const int* src    = (const int*)d_in[6];
    const int* dst    = (const int*)d_in[7];
    const int* rel    = (const int*)d_in[8];
    float* out = (float*)d_out;

    float* ws = (float*)d_ws;
    unsigned short* Wthi = (unsigned short*)(ws + OFF_WTHI);
    unsigned short* Wtlo = (unsigned short*)(ws + OFF_WTLO);
    float* Wtr = ws + OFF_WTR;
    float* Pr  = ws + OFF_PR;
    unsigned short* PrH = (unsigned short*)(ws + OFF_PRH);
    float* stage = ws + OFF_STAGE;
    unsigned short* PsH = (unsigned short*)(ws + OFF_PSH);
    unsigned short* PdH = (unsigned short*)(ws + OFF_PDH);

    int* dI = (int*)d_out;
    int* offsSrc  = dI + DO_OSRC;
    int* dstS     = dI + DO_DSTS;
    int* relS     = dI + DO_RELS;
    float* qs     = (float*)dI + DO_QS;
    float* qd     = (float*)dI + DO_QD;
    float* qr     = (float*)dI + DO_QR;
    int* histSrc  = dI + DO_HSRC;
    int* bsum     = dI + DO_BSUM;
    int* relStart = dI + DO_RELSTART;
    int* part8    = dI + DO_PART8;
    int* chunkOff = dI + DO_CHUNKOFF;
    int* blkHist  = dI + DO_BLKHIST;
    int* blockOffs= dI + DO_BLKOFFS;
    int* srcR     = dI + DO_SRCR;
    int* dstR     = dI + DO_DSTR;
    float* relpart = (float*)dI + DO_RELP;

    hipMemsetAsync(histSrc, 0, (size_t)N_ENT_C * sizeof(int), stream);

    prep_w<<<192, 256, 0, stream>>>(aw, Wthi, Wtlo, Wtr);
    rel_proj<<<N_REL_C, 128, 0, stream>>>(rele, Wtr, ab, a2w, Pr, PrH, qr);
    ent_mfma<<<(N_ENT_C + 63) / 64, 256, 0, stream>>>(ent, Wthi, Wtlo, a2w, PsH, PdH, qs, qd);

    edge_hist<<<NB_EDGE, 256, 0, stream>>>(src, rel, histSrc, blkHist);
    colsum<<<8, 512, 0, stream>>>(blkHist, part8);
    scan512<<<1, 512, 0, stream>>>(part8, relStart, chunkOff);
    colscan<<<8, 512, 0, stream>>>(blkHist, chunkOff, blockOffs);
    scan_blockred<<<SCAN_BLOCKS, 256, 0, stream>>>(histSrc, bsum, N_ENT_C);
    scan_single<<<1, 1024, 0, stream>>>(bsum, SCAN_BLOCKS);
    scan_final<<<SCAN_BLOCKS, 256, 0, stream>>>(histSrc, bsum, offsSrc, N_ENT_C);
    scatter_both<<<NB_EDGE, 256, 0, stream>>>(src, dst, rel, offsSrc, blockOffs,
                                              dstS, relS, srcR, dstR);

    rel_phase<<<N_REL_C * 8, 256, 0, stream>>>(PsH, PdH, qs, qd, qr, relStart, srcR, dstR,
                                               a2b, relpart);
    rel_fin<<<N_REL_C, 128, 0, stream>>>(relpart, Pr, relStart, out + (size_t)N_ENT_C * 128);

    src_phase<<<(N_ENT_C + 3) / 4, 256, 0, stream>>>(PsH, PdH, PrH, qs, qd, qr,
                                                     offsSrc, dstS, relS, a2b, stage, out);

    // copy staged rows (the ones whose d_out slots held src-phase-live scratch)
    hipMemcpyAsync(out, stage, (size_t)SCRATCH_ROWS * 128 * sizeof(float),
                   hipMemcpyDeviceToDevice, stream);
}

// Round 8
// 265.488 us; speedup vs baseline: 3.9661x; 1.0144x over previous
//
#include <hip/hip_runtime.h>
#include <hip/hip_bf16.h>

#define N_ENT_C 100000
#define N_REL_C 500
#define NEDGE_C 500000
#define SCAN_BLOCKS 391   // ceil(100000/256)
#define EPB 1024          // edges per block for rel sort
#define NB_EDGE 489       // ceil(500000/1024)
#define CHUNK_B 62        // ceil(489/8)
#define MT_TOTAL 6250     // 100000/16 m-tiles, exact
#define ENT_GRID 1250     // 5 m-tiles per block

// ---------------- ws layout (float offsets) — well under the proven 25.7M footprint ---
#define OFF_WTHI  0         // Wt hi bf16 [256][128] -> 16384 f32 slots
#define OFF_WTLO  16384     // Wt lo bf16 [256][128]
#define OFF_WTR   32768     // Wtr f32 [128][128]
#define OFF_PR    49152     // Pr f32 [500][128]
#define OFF_PRH   113152    // PrH bf16 [500][128] -> 32000 f32 slots
#define OFF_STAGE 145152    // stage f32 [10161][128] = 1,300,608
#define OFF_PSH   1445760   // PsH bf16 [100000][128] -> 6.4M f32 slots
#define OFF_PDH   7845760   // PdH bf16 [100000][128] -> 6.4M f32 slots
// end = 14,245,760 floats = 57 MB

// ---------------- d_out scratch layout ------------------------------------------------
// LOW region: live during src_phase (rows 0..SCRATCH_ROWS-1, staged in ws, memcpy'd last)
#define DO_OSRC     0         // offsSrc [100000]
#define DO_DSTS     100000    // dstS [500000]
#define DO_RELS     600000    // relS [500000]
#define DO_QS       1100000   // qs [100000]   (atomic-accumulated, zeroed by memset)
#define DO_QD       1200000   // qd [100000]   (atomic-accumulated, zeroed by memset)
#define DO_QR       1300000   // qr [512]
// end low = 1,300,512 -> SCRATCH_ROWS = ceil(/128) = 10161
#define SCRATCH_ROWS 10161
// HIGH region: dead before src_phase runs (src_phase writes these rows directly)
#define DO_HSRC     1300512   // histSrc [100000]
#define DO_BSUM     1400512   // blockSums [512]
#define DO_RELSTART 1401024   // relStart [512]
#define DO_PART8    1401536   // partial [8][512]
#define DO_CHUNKOFF 1405632   // chunkOff [8][512]
#define DO_BLKHIST  1409728   // blkHist [489][512]
#define DO_BLKOFFS  1660096   // blockOffs [489][512]
#define DO_SRCR     1910464   // srcR [500000]
#define DO_DSTR     2410464   // dstR [500000]
#define DO_RELP     2910464   // relpart [4000][132]
// end = 3,438,464 ints << 12.8M entity region

typedef short bf16x8 __attribute__((ext_vector_type(8)));   // 8 bf16 in 4 VGPRs
typedef float f32x4  __attribute__((ext_vector_type(4)));
typedef unsigned short u16x8 __attribute__((ext_vector_type(8)));

__device__ inline unsigned short bf_rne(float x) {
    unsigned int u = __float_as_uint(x);
    u += 0x7FFF + ((u >> 16) & 1);          // round-nearest-even
    return (unsigned short)(u >> 16);
}
__device__ inline float bf2f(unsigned short h) {
    return __uint_as_float(((unsigned int)h) << 16);
}

// ---------------- weight prep: Wt (transposed by n, k contiguous) as bf16 hi/lo -------
__global__ void prep_w(const float* __restrict__ aw, unsigned short* __restrict__ Wthi,
                       unsigned short* __restrict__ Wtlo, float* __restrict__ Wtr) {
    int idx = blockIdx.x * 256 + threadIdx.x;   // 0..49151
    if (idx < 32768) {
        int n = idx >> 7, k = idx & 127;
        float v = (n < 128) ? aw[n * 384 + k] : aw[(n - 128) * 384 + 128 + k];
        unsigned short h = bf_rne(v);
        Wthi[idx] = h;
        Wtlo[idx] = bf_rne(v - bf2f(h));
    } else if (idx < 49152) {
        int t = idx - 32768;
        int k = t >> 7, o = t & 127;
        Wtr[t] = aw[o * 384 + 256 + k];
    }
}

// ---------------- rel projection + qr epilogue (f32, tiny) ----------------
__global__ void rel_proj(const float* __restrict__ rele, const float* __restrict__ Wtr,
                         const float* __restrict__ ab, const float* __restrict__ a2w,
                         float* __restrict__ Pr, unsigned short* __restrict__ PrH,
                         float* __restrict__ qr) {
    int r = blockIdx.x;
    int o = threadIdx.x;
    float acc = ab[o];
    for (int k = 0; k < 128; ++k)
        acc = fmaf(rele[r * 128 + k], Wtr[k * 128 + o], acc);
    Pr[r * 128 + o] = acc;
    PrH[r * 128 + o] = bf_rne(acc);
    __shared__ float red[128];
    red[o] = acc * a2w[o];
    __syncthreads();
    for (int off = 64; off > 0; off >>= 1) {
        if (o < off) red[o] += red[o + off];
        __syncthreads();
    }
    if (o == 0) qr[r] = red[0];
}

// ---------------- ent projection: swapped-operand MFMA, no LDS, no syncthreads --------
// D = W · ent^T. A-frag = W rows (held in regs), B-frag = ent row slices (direct loads).
// C layout: col(lane&15) = entity row, row(lh*4+reg) = output col n -> packed stores.
// Wave w covers n in [w*64, w*64+64). Block does 5 m-tiles (grid-stride).
__global__ __launch_bounds__(256, 2) void ent_mfma(const float* __restrict__ ent,
                                                   const unsigned short* __restrict__ Wthi,
                                                   const unsigned short* __restrict__ Wtlo,
                                                   const float* __restrict__ a2w,
                                                   unsigned short* __restrict__ PsH,
                                                   unsigned short* __restrict__ PdH,
                                                   float* __restrict__ qs,
                                                   float* __restrict__ qd) {
    const int tid = threadIdx.x;
    const int w = tid >> 6, lane = tid & 63;
    const int l15 = lane & 15, lh = lane >> 4;
    const int n0 = w * 64;

    // A-frags: W hi/lo for this wave's 4 n-fragments, all 4 k-steps. 128 VGPRs, loaded once.
    bf16x8 wh[4][4], wl[4][4];
#pragma unroll
    for (int nf = 0; nf < 4; ++nf) {
        int n = n0 + nf * 16 + l15;
#pragma unroll
        for (int ks = 0; ks < 4; ++ks) {
            int kb = ks * 32 + lh * 8;
            wh[nf][ks] = *(const bf16x8*)(Wthi + n * 128 + kb);
            wl[nf][ks] = *(const bf16x8*)(Wtlo + n * 128 + kb);
        }
    }
    float a2v[4][4];
#pragma unroll
    for (int nf = 0; nf < 4; ++nf)
#pragma unroll
        for (int v = 0; v < 4; ++v)
            a2v[nf][v] = a2w[(n0 + nf * 16 + lh * 4 + v) & 127];

    const bool isPs = (w < 2);
    unsigned short* PH = isPs ? PsH : PdH;
    float* qout = isPs ? qs : qd;
    const int colbase0 = (n0 & 127) + lh * 4;   // + nf*16 per fragment

    f32x4 zz = {0.f, 0.f, 0.f, 0.f};

    for (int mt = blockIdx.x; mt < MT_TOTAL; mt += ENT_GRID) {
        const int m = mt * 16 + l15;            // < 100000 always (6250*16 exact)
        // B-frags: ent row m, k-slices, f32 -> bf16 hi/lo in regs
        bf16x8 eh[4], el[4];
#pragma unroll
        for (int ks = 0; ks < 4; ++ks) {
            int kb = ks * 32 + lh * 8;
            float4 e0 = *(const float4*)&ent[(size_t)m * 128 + kb];
            float4 e1 = *(const float4*)&ent[(size_t)m * 128 + kb + 4];
            float f[8] = {e0.x, e0.y, e0.z, e0.w, e1.x, e1.y, e1.z, e1.w};
            bf16x8 hv, lv;
#pragma unroll
            for (int j = 0; j < 8; ++j) {
                unsigned short h = bf_rne(f[j]);
                hv[j] = (short)h;
                lv[j] = (short)bf_rne(f[j] - bf2f(h));
            }
            eh[ks] = hv; el[ks] = lv;
        }

        f32x4 acc[4];
#pragma unroll
        for (int nf = 0; nf < 4; ++nf) acc[nf] = zz;
#pragma unroll
        for (int ks = 0; ks < 4; ++ks)
#pragma unroll
            for (int nf = 0; nf < 4; ++nf) {
                acc[nf] = __builtin_amdgcn_mfma_f32_16x16x32_bf16(wh[nf][ks], eh[ks], acc[nf], 0, 0, 0);
                acc[nf] = __builtin_amdgcn_mfma_f32_16x16x32_bf16(wh[nf][ks], el[ks], acc[nf], 0, 0, 0);
                acc[nf] = __builtin_amdgcn_mfma_f32_16x16x32_bf16(wl[nf][ks], eh[ks], acc[nf], 0, 0, 0);
            }

        // epilogue: packed bf16 stores (n-contiguous) + q partial
        float qp = 0.f;
#pragma unroll
        for (int nf = 0; nf < 4; ++nf) {
            ushort4 st;
            st.x = bf_rne(acc[nf][0]);
            st.y = bf_rne(acc[nf][1]);
            st.z = bf_rne(acc[nf][2]);
            st.w = bf_rne(acc[nf][3]);
#pragma unroll
            for (int v = 0; v < 4; ++v) qp = fmaf(acc[nf][v], a2v[nf][v], qp);
            *(ushort4*)&PH[(size_t)m * 128 + colbase0 + nf * 16] = st;
        }
        qp += __shfl_xor(qp, 16);
        qp += __shfl_xor(qp, 32);
        if (lane < 16) unsafeAtomicAdd(&qout[m], qp);   // 2 writers/address (w pairs)
    }
}

// ---------------- rel-key block histogram (LDS) + src global hist ----------------
__global__ __launch_bounds__(256) void edge_hist(const int* __restrict__ src,
                                                 const int* __restrict__ rel,
                                                 int* __restrict__ histSrc,
                                                 int* __restrict__ blkHist) {
    __shared__ int lh[512];
    int tid = threadIdx.x;
    lh[tid] = 0; lh[tid + 256] = 0;
    __syncthreads();
    int base = blockIdx.x * EPB;
#pragma unroll
    for (int j = 0; j < 4; ++j) {
        int e = base + j * 256 + tid;
        if (e < NEDGE_C) {
            atomicAdd(&histSrc[src[e]], 1);
            atomicAdd(&lh[rel[e]], 1);
        }
    }
    __syncthreads();
    blkHist[blockIdx.x * 512 + tid] = lh[tid];
    blkHist[blockIdx.x * 512 + 256 + tid] = lh[tid + 256];
}

__global__ void colsum(const int* __restrict__ blkHist, int* __restrict__ partial) {
    int r = threadIdx.x;
    int k = blockIdx.x;
    int b0 = k * CHUNK_B;
    int b1 = min(b0 + CHUNK_B, NB_EDGE);
    int t = 0;
    for (int b = b0; b < b1; ++b) t += blkHist[b * 512 + r];
    partial[k * 512 + r] = t;
}

__global__ void scan512(const int* __restrict__ partial, int* __restrict__ relStart,
                        int* __restrict__ chunkOff) {
    __shared__ int a[512], b2[512];
    int tid = threadIdx.x;
    int p8[8];
    int t = 0;
#pragma unroll
    for (int k = 0; k < 8; ++k) { p8[k] = partial[k * 512 + tid]; t += p8[k]; }
    a[tid] = t;
    __syncthreads();
    int v = t;
    int* cur = a; int* nxt = b2;
    for (int off = 1; off < 512; off <<= 1) {
        int x = cur[tid] + ((tid >= off) ? cur[tid - off] : 0);
        nxt[tid] = x;
        __syncthreads();
        int* tmp = cur; cur = nxt; nxt = tmp;
    }
    int excl = cur[tid] - v;
    relStart[tid] = excl;
    int run = excl;
#pragma unroll
    for (int k = 0; k < 8; ++k) { chunkOff[k * 512 + tid] = run; run += p8[k]; }
}

__global__ void colscan(const int* __restrict__ blkHist, const int* __restrict__ chunkOff,
                        int* __restrict__ blockOffs) {
    int r = threadIdx.x;
    int k = blockIdx.x;
    int b0 = k * CHUNK_B;
    int b1 = min(b0 + CHUNK_B, NB_EDGE);
    int off = chunkOff[k * 512 + r];
    for (int b = b0; b < b1; ++b) {
        blockOffs[b * 512 + r] = off;
        off += blkHist[b * 512 + r];
    }
}

__global__ void scan_blockred(const int* __restrict__ hist, int* __restrict__ blockSums, int n) {
    __shared__ int s[256];
    int tid = threadIdx.x;
    int i = blockIdx.x * 256 + tid;
    s[tid] = (i < n) ? hist[i] : 0;
    __syncthreads();
    for (int off = 128; off > 0; off >>= 1) {
        if (tid < off) s[tid] += s[tid + off];
        __syncthreads();
    }
    if (tid == 0) blockSums[blockIdx.x] = s[0];
}

__global__ void scan_single(int* __restrict__ data, int n) {
    __shared__ int a[1024], b2[1024];
    int tid = threadIdx.x;
    int v = (tid < n) ? data[tid] : 0;
    a[tid] = v;
    __syncthreads();
    int* cur = a; int* nxt = b2;
    for (int off = 1; off < 1024; off <<= 1) {
        int x = cur[tid] + ((tid >= off) ? cur[tid - off] : 0);
        nxt[tid] = x;
        __syncthreads();
        int* t = cur; cur = nxt; nxt = t;
    }
    if (tid < n) data[tid] = cur[tid] - v;   // exclusive
}

__global__ void scan_final(const int* __restrict__ hist, const int* __restrict__ blockOffs,
                           int* __restrict__ offs, int n) {
    __shared__ int a[256], b2[256];
    int tid = threadIdx.x;
    int i = blockIdx.x * 256 + tid;
    int v = (i < n) ? hist[i] : 0;
    a[tid] = v;
    __syncthreads();
    int* cur = a; int* nxt = b2;
    for (int off = 1; off < 256; off <<= 1) {
        int x = cur[tid] + ((tid >= off) ? cur[tid - off] : 0);
        nxt[tid] = x;
        __syncthreads();
        int* t = cur; cur = nxt; nxt = t;
    }
    if (i < n) offs[i] = cur[tid] - v + blockOffs[blockIdx.x];
}

__global__ __launch_bounds__(256) void scatter_both(const int* __restrict__ src,
                                                    const int* __restrict__ dst,
                                                    const int* __restrict__ rel,
                                                    int* __restrict__ offsSrc,
                                                    const int* __restrict__ blockOffs,
                                                    int* __restrict__ dstS, int* __restrict__ relS,
                                                    int* __restrict__ srcR, int* __restrict__ dstR) {
    __shared__ int lh[512];
    int tid = threadIdx.x;
    lh[tid] = 0; lh[tid + 256] = 0;
    __syncthreads();
    int base = blockIdx.x * EPB;
    const int* bo = &blockOffs[blockIdx.x * 512];
#pragma unroll
    for (int j = 0; j < 4; ++j) {
        int e = base + j * 256 + tid;
        if (e < NEDGE_C) {
            int s = src[e], d = dst[e], r = rel[e];
            int p = atomicAdd(&offsSrc[s], 1);
            dstS[p] = d; relS[p] = r;
            int lr = atomicAdd(&lh[r], 1);
            int q = bo[r] + lr;
            srcR[q] = s; dstR[q] = d;
        }
    }
}

// ---------------- rel phase: 8 partial blocks per relation, bf16 row gathers ----------
__global__ __launch_bounds__(256) void rel_phase(const unsigned short* __restrict__ PsH,
                                                 const unsigned short* __restrict__ PdH,
                                                 const float* __restrict__ qs,
                                                 const float* __restrict__ qd,
                                                 const float* __restrict__ qr,
                                                 const int* __restrict__ relStart,
                                                 const int* __restrict__ srcR,
                                                 const int* __restrict__ dstR,
                                                 const float* __restrict__ a2b,
                                                 float* __restrict__ relpart) {
    int r = blockIdx.x >> 3;
    int p = blockIdx.x & 7;
    int start = relStart[r];
    int end = relStart[r + 1];
    int tid = threadIdx.x;
    int w = tid >> 6;
    int h = (tid >> 5) & 1;
    int l = tid & 31;
    int slot = p * 8 + w * 2 + h;
    float bb = a2b[0];
    float qrr = qr[r];
    float4 acc = make_float4(0.f, 0.f, 0.f, 0.f);
    float ebs = 0.f;
    for (int i = start + slot; i < end; i += 64) {
        int s = srcR[i], d = dstR[i];
        float b = qs[s] + qd[d] + qrr + bb;
        b = (b > 0.f) ? b : 0.01f * b;
        float eb = expf(b);
        ushort4 pv = *(const ushort4*)&PsH[(size_t)s * 128 + l * 4];
        ushort4 dv = *(const ushort4*)&PdH[(size_t)d * 128 + l * 4];
        acc.x = fmaf(eb, bf2f(pv.x) + bf2f(dv.x), acc.x);
        acc.y = fmaf(eb, bf2f(pv.y) + bf2f(dv.y), acc.y);
        acc.z = fmaf(eb, bf2f(pv.z) + bf2f(dv.z), acc.z);
        acc.w = fmaf(eb, bf2f(pv.w) + bf2f(dv.w), acc.w);
        ebs += eb;
    }
    __shared__ float vred[8][128];
    __shared__ float sred[8];
    int sub = w * 2 + h;
    *(float4*)&vred[sub][l * 4] = acc;
    if (l == 0) sred[sub] = ebs;
    __syncthreads();
    if (tid < 128) {
        float v = 0.f;
#pragma unroll
        for (int k2 = 0; k2 < 8; ++k2) v += vred[k2][tid];
        float e = 0.f;
#pragma unroll
        for (int k2 = 0; k2 < 8; ++k2) e += sred[k2];
        int pi = r * 8 + p;
        relpart[pi * 132 + tid] = v;
        if (tid == 0) relpart[pi * 132 + 128] = e;
    }
}

__global__ void rel_fin(const float* __restrict__ relpart, const float* __restrict__ Pr,
                        const int* __restrict__ relStart, float* __restrict__ outRel) {
    int r = blockIdx.x;
    int o = threadIdx.x;
    float v = 0.f, e = 0.f;
#pragma unroll
    for (int p = 0; p < 8; ++p) {
        v += relpart[(r * 8 + p) * 132 + o];
        e += relpart[(r * 8 + p) * 132 + 128];
    }
    float cnt = (float)(relStart[r + 1] - relStart[r]);
    float h = (v + e * Pr[r * 128 + o]) / fmaxf(cnt, 1.f);
    outRel[r * 128 + o] = (h > 0.f) ? h : (expf(h) - 1.f);
}

// ---------------- src phase: 4 edges in flight, all-bf16 gathers ----------------
__global__ __launch_bounds__(256) void src_phase(const unsigned short* __restrict__ PsH,
                                                 const unsigned short* __restrict__ PdH,
                                                 const unsigned short* __restrict__ PrH,
                                                 const float* __restrict__ qs,
                                                 const float* __restrict__ qd,
                                                 const float* __restrict__ qr,
                                                 const int* __restrict__ offsSrc,
                                                 const int* __restrict__ dstS,
                                                 const int* __restrict__ relS,
                                                 const float* __restrict__ a2b,
                                                 float* __restrict__ stage,
                                                 float* __restrict__ out) {
    int wid = (blockIdx.x * 256 + threadIdx.x) >> 6;
    if (wid >= N_ENT_C) return;
    int lane = threadIdx.x & 63;
    int g = lane >> 4, l = lane & 15;       // 4 groups x 16 lanes; lane covers cols l*8..l*8+7
    int s = wid;
    int start = (s == 0) ? 0 : offsSrc[s - 1];
    int end = offsSrc[s];
    float* dstp = (s < SCRATCH_ROWS) ? &stage[(size_t)s * 128] : &out[(size_t)s * 128];
    if (end == start) {
        if (g == 0) {
            *(float4*)&dstp[l * 8] = make_float4(0.f, 0.f, 0.f, 0.f);
            *(float4*)&dstp[l * 8 + 4] = make_float4(0.f, 0.f, 0.f, 0.f);
        }
        return;
    }
    float bb = a2b[0];
    float qss = qs[s];
    float acc[8];
#pragma unroll
    for (int j = 0; j < 8; ++j) acc[j] = 0.f;
    float ebs = 0.f;
    for (int i = start + g; i < end; i += 4) {
        int d = dstS[i], r = relS[i];
        float b = qss + qd[d] + qr[r] + bb;
        b = (b > 0.f) ? b : 0.01f * b;
        float eb = expf(b);
        u16x8 dv = *(const u16x8*)&PdH[(size_t)d * 128 + l * 8];
        u16x8 rv = *(const u16x8*)&PrH[(size_t)r * 128 + l * 8];
#pragma unroll
        for (int j = 0; j < 8; ++j)
            acc[j] = fmaf(eb, bf2f(dv[j]) + bf2f(rv[j]), acc[j]);
        ebs += eb;
    }
#pragma unroll
    for (int j = 0; j < 8; ++j) {
        acc[j] += __shfl_xor(acc[j], 16);
        acc[j] += __shfl_xor(acc[j], 32);
    }
    ebs += __shfl_xor(ebs, 16);
    ebs += __shfl_xor(ebs, 32);
    if (g == 0) {
        float inv = 1.f / ebs;
        u16x8 ps = *(const u16x8*)&PsH[(size_t)s * 128 + l * 8];
        float h[8];
#pragma unroll
        for (int j = 0; j < 8; ++j) {
            float x = bf2f(ps[j]) + acc[j] * inv;
            h[j] = (x > 0.f) ? x : (expf(x) - 1.f);
        }
        *(float4*)&dstp[l * 8]     = make_float4(h[0], h[1], h[2], h[3]);
        *(float4*)&dstp[l * 8 + 4] = make_float4(h[4], h[5], h[6], h[7]);
    }
}

extern "C" void kernel_launch(void* const* d_in, const int* in_sizes, int n_in,
                              void* d_out, int out_size, void* d_ws, size_t ws_size,
                              hipStream_t stream) {
    const float* ent  = (const float*)d_in[0];
    const float* rele = (const float*)d_in[1];
    const float* aw   = (const float*)d_in[2];
    const float* ab   = (const float*)d_in[3];
    const float* a2w  = (const float*)d_in[4];
    const float* a2b  = (const float*)d_in[5];
    const int* src    = (const int*)d_in[6];
    const int* dst    = (const int*)d_in[7];
    const int* rel    = (const int*)d_in[8];
    float* out = (float*)d_out;

    float* ws = (float*)d_ws;
    unsigned short* Wthi = (unsigned short*)(ws + OFF_WTHI);
    unsigned short* Wtlo = (unsigned short*)(ws + OFF_WTLO);
    float* Wtr = ws + OFF_WTR;
    float* Pr  = ws + OFF_PR;
    unsigned short* PrH = (unsigned short*)(ws + OFF_PRH);
    float* stage = ws + OFF_STAGE;
    unsigned short* PsH = (unsigned short*)(ws + OFF_PSH);
    unsigned short* PdH = (unsigned short*)(ws + OFF_PDH);

    int* dI = (int*)d_out;
    int* offsSrc  = dI + DO_OSRC;
    int* dstS     = dI + DO_DSTS;
    int* relS     = dI + DO_RELS;
    float* qs     = (float*)dI + DO_QS;
    float* qd     = (float*)dI + DO_QD;
    float* qr     = (float*)dI + DO_QR;
    int* histSrc  = dI + DO_HSRC;
    int* bsum     = dI + DO_BSUM;
    int* relStart = dI + DO_RELSTART;
    int* part8    = dI + DO_PART8;
    int* chunkOff = dI + DO_CHUNKOFF;
    int* blkHist  = dI + DO_BLKHIST;
    int* blockOffs= dI + DO_BLKOFFS;
    int* srcR     = dI + DO_SRCR;
    int* dstR     = dI + DO_DSTR;
    float* relpart = (float*)dI + DO_RELP;

    // zero qs, qd, qr, histSrc in one contiguous memset (qs/qd are atomic accumulators)
    hipMemsetAsync(dI + DO_QS, 0, (size_t)(DO_HSRC + N_ENT_C - DO_QS) * sizeof(int), stream);

    prep_w<<<192, 256, 0, stream>>>(aw, Wthi, Wtlo, Wtr);
    rel_proj<<<N_REL_C, 128, 0, stream>>>(rele, Wtr, ab, a2w, Pr, PrH, qr);
    ent_mfma<<<ENT_GRID, 256, 0, stream>>>(ent, Wthi, Wtlo, a2w, PsH, PdH, qs, qd);

    edge_hist<<<NB_EDGE, 256, 0, stream>>>(src, rel, histSrc, blkHist);
    colsum<<<8, 512, 0, stream>>>(blkHist, part8);
    scan512<<<1, 512, 0, stream>>>(part8, relStart, chunkOff);
    colscan<<<8, 512, 0, stream>>>(blkHist, chunkOff, blockOffs);
    scan_blockred<<<SCAN_BLOCKS, 256, 0, stream>>>(histSrc, bsum, N_ENT_C);
    scan_single<<<1, 1024, 0, stream>>>(bsum, SCAN_BLOCKS);
    scan_final<<<SCAN_BLOCKS, 256, 0, stream>>>(histSrc, bsum, offsSrc, N_ENT_C);
    scatter_both<<<NB_EDGE, 256, 0, stream>>>(src, dst, rel, offsSrc, blockOffs,
                                              dstS, relS, srcR, dstR);

    rel_phase<<<N_REL_C * 8, 256, 0, stream>>>(PsH, PdH, qs, qd, qr, relStart, srcR, dstR,
                                               a2b, relpart);
    rel_fin<<<N_REL_C, 128, 0, stream>>>(relpart, Pr, relStart, out + (size_t)N_ENT_C * 128);

    src_phase<<<(N_ENT_C + 3) / 4, 256, 0, stream>>>(PsH, PdH, PrH, qs, qd, qr,
                                                     offsSrc, dstS, relS, a2b, stage, out);

    // copy staged rows (the ones whose d_out slots held src-phase-live scratch)
    hipMemcpyAsync(out, stage, (size_t)SCRATCH_ROWS * 128 * sizeof(float),
                   hipMemcpyDeviceToDevice, stream);
}

// Round 9
// 264.639 us; speedup vs baseline: 3.9788x; 1.0032x over previous
//
#include <hip/hip_runtime.h>
#include <hip/hip_bf16.h>

#define N_ENT_C 100000
#define N_REL_C 500
#define NEDGE_C 500000
#define SCAN_BLOCKS 391   // ceil(100000/256)
#define EPB 1024          // edges per block for rel sort
#define NB_EDGE 489       // ceil(500000/1024)
#define CHUNK_B 62        // ceil(489/8)
#define MT_TOTAL 6250     // 100000/16 m-tiles, exact
#define ENT_GRID 1250     // 5 m-tiles per block

// ---------------- ws layout (float offsets) — well under the proven 25.7M footprint ---
#define OFF_WTHI  0         // Wt hi bf16 [256][128] -> 16384 f32 slots
#define OFF_WTLO  16384     // Wt lo bf16 [256][128]
#define OFF_WTR   32768     // Wtr f32 [128][128]
#define OFF_PR    49152     // Pr f32 [500][128]
#define OFF_PRH   113152    // PrH bf16 [500][128] -> 32000 f32 slots
#define OFF_STAGE 145152    // stage f32 [10161][128] = 1,300,608
#define OFF_PSH   1445760   // PsH bf16 [100000][128] -> 6.4M f32 slots
#define OFF_PDH   7845760   // PdH bf16 [100000][128] -> 6.4M f32 slots
// end = 14,245,760 floats = 57 MB

// ---------------- d_out scratch layout ------------------------------------------------
// LOW region: live during src_phase (rows 0..SCRATCH_ROWS-1, staged in ws, memcpy'd last)
#define DO_OSRC     0         // offsSrc [100000]
#define DO_DSTS     100000    // dstS [500000]
#define DO_RELS     600000    // relS [500000]
#define DO_QS       1100000   // qs [100000]   (atomic-accumulated, zeroed by memset)
#define DO_QD       1200000   // qd [100000]   (atomic-accumulated, zeroed by memset)
#define DO_QR       1300000   // qr [512]
// end low = 1,300,512 -> SCRATCH_ROWS = ceil(/128) = 10161
#define SCRATCH_ROWS 10161
// HIGH region: dead before src_phase runs (src_phase writes these rows directly)
#define DO_HSRC     1300512   // histSrc [100000]
#define DO_BSUM     1400512   // blockSums [512]
#define DO_RELSTART 1401024   // relStart [512]
#define DO_PART8    1401536   // partial [8][512]
#define DO_CHUNKOFF 1405632   // chunkOff [8][512]
#define DO_BLKHIST  1409728   // blkHist [489][512]
#define DO_BLKOFFS  1660096   // blockOffs [489][512]
#define DO_SRCR     1910464   // srcR [500000]
#define DO_DSTR     2410464   // dstR [500000]
#define DO_RELP     2910464   // relpart [4000][132]
// end = 3,438,464 ints << 12.8M entity region

typedef short bf16x8 __attribute__((ext_vector_type(8)));   // 8 bf16 in 4 VGPRs
typedef float f32x4  __attribute__((ext_vector_type(4)));
typedef unsigned short u16x8 __attribute__((ext_vector_type(8)));

__device__ inline unsigned short bf_rne(float x) {
    unsigned int u = __float_as_uint(x);
    u += 0x7FFF + ((u >> 16) & 1);          // round-nearest-even
    return (unsigned short)(u >> 16);
}
__device__ inline float bf2f(unsigned short h) {
    return __uint_as_float(((unsigned int)h) << 16);
}

// ---------------- weight prep: Wt (transposed by n, k contiguous) as bf16 hi/lo -------
__global__ void prep_w(const float* __restrict__ aw, unsigned short* __restrict__ Wthi,
                       unsigned short* __restrict__ Wtlo, float* __restrict__ Wtr) {
    int idx = blockIdx.x * 256 + threadIdx.x;   // 0..49151
    if (idx < 32768) {
        int n = idx >> 7, k = idx & 127;
        float v = (n < 128) ? aw[n * 384 + k] : aw[(n - 128) * 384 + 128 + k];
        unsigned short h = bf_rne(v);
        Wthi[idx] = h;
        Wtlo[idx] = bf_rne(v - bf2f(h));
    } else if (idx < 49152) {
        int t = idx - 32768;
        int k = t >> 7, o = t & 127;
        Wtr[t] = aw[o * 384 + 256 + k];
    }
}

// ---------------- rel projection + qr epilogue (f32, tiny) ----------------
__global__ void rel_proj(const float* __restrict__ rele, const float* __restrict__ Wtr,
                         const float* __restrict__ ab, const float* __restrict__ a2w,
                         float* __restrict__ Pr, unsigned short* __restrict__ PrH,
                         float* __restrict__ qr) {
    int r = blockIdx.x;
    int o = threadIdx.x;
    float acc = ab[o];
    for (int k = 0; k < 128; ++k)
        acc = fmaf(rele[r * 128 + k], Wtr[k * 128 + o], acc);
    Pr[r * 128 + o] = acc;
    PrH[r * 128 + o] = bf_rne(acc);
    __shared__ float red[128];
    red[o] = acc * a2w[o];
    __syncthreads();
    for (int off = 64; off > 0; off >>= 1) {
        if (o < off) red[o] += red[o + off];
        __syncthreads();
    }
    if (o == 0) qr[r] = red[0];
}

// ---------------- ent projection: swapped-operand MFMA, W pinned in VGPRs -------------
// D = W · ent^T. A-frag = W rows (PINNED in regs via asm), B-frag = ent row slices.
// C layout: col(lane&15) = entity row, row(lh*4+reg) = output col n -> packed stores.
__global__ __launch_bounds__(256, 2) void ent_mfma(const float* __restrict__ ent,
                                                   const unsigned short* __restrict__ Wthi,
                                                   const unsigned short* __restrict__ Wtlo,
                                                   const float* __restrict__ a2w,
                                                   unsigned short* __restrict__ PsH,
                                                   unsigned short* __restrict__ PdH,
                                                   float* __restrict__ qs,
                                                   float* __restrict__ qd) {
    const int tid = threadIdx.x;
    const int w = tid >> 6, lane = tid & 63;
    const int l15 = lane & 15, lh = lane >> 4;
    const int n0 = w * 64;

    // A-frags: W hi/lo for this wave's 4 n-fragments, all 4 k-steps. 128 VGPRs, loaded once.
    bf16x8 wh[4][4], wl[4][4];
#pragma unroll
    for (int nf = 0; nf < 4; ++nf) {
        int n = n0 + nf * 16 + l15;
#pragma unroll
        for (int ks = 0; ks < 4; ++ks) {
            int kb = ks * 32 + lh * 8;
            wh[nf][ks] = *(const bf16x8*)(Wthi + n * 128 + kb);
            wl[nf][ks] = *(const bf16x8*)(Wtlo + n * 128 + kb);
        }
    }
    // Pin W fragments in registers: opaque provenance -> compiler cannot rematerialize
    // the loads inside the m-loop (R8 showed it reloading all 32 frags per iteration).
#pragma unroll
    for (int nf = 0; nf < 4; ++nf)
#pragma unroll
        for (int ks = 0; ks < 4; ++ks) {
            asm volatile("" : "+v"(wh[nf][ks]));
            asm volatile("" : "+v"(wl[nf][ks]));
        }

    float a2v[4][4];
#pragma unroll
    for (int nf = 0; nf < 4; ++nf)
#pragma unroll
        for (int v = 0; v < 4; ++v)
            a2v[nf][v] = a2w[(n0 + nf * 16 + lh * 4 + v) & 127];

    const bool isPs = (w < 2);
    unsigned short* PH = isPs ? PsH : PdH;
    float* qout = isPs ? qs : qd;
    const int colbase0 = (n0 & 127) + lh * 4;   // + nf*16 per fragment

    f32x4 zz = {0.f, 0.f, 0.f, 0.f};

    for (int mt = blockIdx.x; mt < MT_TOTAL; mt += ENT_GRID) {
        const int m = mt * 16 + l15;            // < 100000 always (6250*16 exact)
        // issue all 8 ent loads up front (one latency per iteration)
        float4 e[8];
#pragma unroll
        for (int q2 = 0; q2 < 8; ++q2)
            e[q2] = *(const float4*)&ent[(size_t)m * 128 + lh * 8 + q2 * 16 + (q2 & 1) * 4 - (q2 & 1) * 16 + (q2 >> 1) * 32 - (q2 >> 1) * 16];
        // (indexing: slice ks=q2>>1 at kb=ks*32+lh*8, halves q2&1 -> kb and kb+4)
        // rewritten plainly below to avoid any confusion:
#pragma unroll
        for (int ks = 0; ks < 4; ++ks) {
            int kb = ks * 32 + lh * 8;
            e[ks * 2]     = *(const float4*)&ent[(size_t)m * 128 + kb];
            e[ks * 2 + 1] = *(const float4*)&ent[(size_t)m * 128 + kb + 4];
        }

        f32x4 acc[4];
#pragma unroll
        for (int nf = 0; nf < 4; ++nf) acc[nf] = zz;

        // per k-slice: convert 8 elems -> hi/lo frags, then 12 MFMAs
#pragma unroll
        for (int ks = 0; ks < 4; ++ks) {
            float f[8] = {e[ks * 2].x, e[ks * 2].y, e[ks * 2].z, e[ks * 2].w,
                          e[ks * 2 + 1].x, e[ks * 2 + 1].y, e[ks * 2 + 1].z, e[ks * 2 + 1].w};
            bf16x8 eh, el;
#pragma unroll
            for (int j = 0; j < 8; ++j) {
                unsigned short h = bf_rne(f[j]);
                eh[j] = (short)h;
                el[j] = (short)bf_rne(f[j] - bf2f(h));
            }
#pragma unroll
            for (int nf = 0; nf < 4; ++nf) {
                acc[nf] = __builtin_amdgcn_mfma_f32_16x16x32_bf16(wh[nf][ks], eh, acc[nf], 0, 0, 0);
                acc[nf] = __builtin_amdgcn_mfma_f32_16x16x32_bf16(wh[nf][ks], el, acc[nf], 0, 0, 0);
                acc[nf] = __builtin_amdgcn_mfma_f32_16x16x32_bf16(wl[nf][ks], eh, acc[nf], 0, 0, 0);
            }
        }

        // epilogue: packed bf16 stores (n-contiguous) + q partial
        float qp = 0.f;
#pragma unroll
        for (int nf = 0; nf < 4; ++nf) {
            ushort4 st;
            st.x = bf_rne(acc[nf][0]);
            st.y = bf_rne(acc[nf][1]);
            st.z = bf_rne(acc[nf][2]);
            st.w = bf_rne(acc[nf][3]);
#pragma unroll
            for (int v = 0; v < 4; ++v) qp = fmaf(acc[nf][v], a2v[nf][v], qp);
            *(ushort4*)&PH[(size_t)m * 128 + colbase0 + nf * 16] = st;
        }
        qp += __shfl_xor(qp, 16);
        qp += __shfl_xor(qp, 32);
        if (lane < 16) unsafeAtomicAdd(&qout[m], qp);   // 2 writers/address (w pairs)
    }
}

// ---------------- rel-key block histogram (LDS) + src global hist ----------------
__global__ __launch_bounds__(256) void edge_hist(const int* __restrict__ src,
                                                 const int* __restrict__ rel,
                                                 int* __restrict__ histSrc,
                                                 int* __restrict__ blkHist) {
    __shared__ int lh[512];
    int tid = threadIdx.x;
    lh[tid] = 0; lh[tid + 256] = 0;
    __syncthreads();
    int base = blockIdx.x * EPB;
#pragma unroll
    for (int j = 0; j < 4; ++j) {
        int e = base + j * 256 + tid;
        if (e < NEDGE_C) {
            atomicAdd(&histSrc[src[e]], 1);
            atomicAdd(&lh[rel[e]], 1);
        }
    }
    __syncthreads();
    blkHist[blockIdx.x * 512 + tid] = lh[tid];
    blkHist[blockIdx.x * 512 + 256 + tid] = lh[tid + 256];
}

__global__ void colsum(const int* __restrict__ blkHist, int* __restrict__ partial) {
    int r = threadIdx.x;
    int k = blockIdx.x;
    int b0 = k * CHUNK_B;
    int b1 = min(b0 + CHUNK_B, NB_EDGE);
    int t = 0;
    for (int b = b0; b < b1; ++b) t += blkHist[b * 512 + r];
    partial[k * 512 + r] = t;
}

__global__ void scan512(const int* __restrict__ partial, int* __restrict__ relStart,
                        int* __restrict__ chunkOff) {
    __shared__ int a[512], b2[512];
    int tid = threadIdx.x;
    int p8[8];
    int t = 0;
#pragma unroll
    for (int k = 0; k < 8; ++k) { p8[k] = partial[k * 512 + tid]; t += p8[k]; }
    a[tid] = t;
    __syncthreads();
    int v = t;
    int* cur = a; int* nxt = b2;
    for (int off = 1; off < 512; off <<= 1) {
        int x = cur[tid] + ((tid >= off) ? cur[tid - off] : 0);
        nxt[tid] = x;
        __syncthreads();
        int* tmp = cur; cur = nxt; nxt = tmp;
    }
    int excl = cur[tid] - v;
    relStart[tid] = excl;
    int run = excl;
#pragma unroll
    for (int k = 0; k < 8; ++k) { chunkOff[k * 512 + tid] = run; run += p8[k]; }
}

__global__ void colscan(const int* __restrict__ blkHist, const int* __restrict__ chunkOff,
                        int* __restrict__ blockOffs) {
    int r = threadIdx.x;
    int k = blockIdx.x;
    int b0 = k * CHUNK_B;
    int b1 = min(b0 + CHUNK_B, NB_EDGE);
    int off = chunkOff[k * 512 + r];
    for (int b = b0; b < b1; ++b) {
        blockOffs[b * 512 + r] = off;
        off += blkHist[b * 512 + r];
    }
}

__global__ void scan_blockred(const int* __restrict__ hist, int* __restrict__ blockSums, int n) {
    __shared__ int s[256];
    int tid = threadIdx.x;
    int i = blockIdx.x * 256 + tid;
    s[tid] = (i < n) ? hist[i] : 0;
    __syncthreads();
    for (int off = 128; off > 0; off >>= 1) {
        if (tid < off) s[tid] += s[tid + off];
        __syncthreads();
    }
    if (tid == 0) blockSums[blockIdx.x] = s[0];
}

__global__ void scan_single(int* __restrict__ data, int n) {
    __shared__ int a[1024], b2[1024];
    int tid = threadIdx.x;
    int v = (tid < n) ? data[tid] : 0;
    a[tid] = v;
    __syncthreads();
    int* cur = a; int* nxt = b2;
    for (int off = 1; off < 1024; off <<= 1) {
        int x = cur[tid] + ((tid >= off) ? cur[tid - off] : 0);
        nxt[tid] = x;
        __syncthreads();
        int* t = cur; cur = nxt; nxt = t;
    }
    if (tid < n) data[tid] = cur[tid] - v;   // exclusive
}

__global__ void scan_final(const int* __restrict__ hist, const int* __restrict__ blockOffs,
                           int* __restrict__ offs, int n) {
    __shared__ int a[256], b2[256];
    int tid = threadIdx.x;
    int i = blockIdx.x * 256 + tid;
    int v = (i < n) ? hist[i] : 0;
    a[tid] = v;
    __syncthreads();
    int* cur = a; int* nxt = b2;
    for (int off = 1; off < 256; off <<= 1) {
        int x = cur[tid] + ((tid >= off) ? cur[tid - off] : 0);
        nxt[tid] = x;
        __syncthreads();
        int* t = cur; cur = nxt; nxt = t;
    }
    if (i < n) offs[i] = cur[tid] - v + blockOffs[blockIdx.x];
}

__global__ __launch_bounds__(256) void scatter_both(const int* __restrict__ src,
                                                    const int* __restrict__ dst,
                                                    const int* __restrict__ rel,
                                                    int* __restrict__ offsSrc,
                                                    const int* __restrict__ blockOffs,
                                                    int* __restrict__ dstS, int* __restrict__ relS,
                                                    int* __restrict__ srcR, int* __restrict__ dstR) {
    __shared__ int lh[512];
    int tid = threadIdx.x;
    lh[tid] = 0; lh[tid + 256] = 0;
    __syncthreads();
    int base = blockIdx.x * EPB;
    const int* bo = &blockOffs[blockIdx.x * 512];
#pragma unroll
    for (int j = 0; j < 4; ++j) {
        int e = base + j * 256 + tid;
        if (e < NEDGE_C) {
            int s = src[e], d = dst[e], r = rel[e];
            int p = atomicAdd(&offsSrc[s], 1);
            dstS[p] = d; relS[p] = r;
            int lr = atomicAdd(&lh[r], 1);
            int q = bo[r] + lr;
            srcR[q] = s; dstR[q] = d;
        }
    }
}

// ---------------- rel phase: 8 partial blocks per relation, bf16 row gathers ----------
__global__ __launch_bounds__(256) void rel_phase(const unsigned short* __restrict__ PsH,
                                                 const unsigned short* __restrict__ PdH,
                                                 const float* __restrict__ qs,
                                                 const float* __restrict__ qd,
                                                 const float* __restrict__ qr,
                                                 const int* __restrict__ relStart,
                                                 const int* __restrict__ srcR,
                                                 const int* __restrict__ dstR,
                                                 const float* __restrict__ a2b,
                                                 float* __restrict__ relpart) {
    int r = blockIdx.x >> 3;
    int p = blockIdx.x & 7;
    int start = relStart[r];
    int end = relStart[r + 1];
    int tid = threadIdx.x;
    int w = tid >> 6;
    int h = (tid >> 5) & 1;
    int l = tid & 31;
    int slot = p * 8 + w * 2 + h;
    float bb = a2b[0];
    float qrr = qr[r];
    float4 acc = make_float4(0.f, 0.f, 0.f, 0.f);
    float ebs = 0.f;
    for (int i = start + slot; i < end; i += 64) {
        int s = srcR[i], d = dstR[i];
        float b = qs[s] + qd[d] + qrr + bb;
        b = (b > 0.f) ? b : 0.01f * b;
        float eb = expf(b);
        ushort4 pv = *(const ushort4*)&PsH[(size_t)s * 128 + l * 4];
        ushort4 dv = *(const ushort4*)&PdH[(size_t)d * 128 + l * 4];
        acc.x = fmaf(eb, bf2f(pv.x) + bf2f(dv.x), acc.x);
        acc.y = fmaf(eb, bf2f(pv.y) + bf2f(dv.y), acc.y);
        acc.z = fmaf(eb, bf2f(pv.z) + bf2f(dv.z), acc.z);
        acc.w = fmaf(eb, bf2f(pv.w) + bf2f(dv.w), acc.w);
        ebs += eb;
    }
    __shared__ float vred[8][128];
    __shared__ float sred[8];
    int sub = w * 2 + h;
    *(float4*)&vred[sub][l * 4] = acc;
    if (l == 0) sred[sub] = ebs;
    __syncthreads();
    if (tid < 128) {
        float v = 0.f;
#pragma unroll
        for (int k2 = 0; k2 < 8; ++k2) v += vred[k2][tid];
        float e = 0.f;
#pragma unroll
        for (int k2 = 0; k2 < 8; ++k2) e += sred[k2];
        int pi = r * 8 + p;
        relpart[pi * 132 + tid] = v;
        if (tid == 0) relpart[pi * 132 + 128] = e;
    }
}

__global__ void rel_fin(const float* __restrict__ relpart, const float* __restrict__ Pr,
                        const int* __restrict__ relStart, float* __restrict__ outRel) {
    int r = blockIdx.x;
    int o = threadIdx.x;
    float v = 0.f, e = 0.f;
#pragma unroll
    for (int p = 0; p < 8; ++p) {
        v += relpart[(r * 8 + p) * 132 + o];
        e += relpart[(r * 8 + p) * 132 + 128];
    }
    float cnt = (float)(relStart[r + 1] - relStart[r]);
    float h = (v + e * Pr[r * 128 + o]) / fmaxf(cnt, 1.f);
    outRel[r * 128 + o] = (h > 0.f) ? h : (expf(h) - 1.f);
}

// ---------------- src phase: 4 edges in flight, all-bf16 gathers ----------------
__global__ __launch_bounds__(256) void src_phase(const unsigned short* __restrict__ PsH,
                                                 const unsigned short* __restrict__ PdH,
                                                 const unsigned short* __restrict__ PrH,
                                                 const float* __restrict__ qs,
                                                 const float* __restrict__ qd,
                                                 const float* __restrict__ qr,
                                                 const int* __restrict__ offsSrc,
                                                 const int* __restrict__ dstS,
                                                 const int* __restrict__ relS,
                                                 const float* __restrict__ a2b,
                                                 float* __restrict__ stage,
                                                 float* __restrict__ out) {
    int wid = (blockIdx.x * 256 + threadIdx.x) >> 6;
    if (wid >= N_ENT_C) return;
    int lane = threadIdx.x & 63;
    int g = lane >> 4, l = lane & 15;       // 4 groups x 16 lanes; lane covers cols l*8..l*8+7
    int s = wid;
    int start = (s == 0) ? 0 : offsSrc[s - 1];
    int end = offsSrc[s];
    float* dstp = (s < SCRATCH_ROWS) ? &stage[(size_t)s * 128] : &out[(size_t)s * 128];
    if (end == start) {
        if (g == 0) {
            *(float4*)&dstp[l * 8] = make_float4(0.f, 0.f, 0.f, 0.f);
            *(float4*)&dstp[l * 8 + 4] = make_float4(0.f, 0.f, 0.f, 0.f);
        }
        return;
    }
    float bb = a2b[0];
    float qss = qs[s];
    float acc[8];
#pragma unroll
    for (int j = 0; j < 8; ++j) acc[j] = 0.f;
    float ebs = 0.f;
    for (int i = start + g; i < end; i += 4) {
        int d = dstS[i], r = relS[i];
        float b = qss + qd[d] + qr[r] + bb;
        b = (b > 0.f) ? b : 0.01f * b;
        float eb = expf(b);
        u16x8 dv = *(const u16x8*)&PdH[(size_t)d * 128 + l * 8];
        u16x8 rv = *(const u16x8*)&PrH[(size_t)r * 128 + l * 8];
#pragma unroll
        for (int j = 0; j < 8; ++j)
            acc[j] = fmaf(eb, bf2f(dv[j]) + bf2f(rv[j]), acc[j]);
        ebs += eb;
    }
#pragma unroll
    for (int j = 0; j < 8; ++j) {
        acc[j] += __shfl_xor(acc[j], 16);
        acc[j] += __shfl_xor(acc[j], 32);
    }
    ebs += __shfl_xor(ebs, 16);
    ebs += __shfl_xor(ebs, 32);
    if (g == 0) {
        float inv = 1.f / ebs;
        u16x8 ps = *(const u16x8*)&PsH[(size_t)s * 128 + l * 8];
        float h[8];
#pragma unroll
        for (int j = 0; j < 8; ++j) {
            float x = bf2f(ps[j]) + acc[j] * inv;
            h[j] = (x > 0.f) ? x : (expf(x) - 1.f);
        }
        *(float4*)&dstp[l * 8]     = make_float4(h[0], h[1], h[2], h[3]);
        *(float4*)&dstp[l * 8 + 4] = make_float4(h[4], h[5], h[6], h[7]);
    }
}

extern "C" void kernel_launch(void* const* d_in, const int* in_sizes, int n_in,
                              void* d_out, int out_size, void* d_ws, size_t ws_size,
                              hipStream_t stream) {
    const float* ent  = (const float*)d_in[0];
    const float* rele = (const float*)d_in[1];
    const float* aw   = (const float*)d_in[2];
    const float* ab   = (const float*)d_in[3];
    const float* a2w  = (const float*)d_in[4];
    const float* a2b  = (const float*)d_in[5];
    const int* src    = (const int*)d_in[6];
    const int* dst    = (const int*)d_in[7];
    const int* rel    = (const int*)d_in[8];
    float* out = (float*)d_out;

    float* ws = (float*)d_ws;
    unsigned short* Wthi = (unsigned short*)(ws + OFF_WTHI);
    unsigned short* Wtlo = (unsigned short*)(ws + OFF_WTLO);
    float* Wtr = ws + OFF_WTR;
    float* Pr  = ws + OFF_PR;
    unsigned short* PrH = (unsigned short*)(ws + OFF_PRH);
    float* stage = ws + OFF_STAGE;
    unsigned short* PsH = (unsigned short*)(ws + OFF_PSH);
    unsigned short* PdH = (unsigned short*)(ws + OFF_PDH);

    int* dI = (int*)d_out;
    int* offsSrc  = dI + DO_OSRC;
    int* dstS     = dI + DO_DSTS;
    int* relS     = dI + DO_RELS;
    float* qs     = (float*)dI + DO_QS;
    float* qd     = (float*)dI + DO_QD;
    float* qr     = (float*)dI + DO_QR;
    int* histSrc  = dI + DO_HSRC;
    int* bsum     = dI + DO_BSUM;
    int* relStart = dI + DO_RELSTART;
    int* part8    = dI + DO_PART8;
    int* chunkOff = dI + DO_CHUNKOFF;
    int* blkHist  = dI + DO_BLKHIST;
    int* blockOffs= dI + DO_BLKOFFS;
    int* srcR     = dI + DO_SRCR;
    int* dstR     = dI + DO_DSTR;
    float* relpart = (float*)dI + DO_RELP;

    // zero qs, qd, qr, histSrc in one contiguous memset (qs/qd are atomic accumulators)
    hipMemsetAsync(dI + DO_QS, 0, (size_t)(DO_HSRC + N_ENT_C - DO_QS) * sizeof(int), stream);

    prep_w<<<192, 256, 0, stream>>>(aw, Wthi, Wtlo, Wtr);
    rel_proj<<<N_REL_C, 128, 0, stream>>>(rele, Wtr, ab, a2w, Pr, PrH, qr);
    ent_mfma<<<ENT_GRID, 256, 0, stream>>>(ent, Wthi, Wtlo, a2w, PsH, PdH, qs, qd);

    edge_hist<<<NB_EDGE, 256, 0, stream>>>(src, rel, histSrc, blkHist);
    colsum<<<8, 512, 0, stream>>>(blkHist, part8);
    scan512<<<1, 512, 0, stream>>>(part8, relStart, chunkOff);
    colscan<<<8, 512, 0, stream>>>(blkHist, chunkOff, blockOffs);
    scan_blockred<<<SCAN_BLOCKS, 256, 0, stream>>>(histSrc, bsum, N_ENT_C);
    scan_single<<<1, 1024, 0, stream>>>(bsum, SCAN_BLOCKS);
    scan_final<<<SCAN_BLOCKS, 256, 0, stream>>>(histSrc, bsum, offsSrc, N_ENT_C);
    scatter_both<<<NB_EDGE, 256, 0, stream>>>(src, dst, rel, offsSrc, blockOffs,
                                              dstS, relS, srcR, dstR);

    rel_phase<<<N_REL_C * 8, 256, 0, stream>>>(PsH, PdH, qs, qd, qr, relStart, srcR, dstR,
                                               a2b, relpart);
    rel_fin<<<N_REL_C, 128, 0, stream>>>(relpart, Pr, relStart, out + (size_t)N_ENT_C * 128);

    src_phase<<<(N_ENT_C + 3) / 4, 256, 0, stream>>>(PsH, PdH, PrH, qs, qd, qr,
                                                     offsSrc, dstS, relS, a2b, stage, out);

    // copy staged rows (the ones whose d_out slots held src-phase-live scratch)
    hipMemcpyAsync(out, stage, (size_t)SCRATCH_ROWS * 128 * sizeof(float),
                   hipMemcpyDeviceToDevice, stream);
}